// Round 2
// baseline (4580.875 us; speedup 1.0000x reference)
//
#include <hip/hip_runtime.h>
#include <hip/hip_bf16.h>
#include <math.h>

#define BB 2
#define SS 2048
#define DD 1024
#define DMM 1024
#define HH 16
#define DHH 64
#define RR (BB*SS)   // 4096 rows
#define NK (SS+1)    // 2049 keys

// ---------------- LayerNorm (optionally fused broadcast-add writing mixed) ----------------
__global__ __launch_bounds__(256) void ln_kernel(const float* __restrict__ in,
                                                 const float* __restrict__ mproj,   // may be null; [B,D] broadcast add
                                                 const float* __restrict__ g,
                                                 const float* __restrict__ be,
                                                 float* __restrict__ mixed_out,     // may be null (can alias `in`)
                                                 float* __restrict__ out)
{
    int row = blockIdx.x;            // 0..RR-1
    int b = row / SS;
    int tid = threadIdx.x;           // 256 threads, 4 floats each
    float4 v = ((const float4*)(in + (size_t)row * DD))[tid];
    if (mproj) {
        float4 mp = ((const float4*)(mproj + (size_t)b * DD))[tid];
        v.x += mp.x; v.y += mp.y; v.z += mp.z; v.w += mp.w;
        ((float4*)(mixed_out + (size_t)row * DD))[tid] = v;
    }
    float s  = v.x + v.y + v.z + v.w;
    float s2 = v.x*v.x + v.y*v.y + v.z*v.z + v.w*v.w;
    // wave reduce (wave=64)
    #pragma unroll
    for (int off = 32; off > 0; off >>= 1) {
        s  += __shfl_down(s,  off);
        s2 += __shfl_down(s2, off);
    }
    __shared__ float red[2][4];
    if ((tid & 63) == 0) { red[0][tid >> 6] = s; red[1][tid >> 6] = s2; }
    __syncthreads();
    float st  = red[0][0] + red[0][1] + red[0][2] + red[0][3];
    float s2t = red[1][0] + red[1][1] + red[1][2] + red[1][3];
    float mean = st * (1.0f / DD);
    float var  = s2t * (1.0f / DD) - mean * mean;
    float rs = rsqrtf(var + 1e-5f);
    float4 gg = ((const float4*)g)[tid];
    float4 bb = ((const float4*)be)[tid];
    float4 o;
    o.x = (v.x - mean) * rs * gg.x + bb.x;
    o.y = (v.y - mean) * rs * gg.y + bb.y;
    o.z = (v.z - mean) * rs * gg.z + bb.z;
    o.w = (v.w - mean) * rs * gg.w + bb.w;
    ((float4*)(out + (size_t)row * DD))[tid] = o;
}

// ---------------- Generic fp32 tiled GEMM: C = A[M,K] @ B[K,N] (+bias)(+resid)(gelu) ----------------
#define BM 64
#define BN 64
#define BK 16
__global__ __launch_bounds__(256) void gemm_kernel(const float* __restrict__ A,
                                                   const float* __restrict__ Bmat,
                                                   float* __restrict__ C,
                                                   int M, int N, int K,
                                                   const float* __restrict__ bias,
                                                   const float* __restrict__ resid,
                                                   int act)
{
    __shared__ float As[BK][BM + 1];   // [k][m], padded: write lanes step k
    __shared__ float Bs[BK][BN];       // [k][n]
    int bx = blockIdx.x;               // N / 64
    int by = blockIdx.y;               // M / 64
    int tid = threadIdx.x;
    int tx = tid & 15, ty = tid >> 4;
    int arow = by * BM, bcol = bx * BN;
    float acc[4][4] = {};
    for (int k0 = 0; k0 < K; k0 += BK) {
        #pragma unroll
        for (int i = 0; i < 4; i++) {
            int idx = tid + i * 256;           // 0..1023
            int m = idx >> 4, kk = idx & 15;
            As[kk][m] = A[(size_t)(arow + m) * K + k0 + kk];
        }
        #pragma unroll
        for (int i = 0; i < 4; i++) {
            int idx = tid + i * 256;
            int kk = idx >> 6, n = idx & 63;
            Bs[kk][n] = Bmat[(size_t)(k0 + kk) * N + bcol + n];
        }
        __syncthreads();
        #pragma unroll
        for (int kk = 0; kk < BK; kk++) {
            float a[4], bb[4];
            #pragma unroll
            for (int i = 0; i < 4; i++) a[i]  = As[kk][ty * 4 + i];
            #pragma unroll
            for (int j = 0; j < 4; j++) bb[j] = Bs[kk][tx * 4 + j];
            #pragma unroll
            for (int i = 0; i < 4; i++)
                #pragma unroll
                for (int j = 0; j < 4; j++)
                    acc[i][j] += a[i] * bb[j];
        }
        __syncthreads();
    }
    #pragma unroll
    for (int i = 0; i < 4; i++) {
        int m = arow + ty * 4 + i;
        #pragma unroll
        for (int j = 0; j < 4; j++) {
            int n = bcol + tx * 4 + j;
            float v = acc[i][j];
            if (bias)  v += bias[n];
            if (resid) v += resid[(size_t)m * N + n];
            if (act == 1) v = 0.5f * v * (1.0f + erff(v * 0.70710678118654752f));
            C[(size_t)m * N + n] = v;
        }
    }
}

// ---------------- small row-vector x matrix: out[b][j] = sum_k vec[b,k]*W[k,j] ----------------
__global__ __launch_bounds__(256) void vecmat_kernel(const float* __restrict__ vec,
                                                     const float* __restrict__ W,
                                                     float* __restrict__ out,
                                                     int K, int N)
{
    int b = blockIdx.y;
    int j = blockIdx.x * 256 + threadIdx.x;
    float acc = 0.0f;
    for (int k = 0; k < K; k++)
        acc += vec[(size_t)b * K + k] * W[(size_t)k * N + j];
    out[(size_t)b * N + j] = acc;
}

// ---------------- flash attention (fp32), 32 queries x 64-key tiles ----------------
#define QT 32
#define KT 64
__global__ __launch_bounds__(256) void attn_kernel(const float* __restrict__ Q,
                                                   const float* __restrict__ K,
                                                   const float* __restrict__ V,
                                                   const float* __restrict__ Km,
                                                   const float* __restrict__ Vm,
                                                   float* __restrict__ ao)
{
    __shared__ float Qs[QT][DHH + 1];
    __shared__ float Ks[KT][DHH + 1];
    __shared__ float Vs[KT][DHH + 1];
    __shared__ float Ps[QT][KT + 1];
    int bh = blockIdx.y;             // 0..B*H-1
    int b = bh / HH, h = bh % HH;
    int qt = blockIdx.x;             // 0..S/QT-1
    int tid = threadIdx.x;
    int q = tid >> 3, dg = tid & 7;  // q row 0..31, dim-group 0..7 (8 dims each)

    #pragma unroll
    for (int i = 0; i < 8; i++) {
        int idx = tid + i * 256;
        int r = idx >> 6, c = idx & 63;
        Qs[r][c] = Q[((size_t)(b * SS + qt * QT + r)) * DD + h * DHH + c] * 0.125f;
    }
    float m_run = -1e30f, l_run = 0.0f;
    float o_acc[8] = {0,0,0,0,0,0,0,0};

    for (int kt = 0; kt * KT < NK; kt++) {
        __syncthreads();
        #pragma unroll
        for (int i = 0; i < 16; i++) {
            int idx = tid + i * 256;      // 0..4095
            int kr = idx >> 6, c = idx & 63;
            int kk = kt * KT + kr;
            float kvK, kvV;
            if (kk == 0)      { kvK = Km[(size_t)b * DMM + h * DHH + c]; kvV = Vm[(size_t)b * DMM + h * DHH + c]; }
            else if (kk <= SS){ size_t off = ((size_t)(b * SS + kk - 1)) * DD + h * DHH + c; kvK = K[off]; kvV = V[off]; }
            else              { kvK = 0.0f; kvV = 0.0f; }
            Ks[kr][c] = kvK; Vs[kr][c] = kvV;
        }
        __syncthreads();
        float sv[8] = {0,0,0,0,0,0,0,0};
        for (int d = 0; d < DHH; d++) {
            float qv = Qs[q][d];
            #pragma unroll
            for (int j = 0; j < 8; j++) sv[j] += qv * Ks[dg * 8 + j][d];
        }
        int kbase = kt * KT + dg * 8;
        #pragma unroll
        for (int j = 0; j < 8; j++) if (kbase + j >= NK) sv[j] = -1e30f;
        float tm = sv[0];
        #pragma unroll
        for (int j = 1; j < 8; j++) tm = fmaxf(tm, sv[j]);
        #pragma unroll
        for (int off = 1; off < 8; off <<= 1) tm = fmaxf(tm, __shfl_xor(tm, off, 64));
        float m_new = fmaxf(m_run, tm);
        float alpha = __expf(m_run - m_new);
        float psum = 0.0f;
        #pragma unroll
        for (int j = 0; j < 8; j++) { float p = __expf(sv[j] - m_new); sv[j] = p; psum += p; }
        #pragma unroll
        for (int off = 1; off < 8; off <<= 1) psum += __shfl_xor(psum, off, 64);
        l_run = l_run * alpha + psum;
        m_run = m_new;
        #pragma unroll
        for (int i = 0; i < 8; i++) o_acc[i] *= alpha;
        #pragma unroll
        for (int j = 0; j < 8; j++) Ps[q][dg * 8 + j] = sv[j];
        __syncthreads();
        for (int k = 0; k < KT; k++) {
            float pv = Ps[q][k];
            #pragma unroll
            for (int i = 0; i < 8; i++) o_acc[i] += pv * Vs[k][dg * 8 + i];
        }
    }
    float inv_l = 1.0f / l_run;
    size_t orow = ((size_t)(b * SS + qt * QT + q)) * DD + h * DHH + dg * 8;
    #pragma unroll
    for (int i = 0; i < 8; i++) ao[orow + i] = o_acc[i] * inv_l;
}

// ---------------- mean pool stage 1: partial sums over 128-row chunks ----------------
__global__ __launch_bounds__(256) void pool1_kernel(const float* __restrict__ att, float* __restrict__ partial)
{
    int b = blockIdx.y, sc = blockIdx.x;   // sc in 0..15
    int tid = threadIdx.x;
    float4 acc = {0,0,0,0};
    for (int s = 0; s < 128; s++) {
        int row = b * SS + sc * 128 + s;
        float4 v = ((const float4*)(att + (size_t)row * DD))[tid];
        acc.x += v.x; acc.y += v.y; acc.z += v.z; acc.w += v.w;
    }
    ((float4*)(partial + ((size_t)b * 16 + sc) * DD))[tid] = acc;
}

// ---------------- mean pool stage 2: sum 16 partials, divide by S ----------------
__global__ __launch_bounds__(256) void pool2_kernel(const float* __restrict__ partial, float* __restrict__ pooled)
{
    int b = blockIdx.y;
    int j = blockIdx.x * 256 + threadIdx.x;
    float acc = 0.0f;
    for (int sc = 0; sc < 16; sc++) acc += partial[((size_t)b * 16 + sc) * DD + j];
    pooled[(size_t)b * DD + j] = acc * (1.0f / SS);
}

// ---------------- LSTM gates: gates[b][j] = pooled.Wih[:,j] + b_ih + h.Whh[:,j] + b_hh ----------------
__global__ __launch_bounds__(256) void gates_kernel(const float* __restrict__ pooled,
                                                    const float* __restrict__ h,
                                                    const float* __restrict__ Wih,
                                                    const float* __restrict__ Whh,
                                                    const float* __restrict__ b_ih,
                                                    const float* __restrict__ b_hh,
                                                    float* __restrict__ gates)
{
    int b = blockIdx.y;
    int j = blockIdx.x * 256 + threadIdx.x;   // 0..4095
    float acc = b_ih[j] + b_hh[j];
    for (int k = 0; k < DMM; k++)
        acc += pooled[(size_t)b * DMM + k] * Wih[(size_t)k * 4 * DMM + j]
             + h[(size_t)b * DMM + k]      * Whh[(size_t)k * 4 * DMM + j];
    gates[(size_t)b * 4 * DMM + j] = acc;
}

__device__ __forceinline__ float sigmoidf_(float x) { return 1.0f / (1.0f + __expf(-x)); }

// ---------------- LSTM cell ----------------
__global__ __launch_bounds__(256) void lstm_kernel(const float* __restrict__ gates,
                                                   const float* __restrict__ c,
                                                   float* __restrict__ newh_ws,
                                                   float* __restrict__ out_tail)   // d_out + B*S*D
{
    int idx = blockIdx.x * 256 + threadIdx.x;   // 0..B*DM-1
    int b = idx / DMM, d = idx % DMM;
    const float* g = gates + (size_t)b * 4 * DMM;
    float ig = sigmoidf_(g[d]);
    float fg = sigmoidf_(g[DMM + d]);
    float gg = tanhf(g[2 * DMM + d]);
    float og = sigmoidf_(g[3 * DMM + d]);
    float nc = fg * c[idx] + ig * gg;
    float nh = og * tanhf(nc);
    newh_ws[idx] = nh;
    out_tail[idx] = nh;              // new_h
    out_tail[BB * DMM + idx] = nc;   // new_c
}

// ---------------- launch ----------------
extern "C" void kernel_launch(void* const* d_in, const int* in_sizes, int n_in,
                              void* d_out, int out_size, void* d_ws, size_t ws_size,
                              hipStream_t stream) {
    const float* x    = (const float*)d_in[0];
    const float* h    = (const float*)d_in[1];
    const float* c    = (const float*)d_in[2];
    const float* Wq   = (const float*)d_in[3];
    const float* Wk   = (const float*)d_in[4];
    const float* Wv   = (const float*)d_in[5];
    const float* Wo   = (const float*)d_in[6];
    const float* Wmk  = (const float*)d_in[7];
    const float* Wmv  = (const float*)d_in[8];
    const float* Wih  = (const float*)d_in[9];
    const float* Whh  = (const float*)d_in[10];
    const float* b_ih = (const float*)d_in[11];
    const float* b_hh = (const float*)d_in[12];
    const float* W1   = (const float*)d_in[13];
    const float* bf1  = (const float*)d_in[14];
    const float* W2   = (const float*)d_in[15];
    const float* bf2  = (const float*)d_in[16];
    const float* g1   = (const float*)d_in[17];
    const float* be1  = (const float*)d_in[18];
    const float* g2   = (const float*)d_in[19];
    const float* be2  = (const float*)d_in[20];
    const float* g3   = (const float*)d_in[21];
    const float* be3  = (const float*)d_in[22];
    const float* Wmp  = (const float*)d_in[23];

    float* out = (float*)d_out;
    float* ws  = (float*)d_ws;

    const size_t MEG = 1024 * 1024;
    // buffer plan (element offsets). act (64MB region) overlays xn/Q/K/V which are dead by then.
    float* xn   = ws + 0;            // 4M elems
    float* Qb   = ws + 4 * MEG;      // 4M
    float* Kb   = ws + 8 * MEG;      // 4M
    float* Vb   = ws + 12 * MEG;     // 4M
    float* actb = ws + 0;            // 16M (overlays xn,Q,K,V)
    float* aob  = ws + 16 * MEG;     // 4M
    float* yb   = ws + 16 * MEG;     // 4M (overlays ao)
    float* attb = ws + 20 * MEG;     // 4M (attended -> mixed in-place)
    float* hnb  = ws + 24 * MEG;     // 4M
    float* sm   = ws + 28 * MEG;     // smalls
    float* Kmb     = sm;             // 2048
    float* Vmb     = sm + 2048;      // 2048
    float* partial = sm + 4096;      // 32768
    float* pooled  = sm + 4096 + 32768;          // 2048
    float* gatesb  = sm + 4096 + 32768 + 2048;   // 8192
    float* newh    = sm + 4096 + 32768 + 2048 + 8192;  // 2048
    float* mproj   = newh + 2048;    // 2048

    // 1. LN1
    ln_kernel<<<RR, 256, 0, stream>>>(x, nullptr, g1, be1, nullptr, xn);
    // 2-4. Q,K,V projections
    gemm_kernel<<<dim3(DD / BN, RR / BM), 256, 0, stream>>>(xn, Wq, Qb, RR, DD, DD, nullptr, nullptr, 0);
    gemm_kernel<<<dim3(DD / BN, RR / BM), 256, 0, stream>>>(xn, Wk, Kb, RR, DD, DD, nullptr, nullptr, 0);
    gemm_kernel<<<dim3(DD / BN, RR / BM), 256, 0, stream>>>(xn, Wv, Vb, RR, DD, DD, nullptr, nullptr, 0);
    // 5. memory K/V tokens
    vecmat_kernel<<<dim3(DD / 256, BB), 256, 0, stream>>>(h, Wmk, Kmb, DMM, DD);
    vecmat_kernel<<<dim3(DD / 256, BB), 256, 0, stream>>>(h, Wmv, Vmb, DMM, DD);
    // 6. attention
    attn_kernel<<<dim3(SS / QT, BB * HH), 256, 0, stream>>>(Qb, Kb, Vb, Kmb, Vmb, aob);
    // 7. attended = x + ao @ Wo
    gemm_kernel<<<dim3(DD / BN, RR / BM), 256, 0, stream>>>(aob, Wo, attb, RR, DD, DD, nullptr, x, 0);
    // 8-9. mean pool
    pool1_kernel<<<dim3(16, BB), 256, 0, stream>>>(attb, partial);
    pool2_kernel<<<dim3(DD / 256, BB), 256, 0, stream>>>(partial, pooled);
    // 10. gates
    gates_kernel<<<dim3(4 * DMM / 256, BB), 256, 0, stream>>>(pooled, h, Wih, Whh, b_ih, b_hh, gatesb);
    // 11. LSTM cell (writes new_h/new_c into d_out tail)
    lstm_kernel<<<dim3(BB * DMM / 256), 256, 0, stream>>>(gatesb, c, newh, out + (size_t)BB * SS * DD);
    // 12. mproj = new_h @ Wmp
    vecmat_kernel<<<dim3(DD / 256, BB), 256, 0, stream>>>(newh, Wmp, mproj, DMM, DD);
    // 13. mixed = attended + mproj (in place), hn = LN2(mixed)
    ln_kernel<<<RR, 256, 0, stream>>>(attb, mproj, g2, be2, attb, hnb);
    // 14. act = gelu(hn @ W1 + bf1)
    gemm_kernel<<<dim3(4 * DD / BN, RR / BM), 256, 0, stream>>>(hnb, W1, actb, RR, 4 * DD, DD, bf1, nullptr, 1);
    // 15. y = mixed + act @ W2 + bf2
    gemm_kernel<<<dim3(DD / BN, RR / BM), 256, 0, stream>>>(actb, W2, yb, RR, DD, 4 * DD, bf2, attb, 0);
    // 16. out = LN3(y)
    ln_kernel<<<RR, 256, 0, stream>>>(yb, nullptr, g3, be3, nullptr, out);
}

// Round 3
// 1223.290 us; speedup vs baseline: 3.7447x; 3.7447x over previous
//
#include <hip/hip_runtime.h>
#include <hip/hip_bf16.h>
#include <math.h>

#define BB 2
#define SS 2048
#define DD 1024
#define HH 16
#define RR (BB*SS)
#define KSTRIDE 2064   // padded key stride per (b,h)
#define MB (1024ull*1024ull)

typedef unsigned short u16;
typedef unsigned int u32;
typedef __attribute__((ext_vector_type(8))) short short8v;
typedef __attribute__((ext_vector_type(4))) float f32x4;
typedef __attribute__((ext_vector_type(16))) float f32x16;
typedef __attribute__((ext_vector_type(4))) u16 u16x4;

__device__ __forceinline__ u16 f2bf(float f){
    union { __hip_bfloat16 h; u16 u; } c; c.h = __float2bfloat16(f); return c.u;
}
__device__ __forceinline__ u32 pk2(float a, float b){
    return (u32)f2bf(a) | ((u32)f2bf(b) << 16);
}

#define GLL16(gp, lp) __builtin_amdgcn_global_load_lds( \
    (const __attribute__((address_space(1))) void*)(gp), \
    (__attribute__((address_space(3))) void*)(lp), 16, 0, 0)

// ---------------- LayerNorm: fp32 in, optional broadcast add, fp32 and/or bf16 out ----------------
__global__ __launch_bounds__(256) void ln_kernel(const float* __restrict__ in,
    const float* __restrict__ mproj, const float* __restrict__ g, const float* __restrict__ be,
    float* __restrict__ mixed_out, float* __restrict__ outf, u16* __restrict__ outb)
{
    int row = blockIdx.x; int b = row / SS; int tid = threadIdx.x;
    float4 v = ((const float4*)(in + (size_t)row*DD))[tid];
    if (mproj){
        float4 mp = ((const float4*)(mproj + (size_t)b*DD))[tid];
        v.x+=mp.x; v.y+=mp.y; v.z+=mp.z; v.w+=mp.w;
        ((float4*)(mixed_out + (size_t)row*DD))[tid] = v;
    }
    float s = v.x+v.y+v.z+v.w, s2 = v.x*v.x+v.y*v.y+v.z*v.z+v.w*v.w;
    #pragma unroll
    for (int off=32; off>0; off>>=1){ s += __shfl_down(s,off); s2 += __shfl_down(s2,off); }
    __shared__ float red[2][4];
    if ((tid&63)==0){ red[0][tid>>6]=s; red[1][tid>>6]=s2; }
    __syncthreads();
    float st = red[0][0]+red[0][1]+red[0][2]+red[0][3];
    float s2t= red[1][0]+red[1][1]+red[1][2]+red[1][3];
    float mean = st*(1.f/DD); float var = s2t*(1.f/DD)-mean*mean;
    float rs = rsqrtf(var + 1e-5f);
    float4 gg=((const float4*)g)[tid], bb2=((const float4*)be)[tid];
    float o0=(v.x-mean)*rs*gg.x+bb2.x, o1=(v.y-mean)*rs*gg.y+bb2.y;
    float o2=(v.z-mean)*rs*gg.z+bb2.z, o3=(v.w-mean)*rs*gg.w+bb2.w;
    if (outf){ float4 o={o0,o1,o2,o3}; ((float4*)(outf+(size_t)row*DD))[tid]=o; }
    if (outb){ u16x4 o={f2bf(o0),f2bf(o1),f2bf(o2),f2bf(o3)}; ((u16x4*)(outb+(size_t)row*DD))[tid]=o; }
}

// ---------------- fp32 [K][N] -> bf16 [N][K] transpose ----------------
__global__ __launch_bounds__(256) void tr_kernel(const float* __restrict__ in, u16* __restrict__ out,
                                                 int K, int N)
{
    __shared__ float t[32][33];
    int n0 = blockIdx.x*32, k0 = blockIdx.y*32;
    int tx = threadIdx.x & 31, ty = threadIdx.x >> 5;   // ty 0..7
    #pragma unroll
    for (int i=0;i<4;i++){ int k = ty + i*8; t[k][tx] = in[(size_t)(k0+k)*N + n0 + tx]; }
    __syncthreads();
    #pragma unroll
    for (int i=0;i<4;i++){ int n = ty + i*8; out[(size_t)(n0+n)*K + k0 + tx] = f2bf(t[tx][n]); }
}

// ---------------- bf16 MFMA GEMM: C = A[M,K] @ BT[N,K]^T, 128x128x32 tiles ----------------
#define MODE_Q    0  // bf16 out, *scale
#define MODE_K    1  // bf16 -> Kbuf [b,h,key,dh]
#define MODE_V    2  // bf16 -> VT   [b,h,dh,key]
#define MODE_F32R 3  // f32 + resid
#define MODE_GELU 4  // bf16, +bias, gelu
#define MODE_F32BR 5 // f32 + bias + resid

__global__ __launch_bounds__(256) void mgemm(const u16* __restrict__ A, const u16* __restrict__ BT,
    int M, int N, int K, int mode, const float* __restrict__ bias, const float* __restrict__ resid,
    float scale, void* __restrict__ Cout)
{
    __shared__ __align__(16) u16 Al[2][4096];
    __shared__ __align__(16) u16 Bl[2][4096];
    int tid=threadIdx.x, l=tid&63, w=tid>>6;
    int bm = blockIdx.y*128, bn = blockIdx.x*128;
    int wr = w>>1, wc = w&1;
    f32x4 acc[4][4];
    #pragma unroll
    for(int i=0;i<4;i++)
        #pragma unroll
        for(int j=0;j<4;j++)
            #pragma unroll
            for(int r=0;r<4;r++) acc[i][j][r]=0.f;

    int srow = (w<<4) + (l>>2);     // staging row (+64 per issue)
    int sph  = l&3;                 // physical 16B slot
    const int NT = K >> 5;

    auto stage = [&](int buf, int kt){
        #pragma unroll
        for (int r=0;r<2;r++){
            int rowA = srow + r*64;
            int slA = sph ^ ((rowA>>1)&3);
            const u16* gA = A + (size_t)(bm+rowA)*K + kt*32 + slA*8;
            GLL16(gA, (char*)&Al[buf][0] + r*4096 + w*1024);
            int slB = sph ^ ((rowA>>1)&3);
            const u16* gB = BT + (size_t)(bn+rowA)*K + kt*32 + slB*8;
            GLL16(gB, (char*)&Bl[buf][0] + r*4096 + w*1024);
        }
    };

    int cur=0;
    stage(0,0);
    __syncthreads();
    for (int kt=0; kt<NT; kt++){
        if (kt+1<NT) stage(cur^1, kt+1);
        short8v af[4], bf[4];
        #pragma unroll
        for (int mi=0;mi<4;mi++){
            int row = wr*64 + mi*16 + (l&15);
            int sl = (l>>4) ^ ((row>>1)&3);
            af[mi] = *(const short8v*)((const char*)&Al[cur][0] + row*64 + sl*16);
        }
        #pragma unroll
        for (int ni=0;ni<4;ni++){
            int row = wc*64 + ni*16 + (l&15);
            int sl = (l>>4) ^ ((row>>1)&3);
            bf[ni] = *(const short8v*)((const char*)&Bl[cur][0] + row*64 + sl*16);
        }
        #pragma unroll
        for (int mi=0;mi<4;mi++)
            #pragma unroll
            for (int ni=0;ni<4;ni++)
                acc[mi][ni] = __builtin_amdgcn_mfma_f32_16x16x32_bf16(af[mi], bf[ni], acc[mi][ni], 0,0,0);
        __syncthreads();   // drains vmcnt(0): next tile staged; protects re-stage of cur
        cur ^= 1;
    }

    #pragma unroll
    for (int mi=0;mi<4;mi++){
        #pragma unroll
        for (int ni=0;ni<4;ni++){
            int col = bn + wc*64 + ni*16 + (l&15);
            int rbase = bm + wr*64 + mi*16 + ((l>>4)<<2);
            if (mode==MODE_V){
                int b = rbase>>11; int key = rbase&2047;
                int h = col>>6, dh = col&63;
                u16x4 pkv;
                #pragma unroll
                for (int r=0;r<4;r++) pkv[r] = f2bf(acc[mi][ni][r]);
                *(u16x4*)((u16*)Cout + ((size_t)(b*HH+h)*64 + dh)*KSTRIDE + key) = pkv;
            } else {
                #pragma unroll
                for (int r=0;r<4;r++){
                    int m = rbase + r;
                    float v = acc[mi][ni][r];
                    if (mode==MODE_Q){
                        ((u16*)Cout)[(size_t)m*N + col] = f2bf(v*scale);
                    } else if (mode==MODE_K){
                        int b=m>>11, key=m&2047, h=col>>6, dh=col&63;
                        ((u16*)Cout)[((size_t)(b*HH+h)*KSTRIDE + key)*64 + dh] = f2bf(v);
                    } else if (mode==MODE_F32R){
                        ((float*)Cout)[(size_t)m*N+col] = v + resid[(size_t)m*N+col];
                    } else if (mode==MODE_GELU){
                        v += bias[col];
                        v = 0.5f*v*(1.0f+erff(v*0.70710678118654752f));
                        ((u16*)Cout)[(size_t)m*N+col] = f2bf(v);
                    } else {
                        v += bias[col] + resid[(size_t)m*N+col];
                        ((float*)Cout)[(size_t)m*N+col] = v;
                    }
                }
            }
        }
    }
}

// ---------------- MFMA flash attention: 32x32x16, swapped QK^T, V pre-transposed ----------------
__global__ __launch_bounds__(256) void attn_mfma(const u16* __restrict__ Qb, const u16* __restrict__ Kb,
    const u16* __restrict__ VTb, u16* __restrict__ ao)
{
    __shared__ __align__(16) u16 Kl[2][4096];  // [key 64][dh 64], slot-XOR swizzled
    __shared__ __align__(16) u16 Vl[2][4096];  // [dh 64][key 64], slot-XOR swizzled
    int tid=threadIdx.x, l=tid&63, w=tid>>6;
    int l31=l&31, hi=l>>5;
    int qt=blockIdx.x, bh=blockIdx.y; int b=bh>>4, h=bh&15;
    int qrow = qt*128 + w*32 + l31;

    const u16* qptr = Qb + (size_t)(b*SS + qrow)*DD + h*64;
    short8v qf[4];
    #pragma unroll
    for (int t=0;t<4;t++) qf[t] = *(const short8v*)(qptr + t*16 + hi*8);

    f32x16 so0, so1;
    #pragma unroll
    for (int i=0;i<16;i++){ so0[i]=0.f; so1[i]=0.f; }
    float m_run=-1e30f, l_run=0.f;

    int skey = (w<<3) + (l>>3);   // staging row (+32 per issue)
    int ssl  = l&7;
    auto stage = [&](int buf, int kt){
        #pragma unroll
        for (int r=0;r<2;r++){
            int key = skey + r*32;
            int slot = ssl ^ (key&7);
            const u16* gK = Kb + ((size_t)bh*KSTRIDE + kt*64 + key)*64 + slot*8;
            GLL16(gK, (char*)&Kl[buf][0] + r*4096 + w*1024);
            int slv = ssl ^ (key&7);
            const u16* gV = VTb + ((size_t)bh*64 + key)*KSTRIDE + kt*64 + slv*8;
            GLL16(gV, (char*)&Vl[buf][0] + r*4096 + w*1024);
        }
    };

    int cur=0;
    stage(0,0);
    __syncthreads();
    const int NTILE = 33;
    for (int kt=0; kt<NTILE; kt++){
        if (kt+1<NTILE) stage(cur^1, kt+1);
        f32x16 ss0, ss1;
        #pragma unroll
        for (int i=0;i<16;i++){ ss0[i]=0.f; ss1[i]=0.f; }
        #pragma unroll
        for (int t=0;t<4;t++){
            int sl = (2*t+hi) ^ (l31&7);
            short8v kf0 = *(const short8v*)((const char*)&Kl[cur][0] + l31*128 + sl*16);
            ss0 = __builtin_amdgcn_mfma_f32_32x32x16_bf16(kf0, qf[t], ss0, 0,0,0);
            short8v kf1 = *(const short8v*)((const char*)&Kl[cur][0] + (32+l31)*128 + sl*16);
            ss1 = __builtin_amdgcn_mfma_f32_32x32x16_bf16(kf1, qf[t], ss1, 0,0,0);
        }
        if (kt == NTILE-1){
            #pragma unroll
            for (int r=0;r<16;r++){
                int k0 = 2048 + (r&3) + 8*(r>>2) + 4*hi;
                if (k0 >= 2049) ss0[r] = -1e30f;
                ss1[r] = -1e30f;   // keys 2080..2111 all masked
            }
        }
        float tmax=-1e30f;
        #pragma unroll
        for (int r=0;r<16;r++){ tmax=fmaxf(tmax, ss0[r]); tmax=fmaxf(tmax, ss1[r]); }
        tmax = fmaxf(tmax, __shfl_xor(tmax, 32));
        float mnew = fmaxf(m_run, tmax);
        float alpha = __expf(m_run - mnew);
        float psum = 0.f;
        #pragma unroll
        for (int r=0;r<16;r++){
            float p=__expf(ss0[r]-mnew); ss0[r]=p; psum+=p;
            float q=__expf(ss1[r]-mnew); ss1[r]=q; psum+=q;
        }
        psum += __shfl_xor(psum, 32);
        l_run = l_run*alpha + psum;
        m_run = mnew;
        so0 *= alpha; so1 *= alpha;

        // build P A-frags (B-operand for O^T mfma): slot j <-> key 16t+8hi+j
        short8v pf[4];
        #pragma unroll
        for (int t=0;t<4;t++){
            u32 a0,a1,b0,b1;
            if (t==0){ a0=pk2(ss0[0],ss0[1]);   a1=pk2(ss0[2],ss0[3]);   b0=pk2(ss0[4],ss0[5]);   b1=pk2(ss0[6],ss0[7]); }
            else if (t==1){ a0=pk2(ss0[8],ss0[9]);   a1=pk2(ss0[10],ss0[11]); b0=pk2(ss0[12],ss0[13]); b1=pk2(ss0[14],ss0[15]); }
            else if (t==2){ a0=pk2(ss1[0],ss1[1]);   a1=pk2(ss1[2],ss1[3]);   b0=pk2(ss1[4],ss1[5]);   b1=pk2(ss1[6],ss1[7]); }
            else          { a0=pk2(ss1[8],ss1[9]);   a1=pk2(ss1[10],ss1[11]); b0=pk2(ss1[12],ss1[13]); b1=pk2(ss1[14],ss1[15]); }
            u32 s0 = hi ? a0 : b0, s1 = hi ? a1 : b1;
            u32 r0 = (u32)__shfl_xor((int)s0, 32);
            u32 r1 = (u32)__shfl_xor((int)s1, 32);
            union { u32 u[4]; short8v v; } cvt;
            cvt.u[0] = hi ? r0 : a0;
            cvt.u[1] = hi ? r1 : a1;
            cvt.u[2] = hi ? b0 : r0;
            cvt.u[3] = hi ? b1 : r1;
            pf[t] = cvt.v;
        }
        #pragma unroll
        for (int t=0;t<4;t++){
            int sl = (2*t+hi) ^ (l31&7);
            short8v vf0 = *(const short8v*)((const char*)&Vl[cur][0] + l31*128 + sl*16);
            so0 = __builtin_amdgcn_mfma_f32_32x32x16_bf16(vf0, pf[t], so0, 0,0,0);
            short8v vf1 = *(const short8v*)((const char*)&Vl[cur][0] + (32+l31)*128 + sl*16);
            so1 = __builtin_amdgcn_mfma_f32_32x32x16_bf16(vf1, pf[t], so1, 0,0,0);
        }
        __syncthreads();
        cur ^= 1;
    }
    float inv = 1.f / l_run;
    u16* aop = ao + (size_t)(b*SS + qrow)*DD + h*64;
    #pragma unroll
    for (int rg=0; rg<4; rg++){
        int dh0 = rg*8 + 4*hi;
        u16x4 o0, o1;
        #pragma unroll
        for (int j=0;j<4;j++){ o0[j]=f2bf(so0[rg*4+j]*inv); o1[j]=f2bf(so1[rg*4+j]*inv); }
        *(u16x4*)(aop + dh0) = o0;
        *(u16x4*)(aop + 32 + dh0) = o1;
    }
}

// ---------------- small helpers (fp32) ----------------
__global__ __launch_bounds__(256) void vecmat_kernel(const float* __restrict__ vec,
    const float* __restrict__ W, float* __restrict__ out, int K, int N)
{
    int b = blockIdx.y;
    int j = blockIdx.x * 256 + threadIdx.x;
    float acc = 0.0f;
    for (int k = 0; k < K; k++) acc += vec[(size_t)b*K + k] * W[(size_t)k*N + j];
    out[(size_t)b*N + j] = acc;
}

__global__ __launch_bounds__(256) void fixup_kernel(const float* __restrict__ Kmb,
    const float* __restrict__ Vmb, u16* __restrict__ Kb, u16* __restrict__ VTb)
{
    int idx = blockIdx.x*256 + threadIdx.x;   // 0..2047
    int b = idx>>10, j = idx&1023; int h=j>>6, dh=j&63; int bh=b*HH+h;
    Kb[((size_t)bh*KSTRIDE + 2048)*64 + dh] = f2bf(Kmb[idx]);
    VTb[((size_t)bh*64 + dh)*KSTRIDE + 2048] = f2bf(Vmb[idx]);
}

__global__ __launch_bounds__(256) void pool1_kernel(const float* __restrict__ att, float* __restrict__ partial)
{
    int b = blockIdx.y, sc = blockIdx.x;
    int tid = threadIdx.x;
    float4 acc = {0,0,0,0};
    for (int s = 0; s < 128; s++) {
        int row = b*SS + sc*128 + s;
        float4 v = ((const float4*)(att + (size_t)row*DD))[tid];
        acc.x += v.x; acc.y += v.y; acc.z += v.z; acc.w += v.w;
    }
    ((float4*)(partial + ((size_t)b*16 + sc)*DD))[tid] = acc;
}

__global__ __launch_bounds__(256) void pool2_kernel(const float* __restrict__ partial, float* __restrict__ pooled)
{
    int b = blockIdx.y;
    int j = blockIdx.x*256 + threadIdx.x;
    float acc = 0.0f;
    for (int sc = 0; sc < 16; sc++) acc += partial[((size_t)b*16 + sc)*DD + j];
    pooled[(size_t)b*DD + j] = acc * (1.0f/SS);
}

__global__ __launch_bounds__(256) void gates_kernel(const float* __restrict__ pooled,
    const float* __restrict__ h, const float* __restrict__ Wih, const float* __restrict__ Whh,
    const float* __restrict__ b_ih, const float* __restrict__ b_hh, float* __restrict__ gates)
{
    int b = blockIdx.y;
    int j = blockIdx.x*256 + threadIdx.x;
    float acc = b_ih[j] + b_hh[j];
    for (int k = 0; k < DD; k++)
        acc += pooled[(size_t)b*DD + k] * Wih[(size_t)k*4*DD + j]
             + h[(size_t)b*DD + k]      * Whh[(size_t)k*4*DD + j];
    gates[(size_t)b*4*DD + j] = acc;
}

__device__ __forceinline__ float sigmoidf_(float x) { return 1.0f / (1.0f + __expf(-x)); }

__global__ __launch_bounds__(256) void lstm_kernel(const float* __restrict__ gates,
    const float* __restrict__ c, float* __restrict__ newh_ws, float* __restrict__ out_tail)
{
    int idx = blockIdx.x*256 + threadIdx.x;
    int b = idx >> 10, d = idx & 1023;
    const float* g = gates + (size_t)b*4*DD;
    float ig = sigmoidf_(g[d]);
    float fg = sigmoidf_(g[DD + d]);
    float gg = tanhf(g[2*DD + d]);
    float og = sigmoidf_(g[3*DD + d]);
    float nc = fg * c[idx] + ig * gg;
    float nh = og * tanhf(nc);
    newh_ws[idx] = nh;
    out_tail[idx] = nh;
    out_tail[BB*DD + idx] = nc;
}

// ---------------- launch ----------------
extern "C" void kernel_launch(void* const* d_in, const int* in_sizes, int n_in,
                              void* d_out, int out_size, void* d_ws, size_t ws_size,
                              hipStream_t stream) {
    const float* x    = (const float*)d_in[0];
    const float* h    = (const float*)d_in[1];
    const float* c    = (const float*)d_in[2];
    const float* Wq   = (const float*)d_in[3];
    const float* Wk   = (const float*)d_in[4];
    const float* Wv   = (const float*)d_in[5];
    const float* Wo   = (const float*)d_in[6];
    const float* Wmk  = (const float*)d_in[7];
    const float* Wmv  = (const float*)d_in[8];
    const float* Wih  = (const float*)d_in[9];
    const float* Whh  = (const float*)d_in[10];
    const float* b_ih = (const float*)d_in[11];
    const float* b_hh = (const float*)d_in[12];
    const float* W1   = (const float*)d_in[13];
    const float* bf1  = (const float*)d_in[14];
    const float* W2   = (const float*)d_in[15];
    const float* bf2  = (const float*)d_in[16];
    const float* g1   = (const float*)d_in[17];
    const float* be1  = (const float*)d_in[18];
    const float* g2   = (const float*)d_in[19];
    const float* be2  = (const float*)d_in[20];
    const float* g3   = (const float*)d_in[21];
    const float* be3  = (const float*)d_in[22];
    const float* Wmp  = (const float*)d_in[23];

    float* out = (float*)d_out;
    char* wsb  = (char*)d_ws;

    u16*   xn   = (u16*)(wsb + 0);        // 8MB  [0,8)
    u16*   hn   = (u16*)(wsb + 8*MB);     // 8MB  [8,16)
    float* yb   = (float*)(wsb + 0);      // 16MB overlay [0,16) (xn,hn dead)
    u16*   Qbuf = (u16*)(wsb + 16*MB);    // 8MB  [16,24)
    u16*   Kbuf = (u16*)(wsb + 24*MB);    // 8.5MB [24,33)
    u16*   VTb  = (u16*)(wsb + 33*MB);    // 8.5MB [33,42)
    u16*   act  = (u16*)(wsb + 16*MB);    // 32MB overlay [16,48) (Q/K/VT dead)
    u16*   ao   = (u16*)(wsb + 48*MB);    // 8MB  [48,56)
    float* attb = (float*)(wsb + 56*MB);  // 16MB [56,72)
    u16*   WqT  = (u16*)(wsb + 72*MB);
    u16*   WkT  = (u16*)(wsb + 74*MB);
    u16*   WvT  = (u16*)(wsb + 76*MB);
    u16*   WoT  = (u16*)(wsb + 78*MB);
    u16*   W1T  = (u16*)(wsb + 80*MB);    // [80,88)
    u16*   W2T  = (u16*)(wsb + 88*MB);    // [88,96)
    float* sm   = (float*)(wsb + 96*MB);
    float* Kmb     = sm;
    float* Vmb     = sm + 2048;
    float* partial = sm + 4096;
    float* pooled  = partial + 32768;
    float* gatesb  = pooled + 2048;
    float* newh    = gatesb + 8192;
    float* mproj   = newh + 2048;

    // weight transposes (fp32 [K][N] -> bf16 [N][K])
    tr_kernel<<<dim3(32,32), 256, 0, stream>>>(Wq, WqT, 1024, 1024);
    tr_kernel<<<dim3(32,32), 256, 0, stream>>>(Wk, WkT, 1024, 1024);
    tr_kernel<<<dim3(32,32), 256, 0, stream>>>(Wv, WvT, 1024, 1024);
    tr_kernel<<<dim3(32,32), 256, 0, stream>>>(Wo, WoT, 1024, 1024);
    tr_kernel<<<dim3(128,32), 256, 0, stream>>>(W1, W1T, 1024, 4096);
    tr_kernel<<<dim3(32,128), 256, 0, stream>>>(W2, W2T, 4096, 1024);

    // LN1 -> xn bf16
    ln_kernel<<<RR, 256, 0, stream>>>(x, nullptr, g1, be1, nullptr, nullptr, xn);
    // memory K/V tokens (fp32)
    vecmat_kernel<<<dim3(4, BB), 256, 0, stream>>>(h, Wmk, Kmb, DD, DD);
    vecmat_kernel<<<dim3(4, BB), 256, 0, stream>>>(h, Wmv, Vmb, DD, DD);
    // Q,K,V projections (MFMA)
    mgemm<<<dim3(8,32), 256, 0, stream>>>(xn, WqT, RR, DD, DD, MODE_Q, nullptr, nullptr, 0.125f, Qbuf);
    mgemm<<<dim3(8,32), 256, 0, stream>>>(xn, WkT, RR, DD, DD, MODE_K, nullptr, nullptr, 1.f, Kbuf);
    mgemm<<<dim3(8,32), 256, 0, stream>>>(xn, WvT, RR, DD, DD, MODE_V, nullptr, nullptr, 1.f, VTb);
    fixup_kernel<<<8, 256, 0, stream>>>(Kmb, Vmb, Kbuf, VTb);
    // attention
    attn_mfma<<<dim3(16,32), 256, 0, stream>>>(Qbuf, Kbuf, VTb, ao);
    // attended = x + ao @ Wo  (fp32)
    mgemm<<<dim3(8,32), 256, 0, stream>>>(ao, WoT, RR, DD, DD, MODE_F32R, nullptr, x, 1.f, attb);
    // mean pool, LSTM
    pool1_kernel<<<dim3(16,BB), 256, 0, stream>>>(attb, partial);
    pool2_kernel<<<dim3(4,BB), 256, 0, stream>>>(partial, pooled);
    gates_kernel<<<dim3(16,BB), 256, 0, stream>>>(pooled, h, Wih, Whh, b_ih, b_hh, gatesb);
    lstm_kernel<<<8, 256, 0, stream>>>(gatesb, c, newh, out + (size_t)RR*DD);
    vecmat_kernel<<<dim3(4,BB), 256, 0, stream>>>(newh, Wmp, mproj, DD, DD);
    // mixed = attended + mproj (in place), hn = LN2(mixed) bf16
    ln_kernel<<<RR, 256, 0, stream>>>(attb, mproj, g2, be2, attb, nullptr, hn);
    // FFN
    mgemm<<<dim3(32,32), 256, 0, stream>>>(hn, W1T, RR, 4*DD, DD, MODE_GELU, bf1, nullptr, 1.f, act);
    mgemm<<<dim3(8,32), 256, 0, stream>>>(act, W2T, RR, DD, 4*DD, MODE_F32BR, bf2, attb, 1.f, yb);
    // out = LN3(y)
    ln_kernel<<<RR, 256, 0, stream>>>(yb, nullptr, g3, be3, nullptr, out, nullptr);
}

// Round 5
// 489.067 us; speedup vs baseline: 9.3666x; 2.5013x over previous
//
#include <hip/hip_runtime.h>
#include <hip/hip_bf16.h>
#include <math.h>

#define BB 2
#define SS 2048
#define DD 1024
#define HH 16
#define RR (BB*SS)
#define KSTRIDE 2064   // padded key stride per (b,h)
#define MB (1024ull*1024ull)

typedef unsigned short u16;
typedef unsigned int u32;
typedef __attribute__((ext_vector_type(8))) short short8v;
typedef __attribute__((ext_vector_type(4))) float f32x4;
typedef __attribute__((ext_vector_type(16))) float f32x16;
typedef __attribute__((ext_vector_type(4))) u16 u16x4;

__device__ __forceinline__ u16 f2bf(float f){
    union { __hip_bfloat16 h; u16 u; } c; c.h = __float2bfloat16(f); return c.u;
}
__device__ __forceinline__ u32 pk2(float a, float b){
    return (u32)f2bf(a) | ((u32)f2bf(b) << 16);
}

#define GLL16(gp, lp) __builtin_amdgcn_global_load_lds( \
    (const __attribute__((address_space(1))) void*)(gp), \
    (__attribute__((address_space(3))) void*)(lp), 16, 0, 0)

// ---------------- LayerNorm: fp32 in, optional broadcast add, fp32 and/or bf16 out ----------------
__global__ __launch_bounds__(256) void ln_kernel(const float* __restrict__ in,
    const float* __restrict__ mproj, const float* __restrict__ g, const float* __restrict__ be,
    float* __restrict__ mixed_out, float* __restrict__ outf, u16* __restrict__ outb)
{
    int row = blockIdx.x; int b = row / SS; int tid = threadIdx.x;
    float4 v = ((const float4*)(in + (size_t)row*DD))[tid];
    if (mproj){
        float4 mp = ((const float4*)(mproj + (size_t)b*DD))[tid];
        v.x+=mp.x; v.y+=mp.y; v.z+=mp.z; v.w+=mp.w;
        ((float4*)(mixed_out + (size_t)row*DD))[tid] = v;
    }
    float s = v.x+v.y+v.z+v.w, s2 = v.x*v.x+v.y*v.y+v.z*v.z+v.w*v.w;
    #pragma unroll
    for (int off=32; off>0; off>>=1){ s += __shfl_down(s,off); s2 += __shfl_down(s2,off); }
    __shared__ float red[2][4];
    if ((tid&63)==0){ red[0][tid>>6]=s; red[1][tid>>6]=s2; }
    __syncthreads();
    float st = red[0][0]+red[0][1]+red[0][2]+red[0][3];
    float s2t= red[1][0]+red[1][1]+red[1][2]+red[1][3];
    float mean = st*(1.f/DD); float var = s2t*(1.f/DD)-mean*mean;
    float rs = rsqrtf(var + 1e-5f);
    float4 gg=((const float4*)g)[tid], bb2=((const float4*)be)[tid];
    float o0=(v.x-mean)*rs*gg.x+bb2.x, o1=(v.y-mean)*rs*gg.y+bb2.y;
    float o2=(v.z-mean)*rs*gg.z+bb2.z, o3=(v.w-mean)*rs*gg.w+bb2.w;
    if (outf){ float4 o={o0,o1,o2,o3}; ((float4*)(outf+(size_t)row*DD))[tid]=o; }
    if (outb){ u16x4 o={f2bf(o0),f2bf(o1),f2bf(o2),f2bf(o3)}; ((u16x4*)(outb+(size_t)row*DD))[tid]=o; }
}

// ---------------- fp32 [K][N] -> bf16 [N][K] transpose ----------------
__global__ __launch_bounds__(256) void tr_kernel(const float* __restrict__ in, u16* __restrict__ out,
                                                 int K, int N)
{
    __shared__ float t[32][33];
    int n0 = blockIdx.x*32, k0 = blockIdx.y*32;
    int tx = threadIdx.x & 31, ty = threadIdx.x >> 5;   // ty 0..7
    #pragma unroll
    for (int i=0;i<4;i++){ int k = ty + i*8; t[k][tx] = in[(size_t)(k0+k)*N + n0 + tx]; }
    __syncthreads();
    #pragma unroll
    for (int i=0;i<4;i++){ int n = ty + i*8; out[(size_t)(n0+n)*K + k0 + tx] = f2bf(t[tx][n]); }
}

// ---------------- bf16 MFMA GEMM: C = A[M,K] @ BT[N,K]^T, 128x128x32 tiles ----------------
#define MODE_Q    0  // bf16 out, *scale
#define MODE_K    1  // bf16 -> Kbuf [b,h,key,dh]
#define MODE_V    2  // bf16 -> VT   [b,h,dh,key]
#define MODE_F32R 3  // f32 + resid
#define MODE_GELU 4  // bf16, +bias, gelu
#define MODE_F32BR 5 // f32 + bias + resid

__global__ __launch_bounds__(256) void mgemm(const u16* __restrict__ A, const u16* __restrict__ BT,
    int M, int N, int K, int mode, const float* __restrict__ bias, const float* __restrict__ resid,
    float scale, void* __restrict__ Cout)
{
    __shared__ __align__(16) u16 Al[2][4096];
    __shared__ __align__(16) u16 Bl[2][4096];
    int tid=threadIdx.x, l=tid&63, w=tid>>6;
    int bm = blockIdx.y*128, bn = blockIdx.x*128;
    int wr = w>>1, wc = w&1;
    f32x4 acc[4][4];
    #pragma unroll
    for(int i=0;i<4;i++)
        #pragma unroll
        for(int j=0;j<4;j++)
            #pragma unroll
            for(int r=0;r<4;r++) acc[i][j][r]=0.f;

    int srow = (w<<4) + (l>>2);     // staging row (+64 per issue)
    int sph  = l&3;                 // physical 16B slot
    const int NT = K >> 5;

    auto stage = [&](int buf, int kt){
        #pragma unroll
        for (int r=0;r<2;r++){
            int rowA = srow + r*64;
            int slA = sph ^ ((rowA>>1)&3);
            const u16* gA = A + (size_t)(bm+rowA)*K + kt*32 + slA*8;
            GLL16(gA, (char*)&Al[buf][0] + r*4096 + w*1024);
            int slB = sph ^ ((rowA>>1)&3);
            const u16* gB = BT + (size_t)(bn+rowA)*K + kt*32 + slB*8;
            GLL16(gB, (char*)&Bl[buf][0] + r*4096 + w*1024);
        }
    };

    int cur=0;
    stage(0,0);
    __syncthreads();
    for (int kt=0; kt<NT; kt++){
        if (kt+1<NT) stage(cur^1, kt+1);
        short8v af[4], bf[4];
        #pragma unroll
        for (int mi=0;mi<4;mi++){
            int row = wr*64 + mi*16 + (l&15);
            int sl = (l>>4) ^ ((row>>1)&3);
            af[mi] = *(const short8v*)((const char*)&Al[cur][0] + row*64 + sl*16);
        }
        #pragma unroll
        for (int ni=0;ni<4;ni++){
            int row = wc*64 + ni*16 + (l&15);
            int sl = (l>>4) ^ ((row>>1)&3);
            bf[ni] = *(const short8v*)((const char*)&Bl[cur][0] + row*64 + sl*16);
        }
        #pragma unroll
        for (int mi=0;mi<4;mi++)
            #pragma unroll
            for (int ni=0;ni<4;ni++)
                acc[mi][ni] = __builtin_amdgcn_mfma_f32_16x16x32_bf16(af[mi], bf[ni], acc[mi][ni], 0,0,0);
        __syncthreads();   // drains vmcnt(0): next tile staged; protects re-stage of cur
        cur ^= 1;
    }

    #pragma unroll
    for (int mi=0;mi<4;mi++){
        #pragma unroll
        for (int ni=0;ni<4;ni++){
            int col = bn + wc*64 + ni*16 + (l&15);
            int rbase = bm + wr*64 + mi*16 + ((l>>4)<<2);
            if (mode==MODE_V){
                int b = rbase>>11; int key = rbase&2047;
                int h = col>>6, dh = col&63;
                u16x4 pkv;
                #pragma unroll
                for (int r=0;r<4;r++) pkv[r] = f2bf(acc[mi][ni][r]);
                *(u16x4*)((u16*)Cout + ((size_t)(b*HH+h)*64 + dh)*KSTRIDE + key) = pkv;
            } else {
                #pragma unroll
                for (int r=0;r<4;r++){
                    int m = rbase + r;
                    float v = acc[mi][ni][r];
                    if (mode==MODE_Q){
                        ((u16*)Cout)[(size_t)m*N + col] = f2bf(v*scale);
                    } else if (mode==MODE_K){
                        int b=m>>11, key=m&2047, h=col>>6, dh=col&63;
                        ((u16*)Cout)[((size_t)(b*HH+h)*KSTRIDE + key)*64 + dh] = f2bf(v);
                    } else if (mode==MODE_F32R){
                        ((float*)Cout)[(size_t)m*N+col] = v + resid[(size_t)m*N+col];
                    } else if (mode==MODE_GELU){
                        v += bias[col];
                        v = 0.5f*v*(1.0f+erff(v*0.70710678118654752f));
                        ((u16*)Cout)[(size_t)m*N+col] = f2bf(v);
                    } else {
                        v += bias[col] + resid[(size_t)m*N+col];
                        ((float*)Cout)[(size_t)m*N+col] = v;
                    }
                }
            }
        }
    }
}

// ---------------- MFMA flash attention: 32x32x16, swapped QK^T, V pre-transposed ----------------
__global__ __launch_bounds__(256) void attn_mfma(const u16* __restrict__ Qb, const u16* __restrict__ Kb,
    const u16* __restrict__ VTb, u16* __restrict__ ao)
{
    __shared__ __align__(16) u16 Kl[2][4096];  // [key 64][dh 64], slot-XOR swizzled
    __shared__ __align__(16) u16 Vl[2][4096];  // [dh 64][key 64], slot-XOR swizzled
    int tid=threadIdx.x, l=tid&63, w=tid>>6;
    int l31=l&31, hi=l>>5;
    int qt=blockIdx.x, bh=blockIdx.y; int b=bh>>4, h=bh&15;
    int qrow = qt*128 + w*32 + l31;

    const u16* qptr = Qb + (size_t)(b*SS + qrow)*DD + h*64;
    short8v qf[4];
    #pragma unroll
    for (int t=0;t<4;t++) qf[t] = *(const short8v*)(qptr + t*16 + hi*8);

    f32x16 so0, so1;
    #pragma unroll
    for (int i=0;i<16;i++){ so0[i]=0.f; so1[i]=0.f; }
    float m_run=-1e30f, l_run=0.f;

    int skey = (w<<3) + (l>>3);   // staging row (+32 per issue)
    int ssl  = l&7;
    auto stage = [&](int buf, int kt){
        #pragma unroll
        for (int r=0;r<2;r++){
            int key = skey + r*32;
            int slot = ssl ^ (key&7);
            const u16* gK = Kb + ((size_t)bh*KSTRIDE + kt*64 + key)*64 + slot*8;
            GLL16(gK, (char*)&Kl[buf][0] + r*4096 + w*1024);
            int slv = ssl ^ (key&7);
            const u16* gV = VTb + ((size_t)bh*64 + key)*KSTRIDE + kt*64 + slv*8;
            GLL16(gV, (char*)&Vl[buf][0] + r*4096 + w*1024);
        }
    };

    int cur=0;
    stage(0,0);
    __syncthreads();
    const int NTILE = 33;
    for (int kt=0; kt<NTILE; kt++){
        if (kt+1<NTILE) stage(cur^1, kt+1);
        f32x16 ss0, ss1;
        #pragma unroll
        for (int i=0;i<16;i++){ ss0[i]=0.f; ss1[i]=0.f; }
        #pragma unroll
        for (int t=0;t<4;t++){
            int sl = (2*t+hi) ^ (l31&7);
            short8v kf0 = *(const short8v*)((const char*)&Kl[cur][0] + l31*128 + sl*16);
            ss0 = __builtin_amdgcn_mfma_f32_32x32x16_bf16(kf0, qf[t], ss0, 0,0,0);
            short8v kf1 = *(const short8v*)((const char*)&Kl[cur][0] + (32+l31)*128 + sl*16);
            ss1 = __builtin_amdgcn_mfma_f32_32x32x16_bf16(kf1, qf[t], ss1, 0,0,0);
        }
        if (kt == NTILE-1){
            #pragma unroll
            for (int r=0;r<16;r++){
                int k0 = 2048 + (r&3) + 8*(r>>2) + 4*hi;
                if (k0 >= 2049) ss0[r] = -1e30f;
                ss1[r] = -1e30f;   // keys 2080..2111 all masked
            }
        }
        float tmax=-1e30f;
        #pragma unroll
        for (int r=0;r<16;r++){ tmax=fmaxf(tmax, ss0[r]); tmax=fmaxf(tmax, ss1[r]); }
        tmax = fmaxf(tmax, __shfl_xor(tmax, 32));
        float mnew = fmaxf(m_run, tmax);
        float alpha = __expf(m_run - mnew);
        float psum = 0.f;
        #pragma unroll
        for (int r=0;r<16;r++){
            float p=__expf(ss0[r]-mnew); ss0[r]=p; psum+=p;
            float q=__expf(ss1[r]-mnew); ss1[r]=q; psum+=q;
        }
        psum += __shfl_xor(psum, 32);
        l_run = l_run*alpha + psum;
        m_run = mnew;
        so0 *= alpha; so1 *= alpha;

        // build P A-frags (B-operand for O^T mfma): slot j <-> key 16t+8hi+j
        short8v pf[4];
        #pragma unroll
        for (int t=0;t<4;t++){
            u32 a0,a1,b0,b1;
            if (t==0){ a0=pk2(ss0[0],ss0[1]);   a1=pk2(ss0[2],ss0[3]);   b0=pk2(ss0[4],ss0[5]);   b1=pk2(ss0[6],ss0[7]); }
            else if (t==1){ a0=pk2(ss0[8],ss0[9]);   a1=pk2(ss0[10],ss0[11]); b0=pk2(ss0[12],ss0[13]); b1=pk2(ss0[14],ss0[15]); }
            else if (t==2){ a0=pk2(ss1[0],ss1[1]);   a1=pk2(ss1[2],ss1[3]);   b0=pk2(ss1[4],ss1[5]);   b1=pk2(ss1[6],ss1[7]); }
            else          { a0=pk2(ss1[8],ss1[9]);   a1=pk2(ss1[10],ss1[11]); b0=pk2(ss1[12],ss1[13]); b1=pk2(ss1[14],ss1[15]); }
            u32 s0 = hi ? a0 : b0, s1 = hi ? a1 : b1;
            u32 r0 = (u32)__shfl_xor((int)s0, 32);
            u32 r1 = (u32)__shfl_xor((int)s1, 32);
            union { u32 u[4]; short8v v; } cvt;
            cvt.u[0] = hi ? r0 : a0;
            cvt.u[1] = hi ? r1 : a1;
            cvt.u[2] = hi ? b0 : r0;
            cvt.u[3] = hi ? b1 : r1;
            pf[t] = cvt.v;
        }
        #pragma unroll
        for (int t=0;t<4;t++){
            int sl = (2*t+hi) ^ (l31&7);
            short8v vf0 = *(const short8v*)((const char*)&Vl[cur][0] + l31*128 + sl*16);
            so0 = __builtin_amdgcn_mfma_f32_32x32x16_bf16(vf0, pf[t], so0, 0,0,0);
            short8v vf1 = *(const short8v*)((const char*)&Vl[cur][0] + (32+l31)*128 + sl*16);
            so1 = __builtin_amdgcn_mfma_f32_32x32x16_bf16(vf1, pf[t], so1, 0,0,0);
        }
        __syncthreads();
        cur ^= 1;
    }
    float inv = 1.f / l_run;
    u16* aop = ao + (size_t)(b*SS + qrow)*DD + h*64;
    #pragma unroll
    for (int rg=0; rg<4; rg++){
        int dh0 = rg*8 + 4*hi;
        u16x4 o0, o1;
        #pragma unroll
        for (int j=0;j<4;j++){ o0[j]=f2bf(so0[rg*4+j]*inv); o1[j]=f2bf(so1[rg*4+j]*inv); }
        *(u16x4*)(aop + dh0) = o0;
        *(u16x4*)(aop + 32 + dh0) = o1;
    }
}

// ---------------- split-K matvec: part[(b*8+kc)*N+j] = sum_{k in chunk} vec[b,k]*W[k,j] ----------------
__global__ __launch_bounds__(256) void vecmat_part(const float* __restrict__ vec,
    const float* __restrict__ W, float* __restrict__ part, int K, int N)
{
    int b = blockIdx.z, kc = blockIdx.y;
    int j = blockIdx.x*256 + threadIdx.x;
    int k0 = kc * (K >> 3);
    float acc = 0.0f;
    #pragma unroll 4
    for (int k = k0; k < k0 + (K >> 3); k++)
        acc += vec[(size_t)b*K + k] * W[(size_t)k*N + j];
    part[((size_t)b*8 + kc)*N + j] = acc;
}

__global__ __launch_bounds__(256) void vecmat_red(const float* __restrict__ part,
    float* __restrict__ out, int N)
{
    int b = blockIdx.y;
    int j = blockIdx.x*256 + threadIdx.x;
    float acc = 0.0f;
    #pragma unroll
    for (int kc = 0; kc < 8; kc++) acc += part[((size_t)b*8 + kc)*N + j];
    out[(size_t)b*N + j] = acc;
}

// ---------------- K/V memory-token fixup ----------------
__global__ __launch_bounds__(256) void fixup_kernel(const float* __restrict__ Kmb,
    const float* __restrict__ Vmb, u16* __restrict__ Kb, u16* __restrict__ VTb)
{
    int idx = blockIdx.x*256 + threadIdx.x;   // 0..2047
    int b = idx>>10, j = idx&1023; int h=j>>6, dh=j&63; int bh=b*HH+h;
    Kb[((size_t)bh*KSTRIDE + 2048)*64 + dh] = f2bf(Kmb[idx]);
    VTb[((size_t)bh*64 + dh)*KSTRIDE + 2048] = f2bf(Vmb[idx]);
}

// ---------------- mean pool: 64 chunks of 32 rows, then reduce ----------------
__global__ __launch_bounds__(256) void pool1_kernel(const float* __restrict__ att, float* __restrict__ ppart)
{
    int b = blockIdx.y, sc = blockIdx.x;   // sc 0..63
    int tid = threadIdx.x;
    float4 acc = {0,0,0,0};
    for (int s = 0; s < 32; s++) {
        int row = b*SS + sc*32 + s;
        float4 v = ((const float4*)(att + (size_t)row*DD))[tid];
        acc.x += v.x; acc.y += v.y; acc.z += v.z; acc.w += v.w;
    }
    ((float4*)(ppart + ((size_t)b*64 + sc)*DD))[tid] = acc;
}

__global__ __launch_bounds__(256) void pool2_kernel(const float* __restrict__ ppart, float* __restrict__ pooled)
{
    int b = blockIdx.y;
    int j = blockIdx.x*256 + threadIdx.x;
    float acc = 0.0f;
    for (int sc = 0; sc < 64; sc++) acc += ppart[((size_t)b*64 + sc)*DD + j];
    pooled[(size_t)b*DD + j] = acc * (1.0f/SS);
}

// ---------------- LSTM gates split-K: both weight mats ----------------
__global__ __launch_bounds__(256) void gates_part(const float* __restrict__ pooled,
    const float* __restrict__ h, const float* __restrict__ Wih, const float* __restrict__ Whh,
    float* __restrict__ part)
{
    int b = blockIdx.z, kc = blockIdx.y;
    int j = blockIdx.x*256 + threadIdx.x;   // 0..4095
    int k0 = kc * 128;
    float acc = 0.0f;
    #pragma unroll 4
    for (int k = k0; k < k0 + 128; k++)
        acc += pooled[(size_t)b*DD + k] * Wih[(size_t)k*4*DD + j]
             + h[(size_t)b*DD + k]      * Whh[(size_t)k*4*DD + j];
    part[((size_t)b*8 + kc)*4*DD + j] = acc;
}

__device__ __forceinline__ float sigmoidf_(float x) { return 1.0f / (1.0f + __expf(-x)); }

// ---------------- LSTM cell (fuses gate reduce + biases) ----------------
__global__ __launch_bounds__(256) void lstm_kernel(const float* __restrict__ gpart,
    const float* __restrict__ b_ih, const float* __restrict__ b_hh,
    const float* __restrict__ c, float* __restrict__ newh_ws, float* __restrict__ out_tail)
{
    int idx = blockIdx.x*256 + threadIdx.x;   // 0..2047
    int b = idx >> 10, d = idx & 1023;
    float sI = b_ih[d]          + b_hh[d];
    float sF = b_ih[DD + d]     + b_hh[DD + d];
    float sG = b_ih[2*DD + d]   + b_hh[2*DD + d];
    float sO = b_ih[3*DD + d]   + b_hh[3*DD + d];
    #pragma unroll
    for (int kc = 0; kc < 8; kc++){
        const float* gp = gpart + ((size_t)b*8 + kc)*4*DD;
        sI += gp[d]; sF += gp[DD + d]; sG += gp[2*DD + d]; sO += gp[3*DD + d];
    }
    float ig = sigmoidf_(sI);
    float fg = sigmoidf_(sF);
    float gg = tanhf(sG);
    float og = sigmoidf_(sO);
    float nc = fg * c[idx] + ig * gg;
    float nh = og * tanhf(nc);
    newh_ws[idx] = nh;
    out_tail[idx] = nh;
    out_tail[BB*DD + idx] = nc;
}

// ---------------- launch ----------------
extern "C" void kernel_launch(void* const* d_in, const int* in_sizes, int n_in,
                              void* d_out, int out_size, void* d_ws, size_t ws_size,
                              hipStream_t stream) {
    const float* x    = (const float*)d_in[0];
    const float* h    = (const float*)d_in[1];
    const float* c    = (const float*)d_in[2];
    const float* Wq   = (const float*)d_in[3];
    const float* Wk   = (const float*)d_in[4];
    const float* Wv   = (const float*)d_in[5];
    const float* Wo   = (const float*)d_in[6];
    const float* Wmk  = (const float*)d_in[7];
    const float* Wmv  = (const float*)d_in[8];
    const float* Wih  = (const float*)d_in[9];
    const float* Whh  = (const float*)d_in[10];
    const float* b_ih = (const float*)d_in[11];
    const float* b_hh = (const float*)d_in[12];
    const float* W1   = (const float*)d_in[13];
    const float* bf1  = (const float*)d_in[14];
    const float* W2   = (const float*)d_in[15];
    const float* bf2  = (const float*)d_in[16];
    const float* g1   = (const float*)d_in[17];
    const float* be1  = (const float*)d_in[18];
    const float* g2   = (const float*)d_in[19];
    const float* be2  = (const float*)d_in[20];
    const float* g3   = (const float*)d_in[21];
    const float* be3  = (const float*)d_in[22];
    const float* Wmp  = (const float*)d_in[23];

    float* out = (float*)d_out;
    char* wsb  = (char*)d_ws;

    u16*   xn   = (u16*)(wsb + 0);        // 8MB  [0,8)
    u16*   hn   = (u16*)(wsb + 8*MB);     // 8MB  [8,16)
    float* yb   = (float*)(wsb + 0);      // 16MB overlay [0,16) (xn,hn dead)
    u16*   Qbuf = (u16*)(wsb + 16*MB);    // 8MB  [16,24)
    u16*   Kbuf = (u16*)(wsb + 24*MB);    // 8.5MB [24,33)
    u16*   VTb  = (u16*)(wsb + 33*MB);    // 8.5MB [33,42)
    u16*   act  = (u16*)(wsb + 16*MB);    // 32MB overlay [16,48) (Q/K/VT dead)
    u16*   ao   = (u16*)(wsb + 48*MB);    // 8MB  [48,56)
    float* attb = (float*)(wsb + 56*MB);  // 16MB [56,72)
    u16*   WqT  = (u16*)(wsb + 72*MB);
    u16*   WkT  = (u16*)(wsb + 74*MB);
    u16*   WvT  = (u16*)(wsb + 76*MB);
    u16*   WoT  = (u16*)(wsb + 78*MB);
    u16*   W1T  = (u16*)(wsb + 80*MB);    // [80,88)
    u16*   W2T  = (u16*)(wsb + 88*MB);    // [88,96)
    float* sm   = (float*)(wsb + 96*MB);
    float* Kmb     = sm;                       // 2048
    float* Vmb     = Kmb + 2048;               // 2048
    float* pooled  = Vmb + 2048;               // 2048
    float* newh    = pooled + 2048;            // 2048
    float* mproj   = newh + 2048;              // 2048
    float* vpart   = mproj + 2048;             // 16384 (8 chunks x 1024 x B)
    float* gpart   = vpart + 16384;            // 65536 (8 chunks x 4096 x B)
    float* ppart   = gpart + 65536;            // 131072 (64 chunks x 1024 x B)

    // weight transposes (fp32 [K][N] -> bf16 [N][K])
    tr_kernel<<<dim3(32,32), 256, 0, stream>>>(Wq, WqT, 1024, 1024);
    tr_kernel<<<dim3(32,32), 256, 0, stream>>>(Wk, WkT, 1024, 1024);
    tr_kernel<<<dim3(32,32), 256, 0, stream>>>(Wv, WvT, 1024, 1024);
    tr_kernel<<<dim3(32,32), 256, 0, stream>>>(Wo, WoT, 1024, 1024);
    tr_kernel<<<dim3(128,32), 256, 0, stream>>>(W1, W1T, 1024, 4096);
    tr_kernel<<<dim3(32,128), 256, 0, stream>>>(W2, W2T, 4096, 1024);

    // LN1 -> xn bf16
    ln_kernel<<<RR, 256, 0, stream>>>(x, nullptr, g1, be1, nullptr, nullptr, xn);
    // memory K/V tokens (fp32, split-K)
    vecmat_part<<<dim3(4,8,BB), 256, 0, stream>>>(h, Wmk, vpart, DD, DD);
    vecmat_red<<<dim3(4,BB), 256, 0, stream>>>(vpart, Kmb, DD);
    vecmat_part<<<dim3(4,8,BB), 256, 0, stream>>>(h, Wmv, vpart, DD, DD);
    vecmat_red<<<dim3(4,BB), 256, 0, stream>>>(vpart, Vmb, DD);
    // Q,K,V projections (MFMA)
    mgemm<<<dim3(8,32), 256, 0, stream>>>(xn, WqT, RR, DD, DD, MODE_Q, nullptr, nullptr, 0.125f, Qbuf);
    mgemm<<<dim3(8,32), 256, 0, stream>>>(xn, WkT, RR, DD, DD, MODE_K, nullptr, nullptr, 1.f, Kbuf);
    mgemm<<<dim3(8,32), 256, 0, stream>>>(xn, WvT, RR, DD, DD, MODE_V, nullptr, nullptr, 1.f, VTb);
    fixup_kernel<<<8, 256, 0, stream>>>(Kmb, Vmb, Kbuf, VTb);
    // attention
    attn_mfma<<<dim3(16,32), 256, 0, stream>>>(Qbuf, Kbuf, VTb, ao);
    // attended = x + ao @ Wo  (fp32)
    mgemm<<<dim3(8,32), 256, 0, stream>>>(ao, WoT, RR, DD, DD, MODE_F32R, nullptr, x, 1.f, attb);
    // mean pool, LSTM
    pool1_kernel<<<dim3(64,BB), 256, 0, stream>>>(attb, ppart);
    pool2_kernel<<<dim3(4,BB), 256, 0, stream>>>(ppart, pooled);
    gates_part<<<dim3(16,8,BB), 256, 0, stream>>>(pooled, h, Wih, Whh, gpart);
    lstm_kernel<<<8, 256, 0, stream>>>(gpart, b_ih, b_hh, c, newh, out + (size_t)RR*DD);
    vecmat_part<<<dim3(4,8,BB), 256, 0, stream>>>(newh, Wmp, vpart, DD, DD);
    vecmat_red<<<dim3(4,BB), 256, 0, stream>>>(vpart, mproj, DD);
    // mixed = attended + mproj (in place), hn = LN2(mixed) bf16
    ln_kernel<<<RR, 256, 0, stream>>>(attb, mproj, g2, be2, attb, nullptr, hn);
    // FFN
    mgemm<<<dim3(32,32), 256, 0, stream>>>(hn, W1T, RR, 4*DD, DD, MODE_GELU, bf1, nullptr, 1.f, act);
    mgemm<<<dim3(8,32), 256, 0, stream>>>(act, W2T, RR, DD, 4*DD, MODE_F32BR, bf2, attb, 1.f, yb);
    // out = LN3(y)
    ln_kernel<<<RR, 256, 0, stream>>>(yb, nullptr, g3, be3, nullptr, out, nullptr);
}

// Round 6
// 400.173 us; speedup vs baseline: 11.4472x; 1.2221x over previous
//
#include <hip/hip_runtime.h>
#include <hip/hip_bf16.h>
#include <math.h>

#define BB 2
#define SS 2048
#define DD 1024
#define HH 16
#define RR (BB*SS)
#define KSTRIDE 2064   // padded key stride per (b,h)
#define MB (1024ull*1024ull)

typedef unsigned short u16;
typedef unsigned int u32;
typedef __attribute__((ext_vector_type(8))) short short8v;
typedef __attribute__((ext_vector_type(4))) float f32x4;
typedef __attribute__((ext_vector_type(16))) float f32x16;
typedef __attribute__((ext_vector_type(4))) u16 u16x4;

__device__ __forceinline__ u16 f2bf(float f){
    union { __hip_bfloat16 h; u16 u; } c; c.h = __float2bfloat16(f); return c.u;
}
__device__ __forceinline__ u32 pk2(float a, float b){
    return (u32)f2bf(a) | ((u32)f2bf(b) << 16);
}

#define GLL16(gp, lp) __builtin_amdgcn_global_load_lds( \
    (const __attribute__((address_space(1))) void*)(gp), \
    (__attribute__((address_space(3))) void*)(lp), 16, 0, 0)

// ---------------- LayerNorm: fp32 in, optional broadcast add, fp32 and/or bf16 out ----------------
__global__ __launch_bounds__(256) void ln_kernel(const float* __restrict__ in,
    const float* __restrict__ mproj, const float* __restrict__ g, const float* __restrict__ be,
    float* __restrict__ mixed_out, float* __restrict__ outf, u16* __restrict__ outb)
{
    int row = blockIdx.x; int b = row / SS; int tid = threadIdx.x;
    float4 v = ((const float4*)(in + (size_t)row*DD))[tid];
    if (mproj){
        float4 mp = ((const float4*)(mproj + (size_t)b*DD))[tid];
        v.x+=mp.x; v.y+=mp.y; v.z+=mp.z; v.w+=mp.w;
        ((float4*)(mixed_out + (size_t)row*DD))[tid] = v;
    }
    float s = v.x+v.y+v.z+v.w, s2 = v.x*v.x+v.y*v.y+v.z*v.z+v.w*v.w;
    #pragma unroll
    for (int off=32; off>0; off>>=1){ s += __shfl_down(s,off); s2 += __shfl_down(s2,off); }
    __shared__ float red[2][4];
    if ((tid&63)==0){ red[0][tid>>6]=s; red[1][tid>>6]=s2; }
    __syncthreads();
    float st = red[0][0]+red[0][1]+red[0][2]+red[0][3];
    float s2t= red[1][0]+red[1][1]+red[1][2]+red[1][3];
    float mean = st*(1.f/DD); float var = s2t*(1.f/DD)-mean*mean;
    float rs = rsqrtf(var + 1e-5f);
    float4 gg=((const float4*)g)[tid], bb2=((const float4*)be)[tid];
    float o0=(v.x-mean)*rs*gg.x+bb2.x, o1=(v.y-mean)*rs*gg.y+bb2.y;
    float o2=(v.z-mean)*rs*gg.z+bb2.z, o3=(v.w-mean)*rs*gg.w+bb2.w;
    if (outf){ float4 o={o0,o1,o2,o3}; ((float4*)(outf+(size_t)row*DD))[tid]=o; }
    if (outb){ u16x4 o={f2bf(o0),f2bf(o1),f2bf(o2),f2bf(o3)}; ((u16x4*)(outb+(size_t)row*DD))[tid]=o; }
}

// ---------------- fp32 [K][N] -> bf16 [N][K] transpose ----------------
__global__ __launch_bounds__(256) void tr_kernel(const float* __restrict__ in, u16* __restrict__ out,
                                                 int K, int N)
{
    __shared__ float t[32][33];
    int n0 = blockIdx.x*32, k0 = blockIdx.y*32;
    int tx = threadIdx.x & 31, ty = threadIdx.x >> 5;   // ty 0..7
    #pragma unroll
    for (int i=0;i<4;i++){ int k = ty + i*8; t[k][tx] = in[(size_t)(k0+k)*N + n0 + tx]; }
    __syncthreads();
    #pragma unroll
    for (int i=0;i<4;i++){ int n = ty + i*8; out[(size_t)(n0+n)*K + k0 + tx] = f2bf(t[tx][n]); }
}

// ---------------- bf16 MFMA GEMM: C = A[M,Kfull] @ BT[N,Kfull]^T, 128x128x32 tiles ----------------
// 1D grid = nbx*nby*kchunks, bijective XCD swizzle (grid must be %8==0)
#define MODE_QKV  0  // fused: col<1024 Q(bf16*scale), <2048 K-layout, else V^T-layout
#define MODE_F32R 3  // f32 + resid
#define MODE_GELU 4  // bf16, +bias, gelu
#define MODE_F32BR 5 // f32 + bias + resid
#define MODE_PART 6  // fp32 partial (split-K): chunk0->Cout, chunk1->C2a/C2b row-split at 2048

__global__ __launch_bounds__(256) void mgemm(const u16* __restrict__ A, const u16* __restrict__ BT,
    int nbx, int Kc, int kchunks, int mode,
    const float* __restrict__ bias, const float* __restrict__ resid, float scale,
    void* __restrict__ Cout, void* __restrict__ C2a, void* __restrict__ C2b)
{
    int tid=threadIdx.x, l=tid&63, w=tid>>6;
    // XCD-aware bijective swizzle
    int nwg = gridDim.x;
    int qq = nwg >> 3;
    int bid = blockIdx.x;
    int swz = (bid & 7)*qq + (bid >> 3);
    int tiles = nwg / kchunks;
    int chunk = swz / tiles;
    int t2 = swz % tiles;
    int bx = t2 % nbx, by = t2 / nbx;

    int bm = by*128, bn = bx*128;
    int N = nbx*128;
    int lda = Kc*kchunks;
    int koff = chunk*Kc;
    int wr = w>>1, wc = w&1;
    f32x4 acc[4][4];
    #pragma unroll
    for(int i=0;i<4;i++)
        #pragma unroll
        for(int j=0;j<4;j++)
            #pragma unroll
            for(int r=0;r<4;r++) acc[i][j][r]=0.f;

    __shared__ __align__(16) u16 Al[2][4096];
    __shared__ __align__(16) u16 Bl[2][4096];
    int srow = (w<<4) + (l>>2);     // staging row (+64 per issue)
    int sph  = l&3;                 // physical 16B slot
    const int NT = Kc >> 5;

    auto stage = [&](int buf, int kt){
        #pragma unroll
        for (int r=0;r<2;r++){
            int rowA = srow + r*64;
            int sl = sph ^ ((rowA>>1)&3);
            const u16* gA = A + (size_t)(bm+rowA)*lda + koff + kt*32 + sl*8;
            GLL16(gA, (char*)&Al[buf][0] + r*4096 + w*1024);
            const u16* gB = BT + (size_t)(bn+rowA)*lda + koff + kt*32 + sl*8;
            GLL16(gB, (char*)&Bl[buf][0] + r*4096 + w*1024);
        }
    };

    int cur=0;
    stage(0,0);
    __syncthreads();
    for (int kt=0; kt<NT; kt++){
        if (kt+1<NT) stage(cur^1, kt+1);
        short8v af[4], bf[4];
        #pragma unroll
        for (int mi=0;mi<4;mi++){
            int row = wr*64 + mi*16 + (l&15);
            int sl = (l>>4) ^ ((row>>1)&3);
            af[mi] = *(const short8v*)((const char*)&Al[cur][0] + row*64 + sl*16);
        }
        #pragma unroll
        for (int ni=0;ni<4;ni++){
            int row = wc*64 + ni*16 + (l&15);
            int sl = (l>>4) ^ ((row>>1)&3);
            bf[ni] = *(const short8v*)((const char*)&Bl[cur][0] + row*64 + sl*16);
        }
        #pragma unroll
        for (int mi=0;mi<4;mi++)
            #pragma unroll
            for (int ni=0;ni<4;ni++)
                acc[mi][ni] = __builtin_amdgcn_mfma_f32_16x16x32_bf16(af[mi], bf[ni], acc[mi][ni], 0,0,0);
        __syncthreads();
        cur ^= 1;
    }

    #pragma unroll
    for (int mi=0;mi<4;mi++){
        #pragma unroll
        for (int ni=0;ni<4;ni++){
            int col = bn + wc*64 + ni*16 + (l&15);
            int rbase = bm + wr*64 + mi*16 + ((l>>4)<<2);
            if (mode==MODE_QKV && col >= 2048){
                // V^T: [b,h,dh,key], 4 consecutive keys packed
                int cc = col - 2048;
                int b = rbase>>11, key = rbase&2047;
                int h = cc>>6, dh = cc&63;
                u16x4 pkv;
                #pragma unroll
                for (int r=0;r<4;r++) pkv[r] = f2bf(acc[mi][ni][r]);
                *(u16x4*)((u16*)C2b + ((size_t)(b*HH+h)*64 + dh)*KSTRIDE + key) = pkv;
            } else {
                #pragma unroll
                for (int r=0;r<4;r++){
                    int m = rbase + r;
                    float v = acc[mi][ni][r];
                    if (mode==MODE_QKV){
                        if (col < 1024){
                            ((u16*)Cout)[(size_t)m*1024 + col] = f2bf(v*scale);
                        } else {
                            int cc = col - 1024;
                            int b=m>>11, key=m&2047, h=cc>>6, dh=cc&63;
                            ((u16*)C2a)[((size_t)(b*HH+h)*KSTRIDE + key)*64 + dh] = f2bf(v);
                        }
                    } else if (mode==MODE_F32R){
                        ((float*)Cout)[(size_t)m*N+col] = v + resid[(size_t)m*N+col];
                    } else if (mode==MODE_GELU){
                        v += bias[col];
                        v = 0.5f*v*(1.0f+erff(v*0.70710678118654752f));
                        ((u16*)Cout)[(size_t)m*N+col] = f2bf(v);
                    } else if (mode==MODE_F32BR){
                        v += bias[col] + resid[(size_t)m*N+col];
                        ((float*)Cout)[(size_t)m*N+col] = v;
                    } else { // MODE_PART
                        if (chunk==0){
                            ((float*)Cout)[(size_t)m*N+col] = v;
                        } else if (m < 2048){
                            ((float*)C2a)[(size_t)m*N+col] = v;
                        } else {
                            ((float*)C2b)[(size_t)(m-2048)*N+col] = v;
                        }
                    }
                }
            }
        }
    }
}

// ---------------- split-K reduce for FFN2: yb = p0+p1+bias+resid ----------------
__global__ __launch_bounds__(256) void splitred(const float* __restrict__ p0,
    const float* __restrict__ p1a, const float* __restrict__ p1b,
    const float* __restrict__ bias, const float* __restrict__ resid, float* __restrict__ yb)
{
    int row = blockIdx.x;
    int j = threadIdx.x;
    const float* p1 = (row < 2048) ? (p1a + (size_t)row*DD) : (p1b + (size_t)(row-2048)*DD);
    float4 a = ((const float4*)(p0 + (size_t)row*DD))[j];
    float4 b = ((const float4*)p1)[j];
    float4 bi = ((const float4*)bias)[j];
    float4 rs = ((const float4*)(resid + (size_t)row*DD))[j];
    float4 o = {a.x+b.x+bi.x+rs.x, a.y+b.y+bi.y+rs.y, a.z+b.z+bi.z+rs.z, a.w+b.w+bi.w+rs.w};
    ((float4*)(yb + (size_t)row*DD))[j] = o;
}

// ---------------- MFMA flash attention: 32x32x16, swapped QK^T, V pre-transposed ----------------
__global__ __launch_bounds__(256) void attn_mfma(const u16* __restrict__ Qb, const u16* __restrict__ Kb,
    const u16* __restrict__ VTb, u16* __restrict__ ao)
{
    __shared__ __align__(16) u16 Kl[2][4096];  // [key 64][dh 64], slot-XOR swizzled
    __shared__ __align__(16) u16 Vl[2][4096];  // [dh 64][key 64], slot-XOR swizzled
    int tid=threadIdx.x, l=tid&63, w=tid>>6;
    int l31=l&31, hi=l>>5;
    int qt=blockIdx.x, bh=blockIdx.y; int b=bh>>4, h=bh&15;
    int qrow = qt*128 + w*32 + l31;

    const u16* qptr = Qb + (size_t)(b*SS + qrow)*DD + h*64;
    short8v qf[4];
    #pragma unroll
    for (int t=0;t<4;t++) qf[t] = *(const short8v*)(qptr + t*16 + hi*8);

    f32x16 so0, so1;
    #pragma unroll
    for (int i=0;i<16;i++){ so0[i]=0.f; so1[i]=0.f; }
    float m_run=-1e30f, l_run=0.f;

    int skey = (w<<3) + (l>>3);   // staging row (+32 per issue)
    int ssl  = l&7;
    auto stage = [&](int buf, int kt){
        #pragma unroll
        for (int r=0;r<2;r++){
            int key = skey + r*32;
            int slot = ssl ^ (key&7);
            const u16* gK = Kb + ((size_t)bh*KSTRIDE + kt*64 + key)*64 + slot*8;
            GLL16(gK, (char*)&Kl[buf][0] + r*4096 + w*1024);
            const u16* gV = VTb + ((size_t)bh*64 + key)*KSTRIDE + kt*64 + slot*8;
            GLL16(gV, (char*)&Vl[buf][0] + r*4096 + w*1024);
        }
    };

    int cur=0;
    stage(0,0);
    __syncthreads();
    const int NTILE = 33;
    for (int kt=0; kt<NTILE; kt++){
        if (kt+1<NTILE) stage(cur^1, kt+1);
        f32x16 ss0, ss1;
        #pragma unroll
        for (int i=0;i<16;i++){ ss0[i]=0.f; ss1[i]=0.f; }
        #pragma unroll
        for (int t=0;t<4;t++){
            int sl = (2*t+hi) ^ (l31&7);
            short8v kf0 = *(const short8v*)((const char*)&Kl[cur][0] + l31*128 + sl*16);
            ss0 = __builtin_amdgcn_mfma_f32_32x32x16_bf16(kf0, qf[t], ss0, 0,0,0);
            short8v kf1 = *(const short8v*)((const char*)&Kl[cur][0] + (32+l31)*128 + sl*16);
            ss1 = __builtin_amdgcn_mfma_f32_32x32x16_bf16(kf1, qf[t], ss1, 0,0,0);
        }
        if (kt == NTILE-1){
            #pragma unroll
            for (int r=0;r<16;r++){
                int k0 = 2048 + (r&3) + 8*(r>>2) + 4*hi;
                if (k0 >= 2049) ss0[r] = -1e30f;
                ss1[r] = -1e30f;   // keys 2080..2111 all masked
            }
        }
        float tmax=-1e30f;
        #pragma unroll
        for (int r=0;r<16;r++){ tmax=fmaxf(tmax, ss0[r]); tmax=fmaxf(tmax, ss1[r]); }
        tmax = fmaxf(tmax, __shfl_xor(tmax, 32));
        float mnew = fmaxf(m_run, tmax);
        float alpha = __expf(m_run - mnew);
        float psum = 0.f;
        #pragma unroll
        for (int r=0;r<16;r++){
            float p=__expf(ss0[r]-mnew); ss0[r]=p; psum+=p;
            float q=__expf(ss1[r]-mnew); ss1[r]=q; psum+=q;
        }
        psum += __shfl_xor(psum, 32);
        l_run = l_run*alpha + psum;
        m_run = mnew;
        so0 *= alpha; so1 *= alpha;

        short8v pf[4];
        #pragma unroll
        for (int t=0;t<4;t++){
            u32 a0,a1,b0,b1;
            if (t==0){ a0=pk2(ss0[0],ss0[1]);   a1=pk2(ss0[2],ss0[3]);   b0=pk2(ss0[4],ss0[5]);   b1=pk2(ss0[6],ss0[7]); }
            else if (t==1){ a0=pk2(ss0[8],ss0[9]);   a1=pk2(ss0[10],ss0[11]); b0=pk2(ss0[12],ss0[13]); b1=pk2(ss0[14],ss0[15]); }
            else if (t==2){ a0=pk2(ss1[0],ss1[1]);   a1=pk2(ss1[2],ss1[3]);   b0=pk2(ss1[4],ss1[5]);   b1=pk2(ss1[6],ss1[7]); }
            else          { a0=pk2(ss1[8],ss1[9]);   a1=pk2(ss1[10],ss1[11]); b0=pk2(ss1[12],ss1[13]); b1=pk2(ss1[14],ss1[15]); }
            u32 s0 = hi ? a0 : b0, s1 = hi ? a1 : b1;
            u32 r0 = (u32)__shfl_xor((int)s0, 32);
            u32 r1 = (u32)__shfl_xor((int)s1, 32);
            union { u32 u[4]; short8v v; } cvt;
            cvt.u[0] = hi ? r0 : a0;
            cvt.u[1] = hi ? r1 : a1;
            cvt.u[2] = hi ? b0 : r0;
            cvt.u[3] = hi ? b1 : r1;
            pf[t] = cvt.v;
        }
        #pragma unroll
        for (int t=0;t<4;t++){
            int sl = (2*t+hi) ^ (l31&7);
            short8v vf0 = *(const short8v*)((const char*)&Vl[cur][0] + l31*128 + sl*16);
            so0 = __builtin_amdgcn_mfma_f32_32x32x16_bf16(vf0, pf[t], so0, 0,0,0);
            short8v vf1 = *(const short8v*)((const char*)&Vl[cur][0] + (32+l31)*128 + sl*16);
            so1 = __builtin_amdgcn_mfma_f32_32x32x16_bf16(vf1, pf[t], so1, 0,0,0);
        }
        __syncthreads();
        cur ^= 1;
    }
    float inv = 1.f / l_run;
    u16* aop = ao + (size_t)(b*SS + qrow)*DD + h*64;
    #pragma unroll
    for (int rg=0; rg<4; rg++){
        int dh0 = rg*8 + 4*hi;
        u16x4 o0, o1;
        #pragma unroll
        for (int j=0;j<4;j++){ o0[j]=f2bf(so0[rg*4+j]*inv); o1[j]=f2bf(so1[rg*4+j]*inv); }
        *(u16x4*)(aop + dh0) = o0;
        *(u16x4*)(aop + 32 + dh0) = o1;
    }
}

// ---------------- split-K matvec ----------------
__global__ __launch_bounds__(256) void vecmat_part(const float* __restrict__ vec,
    const float* __restrict__ W, float* __restrict__ part, int K, int N)
{
    int b = blockIdx.z, kc = blockIdx.y;
    int j = blockIdx.x*256 + threadIdx.x;
    int k0 = kc * (K >> 3);
    float acc = 0.0f;
    #pragma unroll 4
    for (int k = k0; k < k0 + (K >> 3); k++)
        acc += vec[(size_t)b*K + k] * W[(size_t)k*N + j];
    part[((size_t)b*8 + kc)*N + j] = acc;
}

__global__ __launch_bounds__(256) void vecmat_red(const float* __restrict__ part,
    float* __restrict__ out, int N)
{
    int b = blockIdx.y;
    int j = blockIdx.x*256 + threadIdx.x;
    float acc = 0.0f;
    #pragma unroll
    for (int kc = 0; kc < 8; kc++) acc += part[((size_t)b*8 + kc)*N + j];
    out[(size_t)b*N + j] = acc;
}

// fused Km/Vm: reads h once, both weights
__global__ __launch_bounds__(256) void vecmat2_part(const float* __restrict__ vec,
    const float* __restrict__ Wa, const float* __restrict__ Wb, float* __restrict__ part)
{
    int b = blockIdx.z, kc = blockIdx.y;
    int j = blockIdx.x*256 + threadIdx.x;
    int k0 = kc * 128;
    float accA = 0.0f, accB = 0.0f;
    #pragma unroll 4
    for (int k = k0; k < k0 + 128; k++){
        float v = vec[(size_t)b*DD + k];
        accA += v * Wa[(size_t)k*DD + j];
        accB += v * Wb[(size_t)k*DD + j];
    }
    part[((size_t)b*8 + kc)*2048 + j] = accA;
    part[((size_t)b*8 + kc)*2048 + 1024 + j] = accB;
}

__global__ __launch_bounds__(256) void vecmat2_red(const float* __restrict__ part,
    float* __restrict__ outA, float* __restrict__ outB)
{
    int b = blockIdx.y;
    int j = blockIdx.x*256 + threadIdx.x;
    float accA = 0.0f, accB = 0.0f;
    #pragma unroll
    for (int kc = 0; kc < 8; kc++){
        accA += part[((size_t)b*8 + kc)*2048 + j];
        accB += part[((size_t)b*8 + kc)*2048 + 1024 + j];
    }
    outA[(size_t)b*DD + j] = accA;
    outB[(size_t)b*DD + j] = accB;
}

// ---------------- K/V memory-token fixup ----------------
__global__ __launch_bounds__(256) void fixup_kernel(const float* __restrict__ Kmb,
    const float* __restrict__ Vmb, u16* __restrict__ Kb, u16* __restrict__ VTb)
{
    int idx = blockIdx.x*256 + threadIdx.x;   // 0..2047
    int b = idx>>10, j = idx&1023; int h=j>>6, dh=j&63; int bh=b*HH+h;
    Kb[((size_t)bh*KSTRIDE + 2048)*64 + dh] = f2bf(Kmb[idx]);
    VTb[((size_t)bh*64 + dh)*KSTRIDE + 2048] = f2bf(Vmb[idx]);
}

// ---------------- mean pool: 64 chunks of 32 rows, then reduce ----------------
__global__ __launch_bounds__(256) void pool1_kernel(const float* __restrict__ att, float* __restrict__ ppart)
{
    int b = blockIdx.y, sc = blockIdx.x;   // sc 0..63
    int tid = threadIdx.x;
    float4 acc = {0,0,0,0};
    for (int s = 0; s < 32; s++) {
        int row = b*SS + sc*32 + s;
        float4 v = ((const float4*)(att + (size_t)row*DD))[tid];
        acc.x += v.x; acc.y += v.y; acc.z += v.z; acc.w += v.w;
    }
    ((float4*)(ppart + ((size_t)b*64 + sc)*DD))[tid] = acc;
}

__global__ __launch_bounds__(256) void pool2_kernel(const float* __restrict__ ppart, float* __restrict__ pooled)
{
    int b = blockIdx.y;
    int j = blockIdx.x*256 + threadIdx.x;
    float acc = 0.0f;
    for (int sc = 0; sc < 64; sc++) acc += ppart[((size_t)b*64 + sc)*DD + j];
    pooled[(size_t)b*DD + j] = acc * (1.0f/SS);
}

// ---------------- LSTM gates split-K (16 chunks) ----------------
__global__ __launch_bounds__(256) void gates_part(const float* __restrict__ pooled,
    const float* __restrict__ h, const float* __restrict__ Wih, const float* __restrict__ Whh,
    float* __restrict__ part)
{
    int b = blockIdx.z, kc = blockIdx.y;   // kc 0..15
    int j = blockIdx.x*256 + threadIdx.x;  // 0..4095
    int k0 = kc * 64;
    float acc = 0.0f;
    #pragma unroll 4
    for (int k = k0; k < k0 + 64; k++)
        acc += pooled[(size_t)b*DD + k] * Wih[(size_t)k*4*DD + j]
             + h[(size_t)b*DD + k]      * Whh[(size_t)k*4*DD + j];
    part[((size_t)b*16 + kc)*4*DD + j] = acc;
}

__device__ __forceinline__ float sigmoidf_(float x) { return 1.0f / (1.0f + __expf(-x)); }

__global__ __launch_bounds__(256) void lstm_kernel(const float* __restrict__ gpart,
    const float* __restrict__ b_ih, const float* __restrict__ b_hh,
    const float* __restrict__ c, float* __restrict__ newh_ws, float* __restrict__ out_tail)
{
    int idx = blockIdx.x*256 + threadIdx.x;   // 0..2047
    int b = idx >> 10, d = idx & 1023;
    float sI = b_ih[d]          + b_hh[d];
    float sF = b_ih[DD + d]     + b_hh[DD + d];
    float sG = b_ih[2*DD + d]   + b_hh[2*DD + d];
    float sO = b_ih[3*DD + d]   + b_hh[3*DD + d];
    #pragma unroll
    for (int kc = 0; kc < 16; kc++){
        const float* gp = gpart + ((size_t)b*16 + kc)*4*DD;
        sI += gp[d]; sF += gp[DD + d]; sG += gp[2*DD + d]; sO += gp[3*DD + d];
    }
    float ig = sigmoidf_(sI);
    float fg = sigmoidf_(sF);
    float gg = tanhf(sG);
    float og = sigmoidf_(sO);
    float nc = fg * c[idx] + ig * gg;
    float nh = og * tanhf(nc);
    newh_ws[idx] = nh;
    out_tail[idx] = nh;
    out_tail[BB*DD + idx] = nc;
}

// ---------------- launch ----------------
extern "C" void kernel_launch(void* const* d_in, const int* in_sizes, int n_in,
                              void* d_out, int out_size, void* d_ws, size_t ws_size,
                              hipStream_t stream) {
    const float* x    = (const float*)d_in[0];
    const float* h    = (const float*)d_in[1];
    const float* c    = (const float*)d_in[2];
    const float* Wq   = (const float*)d_in[3];
    const float* Wk   = (const float*)d_in[4];
    const float* Wv   = (const float*)d_in[5];
    const float* Wo   = (const float*)d_in[6];
    const float* Wmk  = (const float*)d_in[7];
    const float* Wmv  = (const float*)d_in[8];
    const float* Wih  = (const float*)d_in[9];
    const float* Whh  = (const float*)d_in[10];
    const float* b_ih = (const float*)d_in[11];
    const float* b_hh = (const float*)d_in[12];
    const float* W1   = (const float*)d_in[13];
    const float* bf1  = (const float*)d_in[14];
    const float* W2   = (const float*)d_in[15];
    const float* bf2  = (const float*)d_in[16];
    const float* g1   = (const float*)d_in[17];
    const float* be1  = (const float*)d_in[18];
    const float* g2   = (const float*)d_in[19];
    const float* be2  = (const float*)d_in[20];
    const float* g3   = (const float*)d_in[21];
    const float* be3  = (const float*)d_in[22];
    const float* Wmp  = (const float*)d_in[23];

    float* out = (float*)d_out;
    char* wsb  = (char*)d_ws;

    u16*   xn   = (u16*)(wsb + 0);        // 8MB  [0,8)
    u16*   hn   = (u16*)(wsb + 8*MB);     // 8MB  [8,16)
    float* yb   = (float*)(wsb + 0);      // 16MB overlay [0,16) (xn,hn dead) = FFN2 partial0
    u16*   Qbuf = (u16*)(wsb + 16*MB);    // 8MB  [16,24)
    u16*   Kbuf = (u16*)(wsb + 24*MB);    // 8.5MB [24,33)
    u16*   VTb  = (u16*)(wsb + 33*MB);    // 8.5MB [33,42)
    u16*   act  = (u16*)(wsb + 16*MB);    // 32MB overlay [16,48) (Q/K/VT dead)
    u16*   ao   = (u16*)(wsb + 48*MB);    // 8MB  [48,56)
    float* p1a  = (float*)(wsb + 48*MB);  // FFN2 partial1 rows 0..2047 (ao dead)
    float* attb = (float*)(wsb + 56*MB);  // 16MB [56,72)
    u16*   WqkvT= (u16*)(wsb + 72*MB);    // 6MB [72,78): Wq rows 0..1023, Wk 1024.., Wv 2048..
    u16*   WoT  = (u16*)(wsb + 78*MB);    // 2MB [78,80)
    u16*   W1T  = (u16*)(wsb + 80*MB);    // 8MB [80,88)
    float* p1b  = (float*)(wsb + 80*MB);  // FFN2 partial1 rows 2048..4095 (W1T dead)
    u16*   W2T  = (u16*)(wsb + 88*MB);    // 8MB [88,96)
    float* sm   = (float*)(wsb + 96*MB);
    float* Kmb     = sm;                       // 2048
    float* Vmb     = Kmb + 2048;               // 2048
    float* pooled  = Vmb + 2048;               // 2048
    float* newh    = pooled + 2048;            // 2048
    float* mproj   = newh + 2048;              // 2048
    float* vpart   = mproj + 2048;             // 16384
    float* v2part  = vpart + 16384;            // 32768 (8 chunks x 2048 x B)
    float* gpart   = v2part + 32768;           // 131072 (16 chunks x 4096 x B)
    float* ppart   = gpart + 131072;           // 131072 (64 chunks x 1024 x B)

    // weight transposes (fp32 [K][N] -> bf16 [N][K])
    tr_kernel<<<dim3(32,32), 256, 0, stream>>>(Wq, WqkvT,             1024, 1024);
    tr_kernel<<<dim3(32,32), 256, 0, stream>>>(Wk, WqkvT + 1024*1024, 1024, 1024);
    tr_kernel<<<dim3(32,32), 256, 0, stream>>>(Wv, WqkvT + 2048*1024, 1024, 1024);
    tr_kernel<<<dim3(32,32), 256, 0, stream>>>(Wo, WoT, 1024, 1024);
    tr_kernel<<<dim3(128,32), 256, 0, stream>>>(W1, W1T, 1024, 4096);
    tr_kernel<<<dim3(32,128), 256, 0, stream>>>(W2, W2T, 4096, 1024);

    // LN1 -> xn bf16
    ln_kernel<<<RR, 256, 0, stream>>>(x, nullptr, g1, be1, nullptr, nullptr, xn);
    // memory K/V tokens (fp32, split-K, fused)
    vecmat2_part<<<dim3(4,8,BB), 256, 0, stream>>>(h, Wmk, Wmv, v2part);
    vecmat2_red<<<dim3(4,BB), 256, 0, stream>>>(v2part, Kmb, Vmb);
    // fused QKV projection (MFMA): M=4096, N=3072, grid 768
    mgemm<<<24*32, 256, 0, stream>>>(xn, WqkvT, 24, 1024, 1, MODE_QKV, nullptr, nullptr, 0.125f, Qbuf, Kbuf, VTb);
    fixup_kernel<<<8, 256, 0, stream>>>(Kmb, Vmb, Kbuf, VTb);
    // attention
    attn_mfma<<<dim3(16,32), 256, 0, stream>>>(Qbuf, Kbuf, VTb, ao);
    // attended = x + ao @ Wo  (fp32)
    mgemm<<<8*32, 256, 0, stream>>>(ao, WoT, 8, 1024, 1, MODE_F32R, nullptr, x, 1.f, attb, nullptr, nullptr);
    // mean pool, LSTM
    pool1_kernel<<<dim3(64,BB), 256, 0, stream>>>(attb, ppart);
    pool2_kernel<<<dim3(4,BB), 256, 0, stream>>>(ppart, pooled);
    gates_part<<<dim3(16,16,BB), 256, 0, stream>>>(pooled, h, Wih, Whh, gpart);
    lstm_kernel<<<8, 256, 0, stream>>>(gpart, b_ih, b_hh, c, newh, out + (size_t)RR*DD);
    vecmat_part<<<dim3(4,8,BB), 256, 0, stream>>>(newh, Wmp, vpart, DD, DD);
    vecmat_red<<<dim3(4,BB), 256, 0, stream>>>(vpart, mproj, DD);
    // mixed = attended + mproj (in place), hn = LN2(mixed) bf16
    ln_kernel<<<RR, 256, 0, stream>>>(attb, mproj, g2, be2, attb, nullptr, hn);
    // FFN1: act = gelu(hn @ W1 + bf1), grid 1024
    mgemm<<<32*32, 256, 0, stream>>>(hn, W1T, 32, 1024, 1, MODE_GELU, bf1, nullptr, 1.f, act, nullptr, nullptr);
    // FFN2 split-K=2: partials then reduce (+bias+resid)
    mgemm<<<8*32*2, 256, 0, stream>>>(act, W2T, 8, 2048, 2, MODE_PART, nullptr, nullptr, 1.f, yb, p1a, p1b);
    splitred<<<RR, 256, 0, stream>>>(yb, p1a, p1b, bf2, attb, yb);
    // out = LN3(y)
    ln_kernel<<<RR, 256, 0, stream>>>(yb, nullptr, g3, be3, nullptr, out, nullptr);
}

// Round 7
// 369.208 us; speedup vs baseline: 12.4073x; 1.0839x over previous
//
#include <hip/hip_runtime.h>
#include <hip/hip_bf16.h>
#include <math.h>

#define BB 2
#define SS 2048
#define DD 1024
#define HH 16
#define RR (BB*SS)
#define KSTRIDE 2064   // padded key stride per (b,h)
#define MB (1024ull*1024ull)

typedef unsigned short u16;
typedef unsigned int u32;
typedef __attribute__((ext_vector_type(8))) short short8v;
typedef __attribute__((ext_vector_type(4))) float f32x4;
typedef __attribute__((ext_vector_type(16))) float f32x16;
typedef __attribute__((ext_vector_type(4))) u16 u16x4;

__device__ __forceinline__ u16 f2bf(float f){
    union { __hip_bfloat16 h; u16 u; } c; c.h = __float2bfloat16(f); return c.u;
}
__device__ __forceinline__ u32 pk2(float a, float b){
    return (u32)f2bf(a) | ((u32)f2bf(b) << 16);
}
// A&S 7.1.26 erf approximation, |err| <= 1.5e-7 (<< bf16 rounding of act)
__device__ __forceinline__ float erf_fast(float x){
    float ax = fabsf(x);
    float t = __builtin_amdgcn_rcpf(1.0f + 0.3275911f*ax);
    float y = t*(0.254829592f + t*(-0.284496736f + t*(1.421413741f + t*(-1.453152027f + t*1.061405429f))));
    float r = 1.0f - y*__expf(-ax*ax);
    return copysignf(r, x);
}

#define GLL16(gp, lp) __builtin_amdgcn_global_load_lds( \
    (const __attribute__((address_space(1))) void*)(gp), \
    (__attribute__((address_space(3))) void*)(lp), 16, 0, 0)

// ---------------- LayerNorm: fp32 in, optional broadcast add, fp32 and/or bf16 out ----------------
__global__ __launch_bounds__(256) void ln_kernel(const float* __restrict__ in,
    const float* __restrict__ mproj, const float* __restrict__ g, const float* __restrict__ be,
    float* __restrict__ mixed_out, float* __restrict__ outf, u16* __restrict__ outb)
{
    int row = blockIdx.x; int b = row / SS; int tid = threadIdx.x;
    float4 v = ((const float4*)(in + (size_t)row*DD))[tid];
    if (mproj){
        float4 mp = ((const float4*)(mproj + (size_t)b*DD))[tid];
        v.x+=mp.x; v.y+=mp.y; v.z+=mp.z; v.w+=mp.w;
        ((float4*)(mixed_out + (size_t)row*DD))[tid] = v;
    }
    float s = v.x+v.y+v.z+v.w, s2 = v.x*v.x+v.y*v.y+v.z*v.z+v.w*v.w;
    #pragma unroll
    for (int off=32; off>0; off>>=1){ s += __shfl_down(s,off); s2 += __shfl_down(s2,off); }
    __shared__ float red[2][4];
    if ((tid&63)==0){ red[0][tid>>6]=s; red[1][tid>>6]=s2; }
    __syncthreads();
    float st = red[0][0]+red[0][1]+red[0][2]+red[0][3];
    float s2t= red[1][0]+red[1][1]+red[1][2]+red[1][3];
    float mean = st*(1.f/DD); float var = s2t*(1.f/DD)-mean*mean;
    float rs = rsqrtf(var + 1e-5f);
    float4 gg=((const float4*)g)[tid], bb2=((const float4*)be)[tid];
    float o0=(v.x-mean)*rs*gg.x+bb2.x, o1=(v.y-mean)*rs*gg.y+bb2.y;
    float o2=(v.z-mean)*rs*gg.z+bb2.z, o3=(v.w-mean)*rs*gg.w+bb2.w;
    if (outf){ float4 o={o0,o1,o2,o3}; ((float4*)(outf+(size_t)row*DD))[tid]=o; }
    if (outb){ u16x4 o={f2bf(o0),f2bf(o1),f2bf(o2),f2bf(o3)}; ((u16x4*)(outb+(size_t)row*DD))[tid]=o; }
}

// ---------------- final: y = p0+p1+bias+resid, out = LN(y) (fused splitred+LN3) ----------------
__global__ __launch_bounds__(256) void ln3f_kernel(const float* __restrict__ p0,
    const float* __restrict__ p1a, const float* __restrict__ p1b,
    const float* __restrict__ bias, const float* __restrict__ resid,
    const float* __restrict__ g, const float* __restrict__ be, float* __restrict__ out)
{
    int row = blockIdx.x; int tid = threadIdx.x;
    const float* p1 = (row < 2048) ? (p1a + (size_t)row*DD) : (p1b + (size_t)(row-2048)*DD);
    float4 a  = ((const float4*)(p0 + (size_t)row*DD))[tid];
    float4 b  = ((const float4*)p1)[tid];
    float4 bi = ((const float4*)bias)[tid];
    float4 rs4= ((const float4*)(resid + (size_t)row*DD))[tid];
    float4 v = {a.x+b.x+bi.x+rs4.x, a.y+b.y+bi.y+rs4.y, a.z+b.z+bi.z+rs4.z, a.w+b.w+bi.w+rs4.w};
    float s = v.x+v.y+v.z+v.w, s2 = v.x*v.x+v.y*v.y+v.z*v.z+v.w*v.w;
    #pragma unroll
    for (int off=32; off>0; off>>=1){ s += __shfl_down(s,off); s2 += __shfl_down(s2,off); }
    __shared__ float red[2][4];
    if ((tid&63)==0){ red[0][tid>>6]=s; red[1][tid>>6]=s2; }
    __syncthreads();
    float st = red[0][0]+red[0][1]+red[0][2]+red[0][3];
    float s2t= red[1][0]+red[1][1]+red[1][2]+red[1][3];
    float mean = st*(1.f/DD); float var = s2t*(1.f/DD)-mean*mean;
    float rs = rsqrtf(var + 1e-5f);
    float4 gg=((const float4*)g)[tid], bb2=((const float4*)be)[tid];
    float4 o;
    o.x=(v.x-mean)*rs*gg.x+bb2.x; o.y=(v.y-mean)*rs*gg.y+bb2.y;
    o.z=(v.z-mean)*rs*gg.z+bb2.z; o.w=(v.w-mean)*rs*gg.w+bb2.w;
    ((float4*)(out + (size_t)row*DD))[tid] = o;
}

// ---------------- fp32 [K][N] -> bf16 [N][K] transpose ----------------
__global__ __launch_bounds__(256) void tr_kernel(const float* __restrict__ in, u16* __restrict__ out,
                                                 int K, int N)
{
    __shared__ float t[32][33];
    int n0 = blockIdx.x*32, k0 = blockIdx.y*32;
    int tx = threadIdx.x & 31, ty = threadIdx.x >> 5;   // ty 0..7
    #pragma unroll
    for (int i=0;i<4;i++){ int k = ty + i*8; t[k][tx] = in[(size_t)(k0+k)*N + n0 + tx]; }
    __syncthreads();
    #pragma unroll
    for (int i=0;i<4;i++){ int n = ty + i*8; out[(size_t)(n0+n)*K + k0 + tx] = f2bf(t[tx][n]); }
}

// ---------------- bf16 MFMA GEMM (SWAPPED operands: per-thread frag is 4-consecutive-N) ----------------
#define MODE_QKV  0  // fused: n<1024 Q(bf16*scale), <2048 K-layout, else V^T-layout
#define MODE_F32R 3  // f32 + resid
#define MODE_GELU 4  // bf16, +bias, gelu (fast erf)
#define MODE_PART 6  // fp32 partial (split-K): chunk0->Cout, chunk1->C2a/C2b row-split at 2048

__global__ __launch_bounds__(256) void mgemm(const u16* __restrict__ A, const u16* __restrict__ BT,
    int nbx, int Kc, int kchunks, int mode,
    const float* __restrict__ bias, const float* __restrict__ resid, float scale,
    void* __restrict__ Cout, void* __restrict__ C2a, void* __restrict__ C2b)
{
    int tid=threadIdx.x, l=tid&63, w=tid>>6;
    // XCD-aware bijective swizzle (grid % 8 == 0)
    int nwg = gridDim.x;
    int qq = nwg >> 3;
    int bid = blockIdx.x;
    int swz = (bid & 7)*qq + (bid >> 3);
    int tiles = nwg / kchunks;
    int chunk = swz / tiles;
    int t2 = swz % tiles;
    int bx = t2 % nbx, by = t2 / nbx;

    int bm = by*128, bn = bx*128;
    int N = nbx*128;
    int lda = Kc*kchunks;
    int koff = chunk*Kc;
    int wr = w>>1, wc = w&1;
    f32x4 acc[4][4];
    #pragma unroll
    for(int i=0;i<4;i++)
        #pragma unroll
        for(int j=0;j<4;j++)
            #pragma unroll
            for(int r=0;r<4;r++) acc[i][j][r]=0.f;

    __shared__ __align__(16) u16 Al[2][4096];
    __shared__ __align__(16) u16 Bl[2][4096];
    int srow = (w<<4) + (l>>2);     // staging row (+64 per issue)
    int sph  = l&3;                 // physical 16B slot
    const int NT = Kc >> 5;

    auto stage = [&](int buf, int kt){
        #pragma unroll
        for (int r=0;r<2;r++){
            int rowA = srow + r*64;
            int sl = sph ^ ((rowA>>1)&3);
            const u16* gA = A + (size_t)(bm+rowA)*lda + koff + kt*32 + sl*8;
            GLL16(gA, (char*)&Al[buf][0] + r*4096 + w*1024);
            const u16* gB = BT + (size_t)(bn+rowA)*lda + koff + kt*32 + sl*8;
            GLL16(gB, (char*)&Bl[buf][0] + r*4096 + w*1024);
        }
    };

    int cur=0;
    stage(0,0);
    __syncthreads();
    for (int kt=0; kt<NT; kt++){
        if (kt+1<NT) stage(cur^1, kt+1);
        short8v af[4], bf[4];
        #pragma unroll
        for (int mi=0;mi<4;mi++){
            int row = wr*64 + mi*16 + (l&15);
            int sl = (l>>4) ^ ((row>>1)&3);
            af[mi] = *(const short8v*)((const char*)&Al[cur][0] + row*64 + sl*16);
        }
        #pragma unroll
        for (int ni=0;ni<4;ni++){
            int row = wc*64 + ni*16 + (l&15);
            int sl = (l>>4) ^ ((row>>1)&3);
            bf[ni] = *(const short8v*)((const char*)&Bl[cur][0] + row*64 + sl*16);
        }
        // swapped: D^T = B^T * A^T  ->  per-thread 4 consecutive n at fixed m
        #pragma unroll
        for (int mi=0;mi<4;mi++)
            #pragma unroll
            for (int ni=0;ni<4;ni++)
                acc[mi][ni] = __builtin_amdgcn_mfma_f32_16x16x32_bf16(bf[ni], af[mi], acc[mi][ni], 0,0,0);
        __syncthreads();
        cur ^= 1;
    }

    #pragma unroll
    for (int mi=0;mi<4;mi++){
        int m = bm + wr*64 + mi*16 + (l&15);
        #pragma unroll
        for (int ni=0;ni<4;ni++){
            int nb = bn + wc*64 + ni*16 + ((l>>4)<<2);
            f32x4 v = acc[mi][ni];
            if (mode==MODE_QKV){
                if (nb < 1024){
                    u16x4 o;
                    #pragma unroll
                    for (int r=0;r<4;r++) o[r] = f2bf(v[r]*scale);
                    *(u16x4*)((u16*)Cout + (size_t)m*1024 + nb) = o;
                } else if (nb < 2048){
                    int cc = nb-1024; int hh = cc>>6, dh = cc&63;
                    int b2 = m>>11, key = m&2047;
                    u16x4 o;
                    #pragma unroll
                    for (int r=0;r<4;r++) o[r] = f2bf(v[r]);
                    *(u16x4*)((u16*)C2a + ((size_t)(b2*HH+hh)*KSTRIDE + key)*64 + dh) = o;
                } else {
                    int cc = nb-2048; int hh = cc>>6, dh = cc&63;
                    int b2 = m>>11, key = m&2047;
                    #pragma unroll
                    for (int r=0;r<4;r++)
                        ((u16*)C2b)[((size_t)(b2*HH+hh)*64 + dh + r)*KSTRIDE + key] = f2bf(v[r]);
                }
            } else if (mode==MODE_F32R){
                float4 rs = *(const float4*)(resid + (size_t)m*N + nb);
                float4 o = {v[0]+rs.x, v[1]+rs.y, v[2]+rs.z, v[3]+rs.w};
                *(float4*)((float*)Cout + (size_t)m*N + nb) = o;
            } else if (mode==MODE_GELU){
                float4 bi = *(const float4*)(bias + nb);
                float t0=v[0]+bi.x, t1=v[1]+bi.y, t2=v[2]+bi.z, t3=v[3]+bi.w;
                u16x4 o;
                o[0]=f2bf(0.5f*t0*(1.0f+erf_fast(t0*0.70710678118654752f)));
                o[1]=f2bf(0.5f*t1*(1.0f+erf_fast(t1*0.70710678118654752f)));
                o[2]=f2bf(0.5f*t2*(1.0f+erf_fast(t2*0.70710678118654752f)));
                o[3]=f2bf(0.5f*t3*(1.0f+erf_fast(t3*0.70710678118654752f)));
                *(u16x4*)((u16*)Cout + (size_t)m*N + nb) = o;
            } else { // MODE_PART
                float4 o = {v[0],v[1],v[2],v[3]};
                if (chunk==0)       *(float4*)((float*)Cout + (size_t)m*N + nb) = o;
                else if (m < 2048)  *(float4*)((float*)C2a  + (size_t)m*N + nb) = o;
                else                *(float4*)((float*)C2b  + (size_t)(m-2048)*N + nb) = o;
            }
        }
    }
}

// ---------------- MFMA flash attention: 32x32x16, swapped QK^T, V pre-transposed ----------------
__global__ __launch_bounds__(256) void attn_mfma(const u16* __restrict__ Qb, const u16* __restrict__ Kb,
    const u16* __restrict__ VTb, u16* __restrict__ ao)
{
    __shared__ __align__(16) u16 Kl[2][4096];  // [key 64][dh 64], slot-XOR swizzled
    __shared__ __align__(16) u16 Vl[2][4096];  // [dh 64][key 64], slot-XOR swizzled
    int tid=threadIdx.x, l=tid&63, w=tid>>6;
    int l31=l&31, hi=l>>5;
    int qt=blockIdx.x, bh=blockIdx.y; int b=bh>>4, h=bh&15;
    int qrow = qt*128 + w*32 + l31;

    const u16* qptr = Qb + (size_t)(b*SS + qrow)*DD + h*64;
    short8v qf[4];
    #pragma unroll
    for (int t=0;t<4;t++) qf[t] = *(const short8v*)(qptr + t*16 + hi*8);

    f32x16 so0, so1;
    #pragma unroll
    for (int i=0;i<16;i++){ so0[i]=0.f; so1[i]=0.f; }
    float m_run=-1e30f, l_run=0.f;

    int skey = (w<<3) + (l>>3);   // staging row (+32 per issue)
    int ssl  = l&7;
    auto stage = [&](int buf, int kt){
        #pragma unroll
        for (int r=0;r<2;r++){
            int key = skey + r*32;
            int slot = ssl ^ (key&7);
            const u16* gK = Kb + ((size_t)bh*KSTRIDE + kt*64 + key)*64 + slot*8;
            GLL16(gK, (char*)&Kl[buf][0] + r*4096 + w*1024);
            const u16* gV = VTb + ((size_t)bh*64 + key)*KSTRIDE + kt*64 + slot*8;
            GLL16(gV, (char*)&Vl[buf][0] + r*4096 + w*1024);
        }
    };

    int cur=0;
    stage(0,0);
    __syncthreads();
    const int NTILE = 33;
    for (int kt=0; kt<NTILE; kt++){
        if (kt+1<NTILE) stage(cur^1, kt+1);
        f32x16 ss0, ss1;
        #pragma unroll
        for (int i=0;i<16;i++){ ss0[i]=0.f; ss1[i]=0.f; }
        __builtin_amdgcn_s_setprio(1);
        #pragma unroll
        for (int t=0;t<4;t++){
            int sl = (2*t+hi) ^ (l31&7);
            short8v kf0 = *(const short8v*)((const char*)&Kl[cur][0] + l31*128 + sl*16);
            ss0 = __builtin_amdgcn_mfma_f32_32x32x16_bf16(kf0, qf[t], ss0, 0,0,0);
            short8v kf1 = *(const short8v*)((const char*)&Kl[cur][0] + (32+l31)*128 + sl*16);
            ss1 = __builtin_amdgcn_mfma_f32_32x32x16_bf16(kf1, qf[t], ss1, 0,0,0);
        }
        __builtin_amdgcn_s_setprio(0);
        if (kt == NTILE-1){
            #pragma unroll
            for (int r=0;r<16;r++){
                int k0 = 2048 + (r&3) + 8*(r>>2) + 4*hi;
                if (k0 >= 2049) ss0[r] = -1e30f;
                ss1[r] = -1e30f;   // keys 2080..2111 all masked
            }
        }
        float tmax=-1e30f;
        #pragma unroll
        for (int r=0;r<16;r++){ tmax=fmaxf(tmax, ss0[r]); tmax=fmaxf(tmax, ss1[r]); }
        tmax = fmaxf(tmax, __shfl_xor(tmax, 32));
        // defer-max (T13): skip rescale when per-row max growth <= 8 for all rows in wave
        if (!__all(tmax <= m_run + 8.0f)){
            float mnew = fmaxf(m_run, tmax);
            float alpha = __expf(m_run - mnew);
            l_run *= alpha;
            so0 *= alpha; so1 *= alpha;
            m_run = mnew;
        }
        float psum = 0.f;
        #pragma unroll
        for (int r=0;r<16;r++){
            float p=__expf(ss0[r]-m_run); ss0[r]=p; psum+=p;
            float q=__expf(ss1[r]-m_run); ss1[r]=q; psum+=q;
        }
        psum += __shfl_xor(psum, 32);
        l_run += psum;

        short8v pf[4];
        #pragma unroll
        for (int t=0;t<4;t++){
            u32 a0,a1,b0,b1;
            if (t==0){ a0=pk2(ss0[0],ss0[1]);   a1=pk2(ss0[2],ss0[3]);   b0=pk2(ss0[4],ss0[5]);   b1=pk2(ss0[6],ss0[7]); }
            else if (t==1){ a0=pk2(ss0[8],ss0[9]);   a1=pk2(ss0[10],ss0[11]); b0=pk2(ss0[12],ss0[13]); b1=pk2(ss0[14],ss0[15]); }
            else if (t==2){ a0=pk2(ss1[0],ss1[1]);   a1=pk2(ss1[2],ss1[3]);   b0=pk2(ss1[4],ss1[5]);   b1=pk2(ss1[6],ss1[7]); }
            else          { a0=pk2(ss1[8],ss1[9]);   a1=pk2(ss1[10],ss1[11]); b0=pk2(ss1[12],ss1[13]); b1=pk2(ss1[14],ss1[15]); }
            u32 s0 = hi ? a0 : b0, s1 = hi ? a1 : b1;
            u32 r0 = (u32)__shfl_xor((int)s0, 32);
            u32 r1 = (u32)__shfl_xor((int)s1, 32);
            union { u32 u[4]; short8v v; } cvt;
            cvt.u[0] = hi ? r0 : a0;
            cvt.u[1] = hi ? r1 : a1;
            cvt.u[2] = hi ? b0 : r0;
            cvt.u[3] = hi ? b1 : r1;
            pf[t] = cvt.v;
        }
        __builtin_amdgcn_s_setprio(1);
        #pragma unroll
        for (int t=0;t<4;t++){
            int sl = (2*t+hi) ^ (l31&7);
            short8v vf0 = *(const short8v*)((const char*)&Vl[cur][0] + l31*128 + sl*16);
            so0 = __builtin_amdgcn_mfma_f32_32x32x16_bf16(vf0, pf[t], so0, 0,0,0);
            short8v vf1 = *(const short8v*)((const char*)&Vl[cur][0] + (32+l31)*128 + sl*16);
            so1 = __builtin_amdgcn_mfma_f32_32x32x16_bf16(vf1, pf[t], so1, 0,0,0);
        }
        __builtin_amdgcn_s_setprio(0);
        __syncthreads();
        cur ^= 1;
    }
    float inv = 1.f / l_run;
    u16* aop = ao + (size_t)(b*SS + qrow)*DD + h*64;
    #pragma unroll
    for (int rg=0; rg<4; rg++){
        int dh0 = rg*8 + 4*hi;
        u16x4 o0, o1;
        #pragma unroll
        for (int j=0;j<4;j++){ o0[j]=f2bf(so0[rg*4+j]*inv); o1[j]=f2bf(so1[rg*4+j]*inv); }
        *(u16x4*)(aop + dh0) = o0;
        *(u16x4*)(aop + 32 + dh0) = o1;
    }
}

// ---------------- split-K matvec ----------------
__global__ __launch_bounds__(256) void vecmat_part(const float* __restrict__ vec,
    const float* __restrict__ W, float* __restrict__ part, int K, int N)
{
    int b = blockIdx.z, kc = blockIdx.y;
    int j = blockIdx.x*256 + threadIdx.x;
    int k0 = kc * (K >> 3);
    float acc = 0.0f;
    #pragma unroll 4
    for (int k = k0; k < k0 + (K >> 3); k++)
        acc += vec[(size_t)b*K + k] * W[(size_t)k*N + j];
    part[((size_t)b*8 + kc)*N + j] = acc;
}

__global__ __launch_bounds__(256) void vecmat_red(const float* __restrict__ part,
    float* __restrict__ out, int N)
{
    int b = blockIdx.y;
    int j = blockIdx.x*256 + threadIdx.x;
    float acc = 0.0f;
    #pragma unroll
    for (int kc = 0; kc < 8; kc++) acc += part[((size_t)b*8 + kc)*N + j];
    out[(size_t)b*N + j] = acc;
}

// fused Km/Vm: reads h once, both weights
__global__ __launch_bounds__(256) void vecmat2_part(const float* __restrict__ vec,
    const float* __restrict__ Wa, const float* __restrict__ Wb, float* __restrict__ part)
{
    int b = blockIdx.z, kc = blockIdx.y;
    int j = blockIdx.x*256 + threadIdx.x;
    int k0 = kc * 128;
    float accA = 0.0f, accB = 0.0f;
    #pragma unroll 4
    for (int k = k0; k < k0 + 128; k++){
        float v = vec[(size_t)b*DD + k];
        accA += v * Wa[(size_t)k*DD + j];
        accB += v * Wb[(size_t)k*DD + j];
    }
    part[((size_t)b*8 + kc)*2048 + j] = accA;
    part[((size_t)b*8 + kc)*2048 + 1024 + j] = accB;
}

__global__ __launch_bounds__(256) void vecmat2_red(const float* __restrict__ part,
    float* __restrict__ outA, float* __restrict__ outB)
{
    int b = blockIdx.y;
    int j = blockIdx.x*256 + threadIdx.x;
    float accA = 0.0f, accB = 0.0f;
    #pragma unroll
    for (int kc = 0; kc < 8; kc++){
        accA += part[((size_t)b*8 + kc)*2048 + j];
        accB += part[((size_t)b*8 + kc)*2048 + 1024 + j];
    }
    outA[(size_t)b*DD + j] = accA;
    outB[(size_t)b*DD + j] = accB;
}

// ---------------- K/V memory-token fixup ----------------
__global__ __launch_bounds__(256) void fixup_kernel(const float* __restrict__ Kmb,
    const float* __restrict__ Vmb, u16* __restrict__ Kb, u16* __restrict__ VTb)
{
    int idx = blockIdx.x*256 + threadIdx.x;   // 0..2047
    int b = idx>>10, j = idx&1023; int h=j>>6, dh=j&63; int bh=b*HH+h;
    Kb[((size_t)bh*KSTRIDE + 2048)*64 + dh] = f2bf(Kmb[idx]);
    VTb[((size_t)bh*64 + dh)*KSTRIDE + 2048] = f2bf(Vmb[idx]);
}

// ---------------- mean pool: 64 chunks of 32 rows, then reduce ----------------
__global__ __launch_bounds__(256) void pool1_kernel(const float* __restrict__ att, float* __restrict__ ppart)
{
    int b = blockIdx.y, sc = blockIdx.x;   // sc 0..63
    int tid = threadIdx.x;
    float4 acc = {0,0,0,0};
    for (int s = 0; s < 32; s++) {
        int row = b*SS + sc*32 + s;
        float4 v = ((const float4*)(att + (size_t)row*DD))[tid];
        acc.x += v.x; acc.y += v.y; acc.z += v.z; acc.w += v.w;
    }
    ((float4*)(ppart + ((size_t)b*64 + sc)*DD))[tid] = acc;
}

__global__ __launch_bounds__(256) void pool2_kernel(const float* __restrict__ ppart, float* __restrict__ pooled)
{
    int b = blockIdx.y;
    int j = blockIdx.x*256 + threadIdx.x;
    float acc = 0.0f;
    for (int sc = 0; sc < 64; sc++) acc += ppart[((size_t)b*64 + sc)*DD + j];
    pooled[(size_t)b*DD + j] = acc * (1.0f/SS);
}

// ---------------- LSTM gates split-K (16 chunks) ----------------
__global__ __launch_bounds__(256) void gates_part(const float* __restrict__ pooled,
    const float* __restrict__ h, const float* __restrict__ Wih, const float* __restrict__ Whh,
    float* __restrict__ part)
{
    int b = blockIdx.z, kc = blockIdx.y;   // kc 0..15
    int j = blockIdx.x*256 + threadIdx.x;  // 0..4095
    int k0 = kc * 64;
    float acc = 0.0f;
    #pragma unroll 4
    for (int k = k0; k < k0 + 64; k++)
        acc += pooled[(size_t)b*DD + k] * Wih[(size_t)k*4*DD + j]
             + h[(size_t)b*DD + k]      * Whh[(size_t)k*4*DD + j];
    part[((size_t)b*16 + kc)*4*DD + j] = acc;
}

__device__ __forceinline__ float sigmoidf_(float x) { return 1.0f / (1.0f + __expf(-x)); }

__global__ __launch_bounds__(256) void lstm_kernel(const float* __restrict__ gpart,
    const float* __restrict__ b_ih, const float* __restrict__ b_hh,
    const float* __restrict__ c, float* __restrict__ newh_ws, float* __restrict__ out_tail)
{
    int idx = blockIdx.x*256 + threadIdx.x;   // 0..2047
    int b = idx >> 10, d = idx & 1023;
    float sI = b_ih[d]          + b_hh[d];
    float sF = b_ih[DD + d]     + b_hh[DD + d];
    float sG = b_ih[2*DD + d]   + b_hh[2*DD + d];
    float sO = b_ih[3*DD + d]   + b_hh[3*DD + d];
    #pragma unroll
    for (int kc = 0; kc < 16; kc++){
        const float* gp = gpart + ((size_t)b*16 + kc)*4*DD;
        sI += gp[d]; sF += gp[DD + d]; sG += gp[2*DD + d]; sO += gp[3*DD + d];
    }
    float ig = sigmoidf_(sI);
    float fg = sigmoidf_(sF);
    float gg = tanhf(sG);
    float og = sigmoidf_(sO);
    float nc = fg * c[idx] + ig * gg;
    float nh = og * tanhf(nc);
    newh_ws[idx] = nh;
    out_tail[idx] = nh;
    out_tail[BB*DD + idx] = nc;
}

// ---------------- launch ----------------
extern "C" void kernel_launch(void* const* d_in, const int* in_sizes, int n_in,
                              void* d_out, int out_size, void* d_ws, size_t ws_size,
                              hipStream_t stream) {
    const float* x    = (const float*)d_in[0];
    const float* h    = (const float*)d_in[1];
    const float* c    = (const float*)d_in[2];
    const float* Wq   = (const float*)d_in[3];
    const float* Wk   = (const float*)d_in[4];
    const float* Wv   = (const float*)d_in[5];
    const float* Wo   = (const float*)d_in[6];
    const float* Wmk  = (const float*)d_in[7];
    const float* Wmv  = (const float*)d_in[8];
    const float* Wih  = (const float*)d_in[9];
    const float* Whh  = (const float*)d_in[10];
    const float* b_ih = (const float*)d_in[11];
    const float* b_hh = (const float*)d_in[12];
    const float* W1   = (const float*)d_in[13];
    const float* bf1  = (const float*)d_in[14];
    const float* W2   = (const float*)d_in[15];
    const float* bf2  = (const float*)d_in[16];
    const float* g1   = (const float*)d_in[17];
    const float* be1  = (const float*)d_in[18];
    const float* g2   = (const float*)d_in[19];
    const float* be2  = (const float*)d_in[20];
    const float* g3   = (const float*)d_in[21];
    const float* be3  = (const float*)d_in[22];
    const float* Wmp  = (const float*)d_in[23];

    float* out = (float*)d_out;
    char* wsb  = (char*)d_ws;

    u16*   xn   = (u16*)(wsb + 0);        // 8MB  [0,8)
    u16*   hn   = (u16*)(wsb + 8*MB);     // 8MB  [8,16)
    float* p0   = (float*)(wsb + 0);      // 16MB overlay [0,16) (xn,hn dead) = FFN2 partial0
    u16*   Qbuf = (u16*)(wsb + 16*MB);    // 8MB  [16,24)
    u16*   Kbuf = (u16*)(wsb + 24*MB);    // 8.5MB [24,33)
    u16*   VTb  = (u16*)(wsb + 33*MB);    // 8.5MB [33,42)
    u16*   act  = (u16*)(wsb + 16*MB);    // 32MB overlay [16,48) (Q/K/VT dead)
    u16*   ao   = (u16*)(wsb + 48*MB);    // 8MB  [48,56)
    float* p1a  = (float*)(wsb + 48*MB);  // FFN2 partial1 rows 0..2047 (ao dead)
    float* attb = (float*)(wsb + 56*MB);  // 16MB [56,72)
    u16*   WqkvT= (u16*)(wsb + 72*MB);    // 6MB [72,78)
    u16*   WoT  = (u16*)(wsb + 78*MB);    // 2MB [78,80)
    u16*   W1T  = (u16*)(wsb + 80*MB);    // 8MB [80,88)
    float* p1b  = (float*)(wsb + 80*MB);  // FFN2 partial1 rows 2048..4095 (W1T dead)
    u16*   W2T  = (u16*)(wsb + 88*MB);    // 8MB [88,96)
    float* sm   = (float*)(wsb + 96*MB);
    float* Kmb     = sm;
    float* Vmb     = Kmb + 2048;
    float* pooled  = Vmb + 2048;
    float* newh    = pooled + 2048;
    float* mproj   = newh + 2048;
    float* vpart   = mproj + 2048;             // 16384
    float* v2part  = vpart + 16384;            // 32768
    float* gpart   = v2part + 32768;           // 131072
    float* ppart   = gpart + 131072;           // 131072

    // weight transposes (fp32 [K][N] -> bf16 [N][K])
    tr_kernel<<<dim3(32,32), 256, 0, stream>>>(Wq, WqkvT,             1024, 1024);
    tr_kernel<<<dim3(32,32), 256, 0, stream>>>(Wk, WqkvT + 1024*1024, 1024, 1024);
    tr_kernel<<<dim3(32,32), 256, 0, stream>>>(Wv, WqkvT + 2048*1024, 1024, 1024);
    tr_kernel<<<dim3(32,32), 256, 0, stream>>>(Wo, WoT, 1024, 1024);
    tr_kernel<<<dim3(128,32), 256, 0, stream>>>(W1, W1T, 1024, 4096);
    tr_kernel<<<dim3(32,128), 256, 0, stream>>>(W2, W2T, 4096, 1024);

    // LN1 -> xn bf16
    ln_kernel<<<RR, 256, 0, stream>>>(x, nullptr, g1, be1, nullptr, nullptr, xn);
    // memory K/V tokens (fp32, split-K, fused)
    vecmat2_part<<<dim3(4,8,BB), 256, 0, stream>>>(h, Wmk, Wmv, v2part);
    vecmat2_red<<<dim3(4,BB), 256, 0, stream>>>(v2part, Kmb, Vmb);
    // fused QKV projection (MFMA): M=4096, N=3072, grid 768
    mgemm<<<24*32, 256, 0, stream>>>(xn, WqkvT, 24, 1024, 1, MODE_QKV, nullptr, nullptr, 0.125f, Qbuf, Kbuf, VTb);
    fixup_kernel<<<8, 256, 0, stream>>>(Kmb, Vmb, Kbuf, VTb);
    // attention
    attn_mfma<<<dim3(16,32), 256, 0, stream>>>(Qbuf, Kbuf, VTb, ao);
    // attended = x + ao @ Wo  (fp32)
    mgemm<<<8*32, 256, 0, stream>>>(ao, WoT, 8, 1024, 1, MODE_F32R, nullptr, x, 1.f, attb, nullptr, nullptr);
    // mean pool, LSTM
    pool1_kernel<<<dim3(64,BB), 256, 0, stream>>>(attb, ppart);
    pool2_kernel<<<dim3(4,BB), 256, 0, stream>>>(ppart, pooled);
    gates_part<<<dim3(16,16,BB), 256, 0, stream>>>(pooled, h, Wih, Whh, gpart);
    lstm_kernel<<<8, 256, 0, stream>>>(gpart, b_ih, b_hh, c, newh, out + (size_t)RR*DD);
    vecmat_part<<<dim3(4,8,BB), 256, 0, stream>>>(newh, Wmp, vpart, DD, DD);
    vecmat_red<<<dim3(4,BB), 256, 0, stream>>>(vpart, mproj, DD);
    // mixed = attended + mproj (in place), hn = LN2(mixed) bf16
    ln_kernel<<<RR, 256, 0, stream>>>(attb, mproj, g2, be2, attb, nullptr, hn);
    // FFN1: act = gelu(hn @ W1 + bf1), grid 1024
    mgemm<<<32*32, 256, 0, stream>>>(hn, W1T, 32, 1024, 1, MODE_GELU, bf1, nullptr, 1.f, act, nullptr, nullptr);
    // FFN2 split-K=2: partials
    mgemm<<<8*32*2, 256, 0, stream>>>(act, W2T, 8, 2048, 2, MODE_PART, nullptr, nullptr, 1.f, p0, p1a, p1b);
    // out = LN3(p0+p1+bias+resid)  (fused reduce)
    ln3f_kernel<<<RR, 256, 0, stream>>>(p0, p1a, p1b, bf2, attb, g3, be3, out);
}

// Round 8
// 361.910 us; speedup vs baseline: 12.6575x; 1.0202x over previous
//
#include <hip/hip_runtime.h>
#include <hip/hip_bf16.h>
#include <math.h>

#define BB 2
#define SS 2048
#define DD 1024
#define HH 16
#define RR (BB*SS)
#define KSTRIDE 2064   // padded key stride per (b,h)
#define MB (1024ull*1024ull)

typedef unsigned short u16;
typedef unsigned int u32;
typedef __attribute__((ext_vector_type(8))) short short8v;
typedef __attribute__((ext_vector_type(4))) float f32x4;
typedef __attribute__((ext_vector_type(16))) float f32x16;
typedef __attribute__((ext_vector_type(4))) u16 u16x4;

__device__ __forceinline__ u16 f2bf(float f){
    union { __hip_bfloat16 h; u16 u; } c; c.h = __float2bfloat16(f); return c.u;
}
__device__ __forceinline__ u32 pk2(float a, float b){
    return (u32)f2bf(a) | ((u32)f2bf(b) << 16);
}
// A&S 7.1.26 erf approximation, |err| <= 1.5e-7 (<< bf16 rounding of act)
__device__ __forceinline__ float erf_fast(float x){
    float ax = fabsf(x);
    float t = __builtin_amdgcn_rcpf(1.0f + 0.3275911f*ax);
    float y = t*(0.254829592f + t*(-0.284496736f + t*(1.421413741f + t*(-1.453152027f + t*1.061405429f))));
    float r = 1.0f - y*__expf(-ax*ax);
    return copysignf(r, x);
}

#define GLL16(gp, lp) __builtin_amdgcn_global_load_lds( \
    (const __attribute__((address_space(1))) void*)(gp), \
    (__attribute__((address_space(3))) void*)(lp), 16, 0, 0)

// ---------------- LayerNorm: fp32 in, optional broadcast add, fp32 and/or bf16 out ----------------
__global__ __launch_bounds__(256) void ln_kernel(const float* __restrict__ in,
    const float* __restrict__ mproj, const float* __restrict__ g, const float* __restrict__ be,
    float* __restrict__ mixed_out, float* __restrict__ outf, u16* __restrict__ outb)
{
    int row = blockIdx.x; int b = row / SS; int tid = threadIdx.x;
    float4 v = ((const float4*)(in + (size_t)row*DD))[tid];
    if (mproj){
        float4 mp = ((const float4*)(mproj + (size_t)b*DD))[tid];
        v.x+=mp.x; v.y+=mp.y; v.z+=mp.z; v.w+=mp.w;
        ((float4*)(mixed_out + (size_t)row*DD))[tid] = v;
    }
    float s = v.x+v.y+v.z+v.w, s2 = v.x*v.x+v.y*v.y+v.z*v.z+v.w*v.w;
    #pragma unroll
    for (int off=32; off>0; off>>=1){ s += __shfl_down(s,off); s2 += __shfl_down(s2,off); }
    __shared__ float red[2][4];
    if ((tid&63)==0){ red[0][tid>>6]=s; red[1][tid>>6]=s2; }
    __syncthreads();
    float st = red[0][0]+red[0][1]+red[0][2]+red[0][3];
    float s2t= red[1][0]+red[1][1]+red[1][2]+red[1][3];
    float mean = st*(1.f/DD); float var = s2t*(1.f/DD)-mean*mean;
    float rs = rsqrtf(var + 1e-5f);
    float4 gg=((const float4*)g)[tid], bb2=((const float4*)be)[tid];
    float o0=(v.x-mean)*rs*gg.x+bb2.x, o1=(v.y-mean)*rs*gg.y+bb2.y;
    float o2=(v.z-mean)*rs*gg.z+bb2.z, o3=(v.w-mean)*rs*gg.w+bb2.w;
    if (outf){ float4 o={o0,o1,o2,o3}; ((float4*)(outf+(size_t)row*DD))[tid]=o; }
    if (outb){ u16x4 o={f2bf(o0),f2bf(o1),f2bf(o2),f2bf(o3)}; ((u16x4*)(outb+(size_t)row*DD))[tid]=o; }
}

// ---------------- final: y = p0+p1+bias+resid, out = LN(y) (fused splitred+LN3) ----------------
__global__ __launch_bounds__(256) void ln3f_kernel(const float* __restrict__ p0,
    const float* __restrict__ p1a, const float* __restrict__ p1b,
    const float* __restrict__ bias, const float* __restrict__ resid,
    const float* __restrict__ g, const float* __restrict__ be, float* __restrict__ out)
{
    int row = blockIdx.x; int tid = threadIdx.x;
    const float* p1 = (row < 2048) ? (p1a + (size_t)row*DD) : (p1b + (size_t)(row-2048)*DD);
    float4 a  = ((const float4*)(p0 + (size_t)row*DD))[tid];
    float4 b  = ((const float4*)p1)[tid];
    float4 bi = ((const float4*)bias)[tid];
    float4 rs4= ((const float4*)(resid + (size_t)row*DD))[tid];
    float4 v = {a.x+b.x+bi.x+rs4.x, a.y+b.y+bi.y+rs4.y, a.z+b.z+bi.z+rs4.z, a.w+b.w+bi.w+rs4.w};
    float s = v.x+v.y+v.z+v.w, s2 = v.x*v.x+v.y*v.y+v.z*v.z+v.w*v.w;
    #pragma unroll
    for (int off=32; off>0; off>>=1){ s += __shfl_down(s,off); s2 += __shfl_down(s2,off); }
    __shared__ float red[2][4];
    if ((tid&63)==0){ red[0][tid>>6]=s; red[1][tid>>6]=s2; }
    __syncthreads();
    float st = red[0][0]+red[0][1]+red[0][2]+red[0][3];
    float s2t= red[1][0]+red[1][1]+red[1][2]+red[1][3];
    float mean = st*(1.f/DD); float var = s2t*(1.f/DD)-mean*mean;
    float rs = rsqrtf(var + 1e-5f);
    float4 gg=((const float4*)g)[tid], bb2=((const float4*)be)[tid];
    float4 o;
    o.x=(v.x-mean)*rs*gg.x+bb2.x; o.y=(v.y-mean)*rs*gg.y+bb2.y;
    o.z=(v.z-mean)*rs*gg.z+bb2.z; o.w=(v.w-mean)*rs*gg.w+bb2.w;
    ((float4*)(out + (size_t)row*DD))[tid] = o;
}

// ---------------- fp32 [K][N] -> bf16 [N][K] transpose ----------------
__global__ __launch_bounds__(256) void tr_kernel(const float* __restrict__ in, u16* __restrict__ out,
                                                 int K, int N)
{
    __shared__ float t[32][33];
    int n0 = blockIdx.x*32, k0 = blockIdx.y*32;
    int tx = threadIdx.x & 31, ty = threadIdx.x >> 5;   // ty 0..7
    #pragma unroll
    for (int i=0;i<4;i++){ int k = ty + i*8; t[k][tx] = in[(size_t)(k0+k)*N + n0 + tx]; }
    __syncthreads();
    #pragma unroll
    for (int i=0;i<4;i++){ int n = ty + i*8; out[(size_t)(n0+n)*K + k0 + tx] = f2bf(t[tx][n]); }
}

// ---------------- bf16 MFMA GEMM (swapped operands; chunked XCD swizzle) ----------------
#define MODE_QKV  0  // fused: n<1024 Q(bf16*scale), <2048 K-layout, else V^T-layout
#define MODE_F32R 3  // f32 + resid
#define MODE_GELU 4  // bf16, +bias, gelu (fast erf)
#define MODE_PART 6  // fp32 partial (split-K): chunk0->Cout, chunk1->C2a/C2b row-split at 2048

// requires nbx%8==0, nby==32, grid%8==0
__global__ __launch_bounds__(256) void mgemm(const u16* __restrict__ A, const u16* __restrict__ BT,
    int nbx, int Kc, int kchunks, int mode,
    const float* __restrict__ bias, const float* __restrict__ resid, float scale,
    void* __restrict__ Cout, void* __restrict__ C2a, void* __restrict__ C2b)
{
    int tid=threadIdx.x, l=tid&63, w=tid>>6;
    // XCD-aware bijective swizzle, then chunked 8x8 tile decode (L2-footprint <= ~4MB/XCD)
    int nwg = gridDim.x;
    int qq = nwg >> 3;
    int bid = blockIdx.x;
    int swz = (bid & 7)*qq + (bid >> 3);
    int tiles = nwg / kchunks;
    int chunk = swz / tiles;
    int t2 = swz % tiles;
    int sby = t2 / (nbx*8);
    int rem = t2 - sby*(nbx*8);
    int sbx = rem >> 6;
    int ci  = rem & 63;
    int bx = sbx*8 + (ci&7);
    int by = sby*8 + (ci>>3);

    int bm = by*128, bn = bx*128;
    int N = nbx*128;
    int lda = Kc*kchunks;
    int koff = chunk*Kc;
    int wr = w>>1, wc = w&1;
    f32x4 acc[4][4];
    #pragma unroll
    for(int i=0;i<4;i++)
        #pragma unroll
        for(int j=0;j<4;j++)
            #pragma unroll
            for(int r=0;r<4;r++) acc[i][j][r]=0.f;

    __shared__ __align__(16) u16 Al[2][4096];
    __shared__ __align__(16) u16 Bl[2][4096];
    int srow = (w<<4) + (l>>2);     // staging row (+64 per issue)
    int sph  = l&3;                 // physical 16B slot
    const int NT = Kc >> 5;

    auto stage = [&](int buf, int kt){
        #pragma unroll
        for (int r=0;r<2;r++){
            int rowA = srow + r*64;
            int sl = sph ^ ((rowA>>1)&3);
            const u16* gA = A + (size_t)(bm+rowA)*lda + koff + kt*32 + sl*8;
            GLL16(gA, (char*)&Al[buf][0] + r*4096 + w*1024);
            const u16* gB = BT + (size_t)(bn+rowA)*lda + koff + kt*32 + sl*8;
            GLL16(gB, (char*)&Bl[buf][0] + r*4096 + w*1024);
        }
    };

    int cur=0;
    stage(0,0);
    __syncthreads();
    for (int kt=0; kt<NT; kt++){
        if (kt+1<NT) stage(cur^1, kt+1);
        short8v af[4], bf[4];
        #pragma unroll
        for (int mi=0;mi<4;mi++){
            int row = wr*64 + mi*16 + (l&15);
            int sl = (l>>4) ^ ((row>>1)&3);
            af[mi] = *(const short8v*)((const char*)&Al[cur][0] + row*64 + sl*16);
        }
        #pragma unroll
        for (int ni=0;ni<4;ni++){
            int row = wc*64 + ni*16 + (l&15);
            int sl = (l>>4) ^ ((row>>1)&3);
            bf[ni] = *(const short8v*)((const char*)&Bl[cur][0] + row*64 + sl*16);
        }
        // swapped: per-thread frag is 4 consecutive n at fixed m
        #pragma unroll
        for (int mi=0;mi<4;mi++)
            #pragma unroll
            for (int ni=0;ni<4;ni++)
                acc[mi][ni] = __builtin_amdgcn_mfma_f32_16x16x32_bf16(bf[ni], af[mi], acc[mi][ni], 0,0,0);
        __syncthreads();
        cur ^= 1;
    }

    #pragma unroll
    for (int mi=0;mi<4;mi++){
        int m = bm + wr*64 + mi*16 + (l&15);
        #pragma unroll
        for (int ni=0;ni<4;ni++){
            int nb = bn + wc*64 + ni*16 + ((l>>4)<<2);
            f32x4 v = acc[mi][ni];
            if (mode==MODE_QKV){
                if (nb < 1024){
                    u16x4 o;
                    #pragma unroll
                    for (int r=0;r<4;r++) o[r] = f2bf(v[r]*scale);
                    *(u16x4*)((u16*)Cout + (size_t)m*1024 + nb) = o;
                } else if (nb < 2048){
                    int cc = nb-1024; int hh = cc>>6, dh = cc&63;
                    int b2 = m>>11, key = m&2047;
                    u16x4 o;
                    #pragma unroll
                    for (int r=0;r<4;r++) o[r] = f2bf(v[r]);
                    *(u16x4*)((u16*)C2a + ((size_t)(b2*HH+hh)*KSTRIDE + key)*64 + dh) = o;
                } else {
                    int cc = nb-2048; int hh = cc>>6, dh = cc&63;
                    int b2 = m>>11, key = m&2047;
                    #pragma unroll
                    for (int r=0;r<4;r++)
                        ((u16*)C2b)[((size_t)(b2*HH+hh)*64 + dh + r)*KSTRIDE + key] = f2bf(v[r]);
                }
            } else if (mode==MODE_F32R){
                float4 rs = *(const float4*)(resid + (size_t)m*N + nb);
                float4 o = {v[0]+rs.x, v[1]+rs.y, v[2]+rs.z, v[3]+rs.w};
                *(float4*)((float*)Cout + (size_t)m*N + nb) = o;
            } else if (mode==MODE_GELU){
                float4 bi = *(const float4*)(bias + nb);
                float t0=v[0]+bi.x, t1=v[1]+bi.y, t2=v[2]+bi.z, t3=v[3]+bi.w;
                u16x4 o;
                o[0]=f2bf(0.5f*t0*(1.0f+erf_fast(t0*0.70710678118654752f)));
                o[1]=f2bf(0.5f*t1*(1.0f+erf_fast(t1*0.70710678118654752f)));
                o[2]=f2bf(0.5f*t2*(1.0f+erf_fast(t2*0.70710678118654752f)));
                o[3]=f2bf(0.5f*t3*(1.0f+erf_fast(t3*0.70710678118654752f)));
                *(u16x4*)((u16*)Cout + (size_t)m*N + nb) = o;
            } else { // MODE_PART
                float4 o = {v[0],v[1],v[2],v[3]};
                if (chunk==0)       *(float4*)((float*)Cout + (size_t)m*N + nb) = o;
                else if (m < 2048)  *(float4*)((float*)C2a  + (size_t)m*N + nb) = o;
                else                *(float4*)((float*)C2b  + (size_t)(m-2048)*N + nb) = o;
            }
        }
    }
}

// ---------------- MFMA flash attention: no-max exp2 softmax, XCD-grouped grid ----------------
// scores = QK with Q pre-scaled by 0.125*log2(e); softmax(s)=exp2(s')/sum (|s| small => no overflow)
__global__ __launch_bounds__(256) void attn_mfma(const u16* __restrict__ Qb, const u16* __restrict__ Kb,
    const u16* __restrict__ VTb, u16* __restrict__ ao)
{
    __shared__ __align__(16) u16 Kl[2][4096];  // [key 64][dh 64], slot-XOR swizzled
    __shared__ __align__(16) u16 Vl[2][4096];  // [dh 64][key 64], slot-XOR swizzled
    int tid=threadIdx.x, l=tid&63, w=tid>>6;
    int l31=l&31, hi=l>>5;
    // XCD-grouped: 4 bh per XCD, all 16 qt of a bh on one XCD
    int bid = blockIdx.x;                 // 0..511
    int xcd = bid & 7, idx = bid >> 3;    // idx 0..63
    int bh = xcd*4 + (idx>>4);            // 0..31
    int qt = idx & 15;                    // 0..15
    int b=bh>>4, h=bh&15;
    int qrow = qt*128 + w*32 + l31;

    const u16* qptr = Qb + (size_t)(b*SS + qrow)*DD + h*64;
    short8v qf[4];
    #pragma unroll
    for (int t=0;t<4;t++) qf[t] = *(const short8v*)(qptr + t*16 + hi*8);

    f32x16 so0, so1;
    #pragma unroll
    for (int i=0;i<16;i++){ so0[i]=0.f; so1[i]=0.f; }
    float l_run=0.f;

    int skey = (w<<3) + (l>>3);   // staging row (+32 per issue)
    int ssl  = l&7;
    auto stage = [&](int buf, int kt){
        #pragma unroll
        for (int r=0;r<2;r++){
            int key = skey + r*32;
            int slot = ssl ^ (key&7);
            const u16* gK = Kb + ((size_t)bh*KSTRIDE + kt*64 + key)*64 + slot*8;
            GLL16(gK, (char*)&Kl[buf][0] + r*4096 + w*1024);
            const u16* gV = VTb + ((size_t)bh*64 + key)*KSTRIDE + kt*64 + slot*8;
            GLL16(gV, (char*)&Vl[buf][0] + r*4096 + w*1024);
        }
    };

    int cur=0;
    stage(0,0);
    __syncthreads();
    const int NTILE = 33;
    for (int kt=0; kt<NTILE; kt++){
        if (kt+1<NTILE) stage(cur^1, kt+1);
        f32x16 ss0, ss1;
        #pragma unroll
        for (int i=0;i<16;i++){ ss0[i]=0.f; ss1[i]=0.f; }
        __builtin_amdgcn_s_setprio(1);
        #pragma unroll
        for (int t=0;t<4;t++){
            int sl = (2*t+hi) ^ (l31&7);
            short8v kf0 = *(const short8v*)((const char*)&Kl[cur][0] + l31*128 + sl*16);
            ss0 = __builtin_amdgcn_mfma_f32_32x32x16_bf16(kf0, qf[t], ss0, 0,0,0);
            short8v kf1 = *(const short8v*)((const char*)&Kl[cur][0] + (32+l31)*128 + sl*16);
            ss1 = __builtin_amdgcn_mfma_f32_32x32x16_bf16(kf1, qf[t], ss1, 0,0,0);
        }
        __builtin_amdgcn_s_setprio(0);
        if (kt == NTILE-1){
            #pragma unroll
            for (int r=0;r<16;r++){
                int k0 = 2048 + (r&3) + 8*(r>>2) + 4*hi;
                if (k0 >= 2049) ss0[r] = -1e30f;
                ss1[r] = -1e30f;   // keys 2080..2111 all masked
            }
        }
        float psum = 0.f;
        #pragma unroll
        for (int r=0;r<16;r++){
            float p=exp2f(ss0[r]); ss0[r]=p; psum+=p;
            float q=exp2f(ss1[r]); ss1[r]=q; psum+=q;
        }
        psum += __shfl_xor(psum, 32);
        l_run += psum;

        short8v pf[4];
        #pragma unroll
        for (int t=0;t<4;t++){
            u32 a0,a1,b0,b1;
            if (t==0){ a0=pk2(ss0[0],ss0[1]);   a1=pk2(ss0[2],ss0[3]);   b0=pk2(ss0[4],ss0[5]);   b1=pk2(ss0[6],ss0[7]); }
            else if (t==1){ a0=pk2(ss0[8],ss0[9]);   a1=pk2(ss0[10],ss0[11]); b0=pk2(ss0[12],ss0[13]); b1=pk2(ss0[14],ss0[15]); }
            else if (t==2){ a0=pk2(ss1[0],ss1[1]);   a1=pk2(ss1[2],ss1[3]);   b0=pk2(ss1[4],ss1[5]);   b1=pk2(ss1[6],ss1[7]); }
            else          { a0=pk2(ss1[8],ss1[9]);   a1=pk2(ss1[10],ss1[11]); b0=pk2(ss1[12],ss1[13]); b1=pk2(ss1[14],ss1[15]); }
            u32 s0 = hi ? a0 : b0, s1 = hi ? a1 : b1;
            u32 r0 = (u32)__shfl_xor((int)s0, 32);
            u32 r1 = (u32)__shfl_xor((int)s1, 32);
            union { u32 u[4]; short8v v; } cvt;
            cvt.u[0] = hi ? r0 : a0;
            cvt.u[1] = hi ? r1 : a1;
            cvt.u[2] = hi ? b0 : r0;
            cvt.u[3] = hi ? b1 : r1;
            pf[t] = cvt.v;
        }
        __builtin_amdgcn_s_setprio(1);
        #pragma unroll
        for (int t=0;t<4;t++){
            int sl = (2*t+hi) ^ (l31&7);
            short8v vf0 = *(const short8v*)((const char*)&Vl[cur][0] + l31*128 + sl*16);
            so0 = __builtin_amdgcn_mfma_f32_32x32x16_bf16(vf0, pf[t], so0, 0,0,0);
            short8v vf1 = *(const short8v*)((const char*)&Vl[cur][0] + (32+l31)*128 + sl*16);
            so1 = __builtin_amdgcn_mfma_f32_32x32x16_bf16(vf1, pf[t], so1, 0,0,0);
        }
        __builtin_amdgcn_s_setprio(0);
        __syncthreads();
        cur ^= 1;
    }
    float inv = 1.f / l_run;
    u16* aop = ao + (size_t)(b*SS + qrow)*DD + h*64;
    #pragma unroll
    for (int rg=0; rg<4; rg++){
        int dh0 = rg*8 + 4*hi;
        u16x4 o0, o1;
        #pragma unroll
        for (int j=0;j<4;j++){ o0[j]=f2bf(so0[rg*4+j]*inv); o1[j]=f2bf(so1[rg*4+j]*inv); }
        *(u16x4*)(aop + dh0) = o0;
        *(u16x4*)(aop + 32 + dh0) = o1;
    }
}

// ---------------- split-K matvec ----------------
__global__ __launch_bounds__(256) void vecmat_part(const float* __restrict__ vec,
    const float* __restrict__ W, float* __restrict__ part, int K, int N)
{
    int b = blockIdx.z, kc = blockIdx.y;
    int j = blockIdx.x*256 + threadIdx.x;
    int k0 = kc * (K >> 3);
    float acc = 0.0f;
    #pragma unroll 4
    for (int k = k0; k < k0 + (K >> 3); k++)
        acc += vec[(size_t)b*K + k] * W[(size_t)k*N + j];
    part[((size_t)b*8 + kc)*N + j] = acc;
}

__global__ __launch_bounds__(256) void vecmat_red(const float* __restrict__ part,
    float* __restrict__ out, int N)
{
    int b = blockIdx.y;
    int j = blockIdx.x*256 + threadIdx.x;
    float acc = 0.0f;
    #pragma unroll
    for (int kc = 0; kc < 8; kc++) acc += part[((size_t)b*8 + kc)*N + j];
    out[(size_t)b*N + j] = acc;
}

// fused Km/Vm: reads h once, both weights
__global__ __launch_bounds__(256) void vecmat2_part(const float* __restrict__ vec,
    const float* __restrict__ Wa, const float* __restrict__ Wb, float* __restrict__ part)
{
    int b = blockIdx.z, kc = blockIdx.y;
    int j = blockIdx.x*256 + threadIdx.x;
    int k0 = kc * 128;
    float accA = 0.0f, accB = 0.0f;
    #pragma unroll 4
    for (int k = k0; k < k0 + 128; k++){
        float v = vec[(size_t)b*DD + k];
        accA += v * Wa[(size_t)k*DD + j];
        accB += v * Wb[(size_t)k*DD + j];
    }
    part[((size_t)b*8 + kc)*2048 + j] = accA;
    part[((size_t)b*8 + kc)*2048 + 1024 + j] = accB;
}

__global__ __launch_bounds__(256) void vecmat2_red(const float* __restrict__ part,
    float* __restrict__ outA, float* __restrict__ outB)
{
    int b = blockIdx.y;
    int j = blockIdx.x*256 + threadIdx.x;
    float accA = 0.0f, accB = 0.0f;
    #pragma unroll
    for (int kc = 0; kc < 8; kc++){
        accA += part[((size_t)b*8 + kc)*2048 + j];
        accB += part[((size_t)b*8 + kc)*2048 + 1024 + j];
    }
    outA[(size_t)b*DD + j] = accA;
    outB[(size_t)b*DD + j] = accB;
}

// ---------------- K/V memory-token fixup ----------------
__global__ __launch_bounds__(256) void fixup_kernel(const float* __restrict__ Kmb,
    const float* __restrict__ Vmb, u16* __restrict__ Kb, u16* __restrict__ VTb)
{
    int idx = blockIdx.x*256 + threadIdx.x;   // 0..2047
    int b = idx>>10, j = idx&1023; int h=j>>6, dh=j&63; int bh=b*HH+h;
    Kb[((size_t)bh*KSTRIDE + 2048)*64 + dh] = f2bf(Kmb[idx]);
    VTb[((size_t)bh*64 + dh)*KSTRIDE + 2048] = f2bf(Vmb[idx]);
}

// ---------------- mean pool: 64 chunks of 32 rows, then reduce ----------------
__global__ __launch_bounds__(256) void pool1_kernel(const float* __restrict__ att, float* __restrict__ ppart)
{
    int b = blockIdx.y, sc = blockIdx.x;   // sc 0..63
    int tid = threadIdx.x;
    float4 acc = {0,0,0,0};
    for (int s = 0; s < 32; s++) {
        int row = b*SS + sc*32 + s;
        float4 v = ((const float4*)(att + (size_t)row*DD))[tid];
        acc.x += v.x; acc.y += v.y; acc.z += v.z; acc.w += v.w;
    }
    ((float4*)(ppart + ((size_t)b*64 + sc)*DD))[tid] = acc;
}

__global__ __launch_bounds__(256) void pool2_kernel(const float* __restrict__ ppart, float* __restrict__ pooled)
{
    int b = blockIdx.y;
    int j = blockIdx.x*256 + threadIdx.x;
    float acc = 0.0f;
    for (int sc = 0; sc < 64; sc++) acc += ppart[((size_t)b*64 + sc)*DD + j];
    pooled[(size_t)b*DD + j] = acc * (1.0f/SS);
}

// ---------------- LSTM gates split-K (16 chunks) ----------------
__global__ __launch_bounds__(256) void gates_part(const float* __restrict__ pooled,
    const float* __restrict__ h, const float* __restrict__ Wih, const float* __restrict__ Whh,
    float* __restrict__ part)
{
    int b = blockIdx.z, kc = blockIdx.y;   // kc 0..15
    int j = blockIdx.x*256 + threadIdx.x;  // 0..4095
    int k0 = kc * 64;
    float acc = 0.0f;
    #pragma unroll 4
    for (int k = k0; k < k0 + 64; k++)
        acc += pooled[(size_t)b*DD + k] * Wih[(size_t)k*4*DD + j]
             + h[(size_t)b*DD + k]      * Whh[(size_t)k*4*DD + j];
    part[((size_t)b*16 + kc)*4*DD + j] = acc;
}

__device__ __forceinline__ float sigmoidf_(float x) { return 1.0f / (1.0f + __expf(-x)); }

__global__ __launch_bounds__(256) void lstm_kernel(const float* __restrict__ gpart,
    const float* __restrict__ b_ih, const float* __restrict__ b_hh,
    const float* __restrict__ c, float* __restrict__ newh_ws, float* __restrict__ out_tail)
{
    int idx = blockIdx.x*256 + threadIdx.x;   // 0..2047
    int b = idx >> 10, d = idx & 1023;
    float sI = b_ih[d]          + b_hh[d];
    float sF = b_ih[DD + d]     + b_hh[DD + d];
    float sG = b_ih[2*DD + d]   + b_hh[2*DD + d];
    float sO = b_ih[3*DD + d]   + b_hh[3*DD + d];
    #pragma unroll
    for (int kc = 0; kc < 16; kc++){
        const float* gp = gpart + ((size_t)b*16 + kc)*4*DD;
        sI += gp[d]; sF += gp[DD + d]; sG += gp[2*DD + d]; sO += gp[3*DD + d];
    }
    float ig = sigmoidf_(sI);
    float fg = sigmoidf_(sF);
    float gg = tanhf(sG);
    float og = sigmoidf_(sO);
    float nc = fg * c[idx] + ig * gg;
    float nh = og * tanhf(nc);
    newh_ws[idx] = nh;
    out_tail[idx] = nh;
    out_tail[BB*DD + idx] = nc;
}

// ---------------- launch ----------------
extern "C" void kernel_launch(void* const* d_in, const int* in_sizes, int n_in,
                              void* d_out, int out_size, void* d_ws, size_t ws_size,
                              hipStream_t stream) {
    const float* x    = (const float*)d_in[0];
    const float* h    = (const float*)d_in[1];
    const float* c    = (const float*)d_in[2];
    const float* Wq   = (const float*)d_in[3];
    const float* Wk   = (const float*)d_in[4];
    const float* Wv   = (const float*)d_in[5];
    const float* Wo   = (const float*)d_in[6];
    const float* Wmk  = (const float*)d_in[7];
    const float* Wmv  = (const float*)d_in[8];
    const float* Wih  = (const float*)d_in[9];
    const float* Whh  = (const float*)d_in[10];
    const float* b_ih = (const float*)d_in[11];
    const float* b_hh = (const float*)d_in[12];
    const float* W1   = (const float*)d_in[13];
    const float* bf1  = (const float*)d_in[14];
    const float* W2   = (const float*)d_in[15];
    const float* bf2  = (const float*)d_in[16];
    const float* g1   = (const float*)d_in[17];
    const float* be1  = (const float*)d_in[18];
    const float* g2   = (const float*)d_in[19];
    const float* be2  = (const float*)d_in[20];
    const float* g3   = (const float*)d_in[21];
    const float* be3  = (const float*)d_in[22];
    const float* Wmp  = (const float*)d_in[23];

    float* out = (float*)d_out;
    char* wsb  = (char*)d_ws;

    u16*   xn   = (u16*)(wsb + 0);        // 8MB  [0,8)
    u16*   hn   = (u16*)(wsb + 8*MB);     // 8MB  [8,16)
    float* p0   = (float*)(wsb + 0);      // 16MB overlay [0,16) (xn,hn dead) = FFN2 partial0
    u16*   Qbuf = (u16*)(wsb + 16*MB);    // 8MB  [16,24)
    u16*   Kbuf = (u16*)(wsb + 24*MB);    // 8.5MB [24,33)
    u16*   VTb  = (u16*)(wsb + 33*MB);    // 8.5MB [33,42)
    u16*   act  = (u16*)(wsb + 16*MB);    // 32MB overlay [16,48) (Q/K/VT dead)
    u16*   ao   = (u16*)(wsb + 48*MB);    // 8MB  [48,56)
    float* p1a  = (float*)(wsb + 48*MB);  // FFN2 partial1 rows 0..2047 (ao dead)
    float* attb = (float*)(wsb + 56*MB);  // 16MB [56,72)
    u16*   WqkvT= (u16*)(wsb + 72*MB);    // 6MB [72,78)
    u16*   WoT  = (u16*)(wsb + 78*MB);    // 2MB [78,80)
    u16*   W1T  = (u16*)(wsb + 80*MB);    // 8MB [80,88)
    float* p1b  = (float*)(wsb + 80*MB);  // FFN2 partial1 rows 2048..4095 (W1T dead)
    u16*   W2T  = (u16*)(wsb + 88*MB);    // 8MB [88,96)
    float* sm   = (float*)(wsb + 96*MB);
    float* Kmb     = sm;
    float* Vmb     = Kmb + 2048;
    float* pooled  = Vmb + 2048;
    float* newh    = pooled + 2048;
    float* mproj   = newh + 2048;
    float* vpart   = mproj + 2048;             // 16384
    float* v2part  = vpart + 16384;            // 32768
    float* gpart   = v2part + 32768;           // 131072
    float* ppart   = gpart + 131072;           // 131072

    // weight transposes (fp32 [K][N] -> bf16 [N][K])
    tr_kernel<<<dim3(32,32), 256, 0, stream>>>(Wq, WqkvT,             1024, 1024);
    tr_kernel<<<dim3(32,32), 256, 0, stream>>>(Wk, WqkvT + 1024*1024, 1024, 1024);
    tr_kernel<<<dim3(32,32), 256, 0, stream>>>(Wv, WqkvT + 2048*1024, 1024, 1024);
    tr_kernel<<<dim3(32,32), 256, 0, stream>>>(Wo, WoT, 1024, 1024);
    tr_kernel<<<dim3(128,32), 256, 0, stream>>>(W1, W1T, 1024, 4096);
    tr_kernel<<<dim3(32,128), 256, 0, stream>>>(W2, W2T, 4096, 1024);

    // LN1 -> xn bf16
    ln_kernel<<<RR, 256, 0, stream>>>(x, nullptr, g1, be1, nullptr, nullptr, xn);
    // memory K/V tokens (fp32, split-K, fused)
    vecmat2_part<<<dim3(4,8,BB), 256, 0, stream>>>(h, Wmk, Wmv, v2part);
    vecmat2_red<<<dim3(4,BB), 256, 0, stream>>>(v2part, Kmb, Vmb);
    // fused QKV projection (MFMA): M=4096, N=3072; Q pre-scaled by 0.125*log2(e) for exp2 softmax
    mgemm<<<24*32, 256, 0, stream>>>(xn, WqkvT, 24, 1024, 1, MODE_QKV, nullptr, nullptr,
                                     0.125f*1.44269504088896f, Qbuf, Kbuf, VTb);
    fixup_kernel<<<8, 256, 0, stream>>>(Kmb, Vmb, Kbuf, VTb);
    // attention (512 blocks, XCD-grouped)
    attn_mfma<<<512, 256, 0, stream>>>(Qbuf, Kbuf, VTb, ao);
    // attended = x + ao @ Wo  (fp32)
    mgemm<<<8*32, 256, 0, stream>>>(ao, WoT, 8, 1024, 1, MODE_F32R, nullptr, x, 1.f, attb, nullptr, nullptr);
    // mean pool, LSTM
    pool1_kernel<<<dim3(64,BB), 256, 0, stream>>>(attb, ppart);
    pool2_kernel<<<dim3(4,BB), 256, 0, stream>>>(ppart, pooled);
    gates_part<<<dim3(16,16,BB), 256, 0, stream>>>(pooled, h, Wih, Whh, gpart);
    lstm_kernel<<<8, 256, 0, stream>>>(gpart, b_ih, b_hh, c, newh, out + (size_t)RR*DD);
    vecmat_part<<<dim3(4,8,BB), 256, 0, stream>>>(newh, Wmp, vpart, DD, DD);
    vecmat_red<<<dim3(4,BB), 256, 0, stream>>>(vpart, mproj, DD);
    // mixed = attended + mproj (in place), hn = LN2(mixed) bf16
    ln_kernel<<<RR, 256, 0, stream>>>(attb, mproj, g2, be2, attb, nullptr, hn);
    // FFN1: act = gelu(hn @ W1 + bf1)
    mgemm<<<32*32, 256, 0, stream>>>(hn, W1T, 32, 1024, 1, MODE_GELU, bf1, nullptr, 1.f, act, nullptr, nullptr);
    // FFN2 split-K=2: partials
    mgemm<<<8*32*2, 256, 0, stream>>>(act, W2T, 8, 2048, 2, MODE_PART, nullptr, nullptr, 1.f, p0, p1a, p1b);
    // out = LN3(p0+p1+bias+resid)  (fused reduce)
    ln3f_kernel<<<RR, 256, 0, stream>>>(p0, p1a, p1b, bf2, attb, g3, be3, out);
}

// Round 9
// 329.684 us; speedup vs baseline: 13.8947x; 1.0977x over previous
//
#include <hip/hip_runtime.h>
#include <hip/hip_bf16.h>
#include <math.h>

#define BB 2
#define SS 2048
#define DD 1024
#define HH 16
#define RR (BB*SS)
#define KSTRIDE 2064   // padded key stride per (b,h)
#define MB (1024ull*1024ull)

typedef unsigned short u16;
typedef unsigned int u32;
typedef __attribute__((ext_vector_type(8))) short short8v;
typedef __attribute__((ext_vector_type(4))) float f32x4;
typedef __attribute__((ext_vector_type(16))) float f32x16;
typedef __attribute__((ext_vector_type(4))) u16 u16x4;

__device__ __forceinline__ u16 f2bf(float f){
    union { __hip_bfloat16 h; u16 u; } c; c.h = __float2bfloat16(f); return c.u;
}
__device__ __forceinline__ u32 pk2(float a, float b){
    return (u32)f2bf(a) | ((u32)f2bf(b) << 16);
}
// raw v_exp_f32 (exp2): single trans op, no ocml fixup path
__device__ __forceinline__ float exp2_raw(float x){
    float r;
    asm("v_exp_f32 %0, %1" : "=v"(r) : "v"(x));
    return r;
}
// A&S 7.1.26 erf approximation, |err| <= 1.5e-7 (<< bf16 rounding of act)
__device__ __forceinline__ float erf_fast(float x){
    float ax = fabsf(x);
    float t = __builtin_amdgcn_rcpf(1.0f + 0.3275911f*ax);
    float y = t*(0.254829592f + t*(-0.284496736f + t*(1.421413741f + t*(-1.453152027f + t*1.061405429f))));
    float r = 1.0f - y*__expf(-ax*ax);
    return copysignf(r, x);
}

#define GLL16(gp, lp) __builtin_amdgcn_global_load_lds( \
    (const __attribute__((address_space(1))) void*)(gp), \
    (__attribute__((address_space(3))) void*)(lp), 16, 0, 0)

// ---------------- LayerNorm: fp32 in, optional broadcast add, fp32 and/or bf16 out ----------------
__global__ __launch_bounds__(256) void ln_kernel(const float* __restrict__ in,
    const float* __restrict__ mproj, const float* __restrict__ g, const float* __restrict__ be,
    float* __restrict__ mixed_out, float* __restrict__ outf, u16* __restrict__ outb)
{
    int row = blockIdx.x; int b = row / SS; int tid = threadIdx.x;
    float4 v = ((const float4*)(in + (size_t)row*DD))[tid];
    if (mproj){
        float4 mp = ((const float4*)(mproj + (size_t)b*DD))[tid];
        v.x+=mp.x; v.y+=mp.y; v.z+=mp.z; v.w+=mp.w;
        ((float4*)(mixed_out + (size_t)row*DD))[tid] = v;
    }
    float s = v.x+v.y+v.z+v.w, s2 = v.x*v.x+v.y*v.y+v.z*v.z+v.w*v.w;
    #pragma unroll
    for (int off=32; off>0; off>>=1){ s += __shfl_down(s,off); s2 += __shfl_down(s2,off); }
    __shared__ float red[2][4];
    if ((tid&63)==0){ red[0][tid>>6]=s; red[1][tid>>6]=s2; }
    __syncthreads();
    float st = red[0][0]+red[0][1]+red[0][2]+red[0][3];
    float s2t= red[1][0]+red[1][1]+red[1][2]+red[1][3];
    float mean = st*(1.f/DD); float var = s2t*(1.f/DD)-mean*mean;
    float rs = rsqrtf(var + 1e-5f);
    float4 gg=((const float4*)g)[tid], bb2=((const float4*)be)[tid];
    float o0=(v.x-mean)*rs*gg.x+bb2.x, o1=(v.y-mean)*rs*gg.y+bb2.y;
    float o2=(v.z-mean)*rs*gg.z+bb2.z, o3=(v.w-mean)*rs*gg.w+bb2.w;
    if (outf){ float4 o={o0,o1,o2,o3}; ((float4*)(outf+(size_t)row*DD))[tid]=o; }
    if (outb){ u16x4 o={f2bf(o0),f2bf(o1),f2bf(o2),f2bf(o3)}; ((u16x4*)(outb+(size_t)row*DD))[tid]=o; }
}

// ---------------- final: y = p0+p1+bias+resid, out = LN(y) (fused splitred+LN3) ----------------
__global__ __launch_bounds__(256) void ln3f_kernel(const float* __restrict__ p0,
    const float* __restrict__ p1a, const float* __restrict__ p1b,
    const float* __restrict__ bias, const float* __restrict__ resid,
    const float* __restrict__ g, const float* __restrict__ be, float* __restrict__ out)
{
    int row = blockIdx.x; int tid = threadIdx.x;
    const float* p1 = (row < 2048) ? (p1a + (size_t)row*DD) : (p1b + (size_t)(row-2048)*DD);
    float4 a  = ((const float4*)(p0 + (size_t)row*DD))[tid];
    float4 b  = ((const float4*)p1)[tid];
    float4 bi = ((const float4*)bias)[tid];
    float4 rs4= ((const float4*)(resid + (size_t)row*DD))[tid];
    float4 v = {a.x+b.x+bi.x+rs4.x, a.y+b.y+bi.y+rs4.y, a.z+b.z+bi.z+rs4.z, a.w+b.w+bi.w+rs4.w};
    float s = v.x+v.y+v.z+v.w, s2 = v.x*v.x+v.y*v.y+v.z*v.z+v.w*v.w;
    #pragma unroll
    for (int off=32; off>0; off>>=1){ s += __shfl_down(s,off); s2 += __shfl_down(s2,off); }
    __shared__ float red[2][4];
    if ((tid&63)==0){ red[0][tid>>6]=s; red[1][tid>>6]=s2; }
    __syncthreads();
    float st = red[0][0]+red[0][1]+red[0][2]+red[0][3];
    float s2t= red[1][0]+red[1][1]+red[1][2]+red[1][3];
    float mean = st*(1.f/DD); float var = s2t*(1.f/DD)-mean*mean;
    float rs = rsqrtf(var + 1e-5f);
    float4 gg=((const float4*)g)[tid], bb2=((const float4*)be)[tid];
    float4 o;
    o.x=(v.x-mean)*rs*gg.x+bb2.x; o.y=(v.y-mean)*rs*gg.y+bb2.y;
    o.z=(v.z-mean)*rs*gg.z+bb2.z; o.w=(v.w-mean)*rs*gg.w+bb2.w;
    ((float4*)(out + (size_t)row*DD))[tid] = o;
}

// ---------------- merged weight transposes (fp32 [K][N] -> bf16 [N][K]), one launch ----------------
__global__ __launch_bounds__(256) void tr6_kernel(const float* __restrict__ Wq, const float* __restrict__ Wk,
    const float* __restrict__ Wv, const float* __restrict__ Wo,
    const float* __restrict__ W1, const float* __restrict__ W2,
    u16* __restrict__ WqkvT, u16* __restrict__ WoT, u16* __restrict__ W1T, u16* __restrict__ W2T)
{
    __shared__ float t[32][33];
    int bid = blockIdx.x;
    const float* in; u16* out; int K, N, n0, k0;
    if (bid < 3072){
        int m = bid >> 10, r = bid & 1023;
        in = (m==0) ? Wq : (m==1) ? Wk : Wv;
        out = WqkvT + (size_t)m*1024*1024;
        K = 1024; N = 1024; n0 = (r & 31)*32; k0 = (r >> 5)*32;
    } else if (bid < 4096){
        int r = bid - 3072;
        in = Wo; out = WoT; K = 1024; N = 1024; n0 = (r & 31)*32; k0 = (r >> 5)*32;
    } else if (bid < 8192){
        int r = bid - 4096;
        in = W1; out = W1T; K = 1024; N = 4096; n0 = (r & 127)*32; k0 = (r >> 7)*32;
    } else {
        int r = bid - 8192;
        in = W2; out = W2T; K = 4096; N = 1024; n0 = (r & 31)*32; k0 = (r >> 5)*32;
    }
    int tx = threadIdx.x & 31, ty = threadIdx.x >> 5;
    #pragma unroll
    for (int i=0;i<4;i++){ int k = ty + i*8; t[k][tx] = in[(size_t)(k0+k)*N + n0 + tx]; }
    __syncthreads();
    #pragma unroll
    for (int i=0;i<4;i++){ int n = ty + i*8; out[(size_t)(n0+n)*K + k0 + tx] = f2bf(t[tx][n]); }
}

// ---------------- bf16 MFMA GEMM (swapped operands; chunked XCD swizzle) ----------------
#define MODE_QKV  0  // fused: n<1024 Q(bf16*scale), <2048 K-layout, else V^T-layout
#define MODE_F32R 3  // f32 + resid
#define MODE_GELU 4  // bf16, +bias, gelu (fast erf)
#define MODE_PART 6  // fp32 partial (split-K): chunk0->Cout, chunk1->C2a/C2b row-split at 2048

// requires nbx%8==0, nby==32, grid%8==0
__global__ __launch_bounds__(256) void mgemm(const u16* __restrict__ A, const u16* __restrict__ BT,
    int nbx, int Kc, int kchunks, int mode,
    const float* __restrict__ bias, const float* __restrict__ resid, float scale,
    void* __restrict__ Cout, void* __restrict__ C2a, void* __restrict__ C2b)
{
    int tid=threadIdx.x, l=tid&63, w=tid>>6;
    // XCD-aware bijective swizzle, then chunked 8x8 tile decode (L2-footprint <= ~4MB/XCD)
    int nwg = gridDim.x;
    int qq = nwg >> 3;
    int bid = blockIdx.x;
    int swz = (bid & 7)*qq + (bid >> 3);
    int tiles = nwg / kchunks;
    int chunk = swz / tiles;
    int t2 = swz % tiles;
    int sby = t2 / (nbx*8);
    int rem = t2 - sby*(nbx*8);
    int sbx = rem >> 6;
    int ci  = rem & 63;
    int bx = sbx*8 + (ci&7);
    int by = sby*8 + (ci>>3);

    int bm = by*128, bn = bx*128;
    int N = nbx*128;
    int lda = Kc*kchunks;
    int koff = chunk*Kc;
    int wr = w>>1, wc = w&1;
    f32x4 acc[4][4];
    #pragma unroll
    for(int i=0;i<4;i++)
        #pragma unroll
        for(int j=0;j<4;j++)
            #pragma unroll
            for(int r=0;r<4;r++) acc[i][j][r]=0.f;

    __shared__ __align__(16) u16 Al[2][4096];
    __shared__ __align__(16) u16 Bl[2][4096];
    int srow = (w<<4) + (l>>2);     // staging row (+64 per issue)
    int sph  = l&3;                 // physical 16B slot
    const int NT = Kc >> 5;

    auto stage = [&](int buf, int kt){
        #pragma unroll
        for (int r=0;r<2;r++){
            int rowA = srow + r*64;
            int sl = sph ^ ((rowA>>1)&3);
            const u16* gA = A + (size_t)(bm+rowA)*lda + koff + kt*32 + sl*8;
            GLL16(gA, (char*)&Al[buf][0] + r*4096 + w*1024);
            const u16* gB = BT + (size_t)(bn+rowA)*lda + koff + kt*32 + sl*8;
            GLL16(gB, (char*)&Bl[buf][0] + r*4096 + w*1024);
        }
    };

    int cur=0;
    stage(0,0);
    __syncthreads();
    for (int kt=0; kt<NT; kt++){
        if (kt+1<NT) stage(cur^1, kt+1);
        short8v af[4], bf[4];
        #pragma unroll
        for (int mi=0;mi<4;mi++){
            int row = wr*64 + mi*16 + (l&15);
            int sl = (l>>4) ^ ((row>>1)&3);
            af[mi] = *(const short8v*)((const char*)&Al[cur][0] + row*64 + sl*16);
        }
        #pragma unroll
        for (int ni=0;ni<4;ni++){
            int row = wc*64 + ni*16 + (l&15);
            int sl = (l>>4) ^ ((row>>1)&3);
            bf[ni] = *(const short8v*)((const char*)&Bl[cur][0] + row*64 + sl*16);
        }
        // swapped: per-thread frag is 4 consecutive n at fixed m
        #pragma unroll
        for (int mi=0;mi<4;mi++)
            #pragma unroll
            for (int ni=0;ni<4;ni++)
                acc[mi][ni] = __builtin_amdgcn_mfma_f32_16x16x32_bf16(bf[ni], af[mi], acc[mi][ni], 0,0,0);
        __syncthreads();
        cur ^= 1;
    }

    #pragma unroll
    for (int mi=0;mi<4;mi++){
        int m = bm + wr*64 + mi*16 + (l&15);
        #pragma unroll
        for (int ni=0;ni<4;ni++){
            int nb = bn + wc*64 + ni*16 + ((l>>4)<<2);
            f32x4 v = acc[mi][ni];
            if (mode==MODE_QKV){
                if (nb < 1024){
                    u16x4 o;
                    #pragma unroll
                    for (int r=0;r<4;r++) o[r] = f2bf(v[r]*scale);
                    *(u16x4*)((u16*)Cout + (size_t)m*1024 + nb) = o;
                } else if (nb < 2048){
                    int cc = nb-1024; int hh = cc>>6, dh = cc&63;
                    int b2 = m>>11, key = m&2047;
                    u16x4 o;
                    #pragma unroll
                    for (int r=0;r<4;r++) o[r] = f2bf(v[r]);
                    *(u16x4*)((u16*)C2a + ((size_t)(b2*HH+hh)*KSTRIDE + key)*64 + dh) = o;
                } else {
                    int cc = nb-2048; int hh = cc>>6, dh = cc&63;
                    int b2 = m>>11, key = m&2047;
                    #pragma unroll
                    for (int r=0;r<4;r++)
                        ((u16*)C2b)[((size_t)(b2*HH+hh)*64 + dh + r)*KSTRIDE + key] = f2bf(v[r]);
                }
            } else if (mode==MODE_F32R){
                float4 rs = *(const float4*)(resid + (size_t)m*N + nb);
                float4 o = {v[0]+rs.x, v[1]+rs.y, v[2]+rs.z, v[3]+rs.w};
                *(float4*)((float*)Cout + (size_t)m*N + nb) = o;
            } else if (mode==MODE_GELU){
                float4 bi = *(const float4*)(bias + nb);
                float t0=v[0]+bi.x, t1=v[1]+bi.y, t2=v[2]+bi.z, t3=v[3]+bi.w;
                u16x4 o;
                o[0]=f2bf(0.5f*t0*(1.0f+erf_fast(t0*0.70710678118654752f)));
                o[1]=f2bf(0.5f*t1*(1.0f+erf_fast(t1*0.70710678118654752f)));
                o[2]=f2bf(0.5f*t2*(1.0f+erf_fast(t2*0.70710678118654752f)));
                o[3]=f2bf(0.5f*t3*(1.0f+erf_fast(t3*0.70710678118654752f)));
                *(u16x4*)((u16*)Cout + (size_t)m*N + nb) = o;
            } else { // MODE_PART
                float4 o = {v[0],v[1],v[2],v[3]};
                if (chunk==0)       *(float4*)((float*)Cout + (size_t)m*N + nb) = o;
                else if (m < 2048)  *(float4*)((float*)C2a  + (size_t)m*N + nb) = o;
                else                *(float4*)((float*)C2b  + (size_t)(m-2048)*N + nb) = o;
            }
        }
    }
}

// ---------------- MFMA flash attention: pipelined (QK(t+1) || softmax/PV(t)), triple-buffer ----------------
// scores = QK with Q pre-scaled by 0.125*log2(e); softmax(s)=exp2(s')/sum (|s| small => no overflow)
__global__ __launch_bounds__(256) void attn_mfma(const u16* __restrict__ Qb, const u16* __restrict__ Kb,
    const u16* __restrict__ VTb, u16* __restrict__ ao)
{
    __shared__ __align__(16) u16 Kl[3][4096];  // [key 64][dh 64], slot-XOR swizzled
    __shared__ __align__(16) u16 Vl[3][4096];  // [dh 64][key 64], slot-XOR swizzled
    int tid=threadIdx.x, l=tid&63, w=tid>>6;
    int l31=l&31, hi=l>>5;
    // XCD-grouped: 4 bh per XCD, all 16 qt of a bh on one XCD
    int bid = blockIdx.x;                 // 0..511
    int xcd = bid & 7, idx = bid >> 3;    // idx 0..63
    int bh = xcd*4 + (idx>>4);            // 0..31
    int qt = idx & 15;                    // 0..15
    int b=bh>>4, h=bh&15;
    int qrow = qt*128 + w*32 + l31;

    const u16* qptr = Qb + (size_t)(b*SS + qrow)*DD + h*64;
    short8v qf[4];
    #pragma unroll
    for (int t=0;t<4;t++) qf[t] = *(const short8v*)(qptr + t*16 + hi*8);

    f32x16 so0, so1;
    #pragma unroll
    for (int i=0;i<16;i++){ so0[i]=0.f; so1[i]=0.f; }
    float l_run=0.f;

    int skey = (w<<3) + (l>>3);   // staging row (+32 per issue)
    int ssl  = l&7;
    auto stage = [&](int buf, int kt){
        #pragma unroll
        for (int r=0;r<2;r++){
            int key = skey + r*32;
            int slot = ssl ^ (key&7);
            const u16* gK = Kb + ((size_t)bh*KSTRIDE + kt*64 + key)*64 + slot*8;
            GLL16(gK, (char*)&Kl[buf][0] + r*4096 + w*1024);
            const u16* gV = VTb + ((size_t)bh*64 + key)*KSTRIDE + kt*64 + slot*8;
            GLL16(gV, (char*)&Vl[buf][0] + r*4096 + w*1024);
        }
    };

    // QK into given score regs from K buffer bf
    auto QK = [&](int bf, f32x16& s0, f32x16& s1){
        #pragma unroll
        for (int i=0;i<16;i++){ s0[i]=0.f; s1[i]=0.f; }
        __builtin_amdgcn_s_setprio(1);
        #pragma unroll
        for (int t=0;t<4;t++){
            int sl = (2*t+hi) ^ (l31&7);
            short8v kf0 = *(const short8v*)((const char*)&Kl[bf][0] + l31*128 + sl*16);
            s0 = __builtin_amdgcn_mfma_f32_32x32x16_bf16(kf0, qf[t], s0, 0,0,0);
            short8v kf1 = *(const short8v*)((const char*)&Kl[bf][0] + (32+l31)*128 + sl*16);
            s1 = __builtin_amdgcn_mfma_f32_32x32x16_bf16(kf1, qf[t], s1, 0,0,0);
        }
        __builtin_amdgcn_s_setprio(0);
    };

    // softmax + pack + PV from score regs and V buffer bf
    auto SMPV = [&](int bf, f32x16& s0, f32x16& s1){
        float psum = 0.f;
        #pragma unroll
        for (int r=0;r<16;r++){
            float p=exp2_raw(s0[r]); s0[r]=p; psum+=p;
            float q=exp2_raw(s1[r]); s1[r]=q; psum+=q;
        }
        psum += __shfl_xor(psum, 32);
        l_run += psum;
        short8v pf[4];
        #pragma unroll
        for (int t=0;t<4;t++){
            u32 a0,a1,b0,b1;
            if (t==0){ a0=pk2(s0[0],s0[1]);   a1=pk2(s0[2],s0[3]);   b0=pk2(s0[4],s0[5]);   b1=pk2(s0[6],s0[7]); }
            else if (t==1){ a0=pk2(s0[8],s0[9]);   a1=pk2(s0[10],s0[11]); b0=pk2(s0[12],s0[13]); b1=pk2(s0[14],s0[15]); }
            else if (t==2){ a0=pk2(s1[0],s1[1]);   a1=pk2(s1[2],s1[3]);   b0=pk2(s1[4],s1[5]);   b1=pk2(s1[6],s1[7]); }
            else          { a0=pk2(s1[8],s1[9]);   a1=pk2(s1[10],s1[11]); b0=pk2(s1[12],s1[13]); b1=pk2(s1[14],s1[15]); }
            u32 sx0 = hi ? a0 : b0, sx1 = hi ? a1 : b1;
            u32 r0 = (u32)__shfl_xor((int)sx0, 32);
            u32 r1 = (u32)__shfl_xor((int)sx1, 32);
            union { u32 u[4]; short8v v; } cvt;
            cvt.u[0] = hi ? r0 : a0;
            cvt.u[1] = hi ? r1 : a1;
            cvt.u[2] = hi ? b0 : r0;
            cvt.u[3] = hi ? b1 : r1;
            pf[t] = cvt.v;
        }
        __builtin_amdgcn_s_setprio(1);
        #pragma unroll
        for (int t=0;t<4;t++){
            int sl = (2*t+hi) ^ (l31&7);
            short8v vf0 = *(const short8v*)((const char*)&Vl[bf][0] + l31*128 + sl*16);
            so0 = __builtin_amdgcn_mfma_f32_32x32x16_bf16(vf0, pf[t], so0, 0,0,0);
            short8v vf1 = *(const short8v*)((const char*)&Vl[bf][0] + (32+l31)*128 + sl*16);
            so1 = __builtin_amdgcn_mfma_f32_32x32x16_bf16(vf1, pf[t], so1, 0,0,0);
        }
        __builtin_amdgcn_s_setprio(0);
    };

    const int NTILE = 33;
    int bufA = 0, bufB = 1, bufC = 2;   // tiles t, t+1, t+2
    stage(0, 0);
    stage(1, 1);
    __syncthreads();                    // drains both stages

    f32x16 sA0, sA1, sB0, sB1;
    QK(bufA, sA0, sA1);                 // QK(0)

    auto ITER = [&](f32x16& c0, f32x16& c1, f32x16& n0, f32x16& n1, int t){
        if (t+2 < NTILE) stage(bufC, t+2);
        QK(bufB, n0, n1);               // QK(t+1) -- independent of softmax(t)
        SMPV(bufA, c0, c1);             // softmax+PV(t)
        __syncthreads();                // drains stage(t+2); frees bufA readers
        int tmp = bufA; bufA = bufB; bufB = bufC; bufC = tmp;
    };
    #pragma unroll 1
    for (int tt=0; tt<16; tt++){
        ITER(sA0, sA1, sB0, sB1, 2*tt);
        ITER(sB0, sB1, sA0, sA1, 2*tt+1);
    }
    // tail: tile 32 (keys 2048..2111; only 2048 valid)
    #pragma unroll
    for (int r=0;r<16;r++){
        int k0 = 2048 + (r&3) + 8*(r>>2) + 4*hi;
        if (k0 >= 2049) sA0[r] = -1e30f;
        sA1[r] = -1e30f;
    }
    SMPV(bufA, sA0, sA1);

    float inv = 1.f / l_run;
    u16* aop = ao + (size_t)(b*SS + qrow)*DD + h*64;
    #pragma unroll
    for (int rg=0; rg<4; rg++){
        int dh0 = rg*8 + 4*hi;
        u16x4 o0, o1;
        #pragma unroll
        for (int j=0;j<4;j++){ o0[j]=f2bf(so0[rg*4+j]*inv); o1[j]=f2bf(so1[rg*4+j]*inv); }
        *(u16x4*)(aop + dh0) = o0;
        *(u16x4*)(aop + 32 + dh0) = o1;
    }
}

// ---------------- split-K matvec ----------------
__global__ __launch_bounds__(256) void vecmat_part(const float* __restrict__ vec,
    const float* __restrict__ W, float* __restrict__ part, int K, int N)
{
    int b = blockIdx.z, kc = blockIdx.y;
    int j = blockIdx.x*256 + threadIdx.x;
    int k0 = kc * (K >> 3);
    float acc = 0.0f;
    #pragma unroll 4
    for (int k = k0; k < k0 + (K >> 3); k++)
        acc += vec[(size_t)b*K + k] * W[(size_t)k*N + j];
    part[((size_t)b*8 + kc)*N + j] = acc;
}

__global__ __launch_bounds__(256) void vecmat_red(const float* __restrict__ part,
    float* __restrict__ out, int N)
{
    int b = blockIdx.y;
    int j = blockIdx.x*256 + threadIdx.x;
    float acc = 0.0f;
    #pragma unroll
    for (int kc = 0; kc < 8; kc++) acc += part[((size_t)b*8 + kc)*N + j];
    out[(size_t)b*N + j] = acc;
}

// fused Km/Vm: reads h once, both weights
__global__ __launch_bounds__(256) void vecmat2_part(const float* __restrict__ vec,
    const float* __restrict__ Wa, const float* __restrict__ Wb, float* __restrict__ part)
{
    int b = blockIdx.z, kc = blockIdx.y;
    int j = blockIdx.x*256 + threadIdx.x;
    int k0 = kc * 128;
    float accA = 0.0f, accB = 0.0f;
    #pragma unroll 4
    for (int k = k0; k < k0 + 128; k++){
        float v = vec[(size_t)b*DD + k];
        accA += v * Wa[(size_t)k*DD + j];
        accB += v * Wb[(size_t)k*DD + j];
    }
    part[((size_t)b*8 + kc)*2048 + j] = accA;
    part[((size_t)b*8 + kc)*2048 + 1024 + j] = accB;
}

__global__ __launch_bounds__(256) void vecmat2_red(const float* __restrict__ part,
    float* __restrict__ outA, float* __restrict__ outB)
{
    int b = blockIdx.y;
    int j = blockIdx.x*256 + threadIdx.x;
    float accA = 0.0f, accB = 0.0f;
    #pragma unroll
    for (int kc = 0; kc < 8; kc++){
        accA += part[((size_t)b*8 + kc)*2048 + j];
        accB += part[((size_t)b*8 + kc)*2048 + 1024 + j];
    }
    outA[(size_t)b*DD + j] = accA;
    outB[(size_t)b*DD + j] = accB;
}

// ---------------- K/V memory-token fixup ----------------
__global__ __launch_bounds__(256) void fixup_kernel(const float* __restrict__ Kmb,
    const float* __restrict__ Vmb, u16* __restrict__ Kb, u16* __restrict__ VTb)
{
    int idx = blockIdx.x*256 + threadIdx.x;   // 0..2047
    int b = idx>>10, j = idx&1023; int h=j>>6, dh=j&63; int bh=b*HH+h;
    Kb[((size_t)bh*KSTRIDE + 2048)*64 + dh] = f2bf(Kmb[idx]);
    VTb[((size_t)bh*64 + dh)*KSTRIDE + 2048] = f2bf(Vmb[idx]);
}

// ---------------- mean pool: 64 chunks of 32 rows, then reduce ----------------
__global__ __launch_bounds__(256) void pool1_kernel(const float* __restrict__ att, float* __restrict__ ppart)
{
    int b = blockIdx.y, sc = blockIdx.x;   // sc 0..63
    int tid = threadIdx.x;
    float4 acc = {0,0,0,0};
    for (int s = 0; s < 32; s++) {
        int row = b*SS + sc*32 + s;
        float4 v = ((const float4*)(att + (size_t)row*DD))[tid];
        acc.x += v.x; acc.y += v.y; acc.z += v.z; acc.w += v.w;
    }
    ((float4*)(ppart + ((size_t)b*64 + sc)*DD))[tid] = acc;
}

__global__ __launch_bounds__(256) void pool2_kernel(const float* __restrict__ ppart, float* __restrict__ pooled)
{
    int b = blockIdx.y;
    int j = blockIdx.x*256 + threadIdx.x;
    float acc = 0.0f;
    for (int sc = 0; sc < 64; sc++) acc += ppart[((size_t)b*64 + sc)*DD + j];
    pooled[(size_t)b*DD + j] = acc * (1.0f/SS);
}

// ---------------- LSTM gates split-K (16 chunks) ----------------
__global__ __launch_bounds__(256) void gates_part(const float* __restrict__ pooled,
    const float* __restrict__ h, const float* __restrict__ Wih, const float* __restrict__ Whh,
    float* __restrict__ part)
{
    int b = blockIdx.z, kc = blockIdx.y;   // kc 0..15
    int j = blockIdx.x*256 + threadIdx.x;  // 0..4095
    int k0 = kc * 64;
    float acc = 0.0f;
    #pragma unroll 4
    for (int k = k0; k < k0 + 64; k++)
        acc += pooled[(size_t)b*DD + k] * Wih[(size_t)k*4*DD + j]
             + h[(size_t)b*DD + k]      * Whh[(size_t)k*4*DD + j];
    part[((size_t)b*16 + kc)*4*DD + j] = acc;
}

__device__ __forceinline__ float sigmoidf_(float x) { return 1.0f / (1.0f + __expf(-x)); }

__global__ __launch_bounds__(256) void lstm_kernel(const float* __restrict__ gpart,
    const float* __restrict__ b_ih, const float* __restrict__ b_hh,
    const float* __restrict__ c, float* __restrict__ newh_ws, float* __restrict__ out_tail)
{
    int idx = blockIdx.x*256 + threadIdx.x;   // 0..2047
    int b = idx >> 10, d = idx & 1023;
    float sI = b_ih[d]          + b_hh[d];
    float sF = b_ih[DD + d]     + b_hh[DD + d];
    float sG = b_ih[2*DD + d]   + b_hh[2*DD + d];
    float sO = b_ih[3*DD + d]   + b_hh[3*DD + d];
    #pragma unroll
    for (int kc = 0; kc < 16; kc++){
        const float* gp = gpart + ((size_t)b*16 + kc)*4*DD;
        sI += gp[d]; sF += gp[DD + d]; sG += gp[2*DD + d]; sO += gp[3*DD + d];
    }
    float ig = sigmoidf_(sI);
    float fg = sigmoidf_(sF);
    float gg = tanhf(sG);
    float og = sigmoidf_(sO);
    float nc = fg * c[idx] + ig * gg;
    float nh = og * tanhf(nc);
    newh_ws[idx] = nh;
    out_tail[idx] = nh;
    out_tail[BB*DD + idx] = nc;
}

// ---------------- launch ----------------
extern "C" void kernel_launch(void* const* d_in, const int* in_sizes, int n_in,
                              void* d_out, int out_size, void* d_ws, size_t ws_size,
                              hipStream_t stream) {
    const float* x    = (const float*)d_in[0];
    const float* h    = (const float*)d_in[1];
    const float* c    = (const float*)d_in[2];
    const float* Wq   = (const float*)d_in[3];
    const float* Wk   = (const float*)d_in[4];
    const float* Wv   = (const float*)d_in[5];
    const float* Wo   = (const float*)d_in[6];
    const float* Wmk  = (const float*)d_in[7];
    const float* Wmv  = (const float*)d_in[8];
    const float* Wih  = (const float*)d_in[9];
    const float* Whh  = (const float*)d_in[10];
    const float* b_ih = (const float*)d_in[11];
    const float* b_hh = (const float*)d_in[12];
    const float* W1   = (const float*)d_in[13];
    const float* bf1  = (const float*)d_in[14];
    const float* W2   = (const float*)d_in[15];
    const float* bf2  = (const float*)d_in[16];
    const float* g1   = (const float*)d_in[17];
    const float* be1  = (const float*)d_in[18];
    const float* g2   = (const float*)d_in[19];
    const float* be2  = (const float*)d_in[20];
    const float* g3   = (const float*)d_in[21];
    const float* be3  = (const float*)d_in[22];
    const float* Wmp  = (const float*)d_in[23];

    float* out = (float*)d_out;
    char* wsb  = (char*)d_ws;

    u16*   xn   = (u16*)(wsb + 0);        // 8MB  [0,8)
    u16*   hn   = (u16*)(wsb + 8*MB);     // 8MB  [8,16)
    float* p0   = (float*)(wsb + 0);      // 16MB overlay [0,16) (xn,hn dead) = FFN2 partial0
    u16*   Qbuf = (u16*)(wsb + 16*MB);    // 8MB  [16,24)
    u16*   Kbuf = (u16*)(wsb + 24*MB);    // 8.5MB [24,33)
    u16*   VTb  = (u16*)(wsb + 33*MB);    // 8.5MB [33,42)
    u16*   act  = (u16*)(wsb + 16*MB);    // 32MB overlay [16,48) (Q/K/VT dead)
    u16*   ao   = (u16*)(wsb + 48*MB);    // 8MB  [48,56)
    float* p1a  = (float*)(wsb + 48*MB);  // FFN2 partial1 rows 0..2047 (ao dead)
    float* attb = (float*)(wsb + 56*MB);  // 16MB [56,72)
    u16*   WqkvT= (u16*)(wsb + 72*MB);    // 6MB [72,78)
    u16*   WoT  = (u16*)(wsb + 78*MB);    // 2MB [78,80)
    u16*   W1T  = (u16*)(wsb + 80*MB);    // 8MB [80,88)
    float* p1b  = (float*)(wsb + 80*MB);  // FFN2 partial1 rows 2048..4095 (W1T dead)
    u16*   W2T  = (u16*)(wsb + 88*MB);    // 8MB [88,96)
    float* sm   = (float*)(wsb + 96*MB);
    float* Kmb     = sm;
    float* Vmb     = Kmb + 2048;
    float* pooled  = Vmb + 2048;
    float* newh    = pooled + 2048;
    float* mproj   = newh + 2048;
    float* vpart   = mproj + 2048;             // 16384
    float* v2part  = vpart + 16384;            // 32768
    float* gpart   = v2part + 32768;           // 131072
    float* ppart   = gpart + 131072;           // 131072

    // all weight transposes in one launch (fp32 [K][N] -> bf16 [N][K])
    tr6_kernel<<<12288, 256, 0, stream>>>(Wq, Wk, Wv, Wo, W1, W2, WqkvT, WoT, W1T, W2T);

    // LN1 -> xn bf16
    ln_kernel<<<RR, 256, 0, stream>>>(x, nullptr, g1, be1, nullptr, nullptr, xn);
    // memory K/V tokens (fp32, split-K, fused)
    vecmat2_part<<<dim3(4,8,BB), 256, 0, stream>>>(h, Wmk, Wmv, v2part);
    vecmat2_red<<<dim3(4,BB), 256, 0, stream>>>(v2part, Kmb, Vmb);
    // fused QKV projection (MFMA): M=4096, N=3072; Q pre-scaled by 0.125*log2(e) for exp2 softmax
    mgemm<<<24*32, 256, 0, stream>>>(xn, WqkvT, 24, 1024, 1, MODE_QKV, nullptr, nullptr,
                                     0.125f*1.44269504088896f, Qbuf, Kbuf, VTb);
    fixup_kernel<<<8, 256, 0, stream>>>(Kmb, Vmb, Kbuf, VTb);
    // attention (512 blocks, XCD-grouped, pipelined)
    attn_mfma<<<512, 256, 0, stream>>>(Qbuf, Kbuf, VTb, ao);
    // attended = x + ao @ Wo  (fp32)
    mgemm<<<8*32, 256, 0, stream>>>(ao, WoT, 8, 1024, 1, MODE_F32R, nullptr, x, 1.f, attb, nullptr, nullptr);
    // mean pool, LSTM
    pool1_kernel<<<dim3(64,BB), 256, 0, stream>>>(attb, ppart);
    pool2_kernel<<<dim3(4,BB), 256, 0, stream>>>(ppart, pooled);
    gates_part<<<dim3(16,16,BB), 256, 0, stream>>>(pooled, h, Wih, Whh, gpart);
    lstm_kernel<<<8, 256, 0, stream>>>(gpart, b_ih, b_hh, c, newh, out + (size_t)RR*DD);
    vecmat_part<<<dim3(4,8,BB), 256, 0, stream>>>(newh, Wmp, vpart, DD, DD);
    vecmat_red<<<dim3(4,BB), 256, 0, stream>>>(vpart, mproj, DD);
    // mixed = attended + mproj (in place), hn = LN2(mixed) bf16
    ln_kernel<<<RR, 256, 0, stream>>>(attb, mproj, g2, be2, attb, nullptr, hn);
    // FFN1: act = gelu(hn @ W1 + bf1)
    mgemm<<<32*32, 256, 0, stream>>>(hn, W1T, 32, 1024, 1, MODE_GELU, bf1, nullptr, 1.f, act, nullptr, nullptr);
    // FFN2 split-K=2: partials
    mgemm<<<8*32*2, 256, 0, stream>>>(act, W2T, 8, 2048, 2, MODE_PART, nullptr, nullptr, 1.f, p0, p1a, p1b);
    // out = LN3(p0+p1+bias+resid)  (fused reduce)
    ln3f_kernel<<<RR, 256, 0, stream>>>(p0, p1a, p1b, bf2, attb, g3, be3, out);
}

// Round 10
// 303.927 us; speedup vs baseline: 15.0723x; 1.0847x over previous
//
#include <hip/hip_runtime.h>
#include <hip/hip_bf16.h>
#include <math.h>

#define BB 2
#define SS 2048
#define DD 1024
#define HH 16
#define RR (BB*SS)
#define KSTRIDE 2064   // padded key stride per (b,h)
#define MB (1024ull*1024ull)

typedef unsigned short u16;
typedef unsigned int u32;
typedef __attribute__((ext_vector_type(8))) short short8v;
typedef __attribute__((ext_vector_type(4))) float f32x4;
typedef __attribute__((ext_vector_type(16))) float f32x16;
typedef __attribute__((ext_vector_type(4))) u16 u16x4;

__device__ __forceinline__ u16 f2bf(float f){
    union { __hip_bfloat16 h; u16 u; } c; c.h = __float2bfloat16(f); return c.u;
}
__device__ __forceinline__ u32 pk2(float a, float b){
    return (u32)f2bf(a) | ((u32)f2bf(b) << 16);
}
__device__ __forceinline__ float exp2_raw(float x){
    float r;
    asm("v_exp_f32 %0, %1" : "=v"(r) : "v"(x));
    return r;
}
// A&S 7.1.26 erf approximation, |err| <= 1.5e-7
__device__ __forceinline__ float erf_fast(float x){
    float ax = fabsf(x);
    float t = __builtin_amdgcn_rcpf(1.0f + 0.3275911f*ax);
    float y = t*(0.254829592f + t*(-0.284496736f + t*(1.421413741f + t*(-1.453152027f + t*1.061405429f))));
    float r = 1.0f - y*__expf(-ax*ax);
    return copysignf(r, x);
}

#define GLL16(gp, lp) __builtin_amdgcn_global_load_lds( \
    (const __attribute__((address_space(1))) void*)(gp), \
    (__attribute__((address_space(3))) void*)(lp), 16, 0, 0)

#define VMCNT8 asm volatile("s_waitcnt vmcnt(8)" ::: "memory")
#define VMCNT4 asm volatile("s_waitcnt vmcnt(4)" ::: "memory")
#define VMCNT0 asm volatile("s_waitcnt vmcnt(0)" ::: "memory")
#define SBAR   __builtin_amdgcn_s_barrier()
#define SCHEDB __builtin_amdgcn_sched_barrier(0)

// ---------------- LayerNorm ----------------
__global__ __launch_bounds__(256) void ln_kernel(const float* __restrict__ in,
    const float* __restrict__ mproj, const float* __restrict__ g, const float* __restrict__ be,
    float* __restrict__ mixed_out, float* __restrict__ outf, u16* __restrict__ outb)
{
    int row = blockIdx.x; int b = row / SS; int tid = threadIdx.x;
    float4 v = ((const float4*)(in + (size_t)row*DD))[tid];
    if (mproj){
        float4 mp = ((const float4*)(mproj + (size_t)b*DD))[tid];
        v.x+=mp.x; v.y+=mp.y; v.z+=mp.z; v.w+=mp.w;
        ((float4*)(mixed_out + (size_t)row*DD))[tid] = v;
    }
    float s = v.x+v.y+v.z+v.w, s2 = v.x*v.x+v.y*v.y+v.z*v.z+v.w*v.w;
    #pragma unroll
    for (int off=32; off>0; off>>=1){ s += __shfl_down(s,off); s2 += __shfl_down(s2,off); }
    __shared__ float red[2][4];
    if ((tid&63)==0){ red[0][tid>>6]=s; red[1][tid>>6]=s2; }
    __syncthreads();
    float st = red[0][0]+red[0][1]+red[0][2]+red[0][3];
    float s2t= red[1][0]+red[1][1]+red[1][2]+red[1][3];
    float mean = st*(1.f/DD); float var = s2t*(1.f/DD)-mean*mean;
    float rs = rsqrtf(var + 1e-5f);
    float4 gg=((const float4*)g)[tid], bb2=((const float4*)be)[tid];
    float o0=(v.x-mean)*rs*gg.x+bb2.x, o1=(v.y-mean)*rs*gg.y+bb2.y;
    float o2=(v.z-mean)*rs*gg.z+bb2.z, o3=(v.w-mean)*rs*gg.w+bb2.w;
    if (outf){ float4 o={o0,o1,o2,o3}; ((float4*)(outf+(size_t)row*DD))[tid]=o; }
    if (outb){ u16x4 o={f2bf(o0),f2bf(o1),f2bf(o2),f2bf(o3)}; ((u16x4*)(outb+(size_t)row*DD))[tid]=o; }
}

// ---------------- fused splitred+LN3 ----------------
__global__ __launch_bounds__(256) void ln3f_kernel(const float* __restrict__ p0,
    const float* __restrict__ p1a, const float* __restrict__ p1b,
    const float* __restrict__ bias, const float* __restrict__ resid,
    const float* __restrict__ g, const float* __restrict__ be, float* __restrict__ out)
{
    int row = blockIdx.x; int tid = threadIdx.x;
    const float* p1 = (row < 2048) ? (p1a + (size_t)row*DD) : (p1b + (size_t)(row-2048)*DD);
    float4 a  = ((const float4*)(p0 + (size_t)row*DD))[tid];
    float4 b  = ((const float4*)p1)[tid];
    float4 bi = ((const float4*)bias)[tid];
    float4 rs4= ((const float4*)(resid + (size_t)row*DD))[tid];
    float4 v = {a.x+b.x+bi.x+rs4.x, a.y+b.y+bi.y+rs4.y, a.z+b.z+bi.z+rs4.z, a.w+b.w+bi.w+rs4.w};
    float s = v.x+v.y+v.z+v.w, s2 = v.x*v.x+v.y*v.y+v.z*v.z+v.w*v.w;
    #pragma unroll
    for (int off=32; off>0; off>>=1){ s += __shfl_down(s,off); s2 += __shfl_down(s2,off); }
    __shared__ float red[2][4];
    if ((tid&63)==0){ red[0][tid>>6]=s; red[1][tid>>6]=s2; }
    __syncthreads();
    float st = red[0][0]+red[0][1]+red[0][2]+red[0][3];
    float s2t= red[1][0]+red[1][1]+red[1][2]+red[1][3];
    float mean = st*(1.f/DD); float var = s2t*(1.f/DD)-mean*mean;
    float rs = rsqrtf(var + 1e-5f);
    float4 gg=((const float4*)g)[tid], bb2=((const float4*)be)[tid];
    float4 o;
    o.x=(v.x-mean)*rs*gg.x+bb2.x; o.y=(v.y-mean)*rs*gg.y+bb2.y;
    o.z=(v.z-mean)*rs*gg.z+bb2.z; o.w=(v.w-mean)*rs*gg.w+bb2.w;
    ((float4*)(out + (size_t)row*DD))[tid] = o;
}

// ---------------- merged weight transposes ----------------
__global__ __launch_bounds__(256) void tr6_kernel(const float* __restrict__ Wq, const float* __restrict__ Wk,
    const float* __restrict__ Wv, const float* __restrict__ Wo,
    const float* __restrict__ W1, const float* __restrict__ W2,
    u16* __restrict__ WqkvT, u16* __restrict__ WoT, u16* __restrict__ W1T, u16* __restrict__ W2T)
{
    __shared__ float t[32][33];
    int bid = blockIdx.x;
    const float* in; u16* out; int K, N, n0, k0;
    if (bid < 3072){
        int m = bid >> 10, r = bid & 1023;
        in = (m==0) ? Wq : (m==1) ? Wk : Wv;
        out = WqkvT + (size_t)m*1024*1024;
        K = 1024; N = 1024; n0 = (r & 31)*32; k0 = (r >> 5)*32;
    } else if (bid < 4096){
        int r = bid - 3072;
        in = Wo; out = WoT; K = 1024; N = 1024; n0 = (r & 31)*32; k0 = (r >> 5)*32;
    } else if (bid < 8192){
        int r = bid - 4096;
        in = W1; out = W1T; K = 1024; N = 4096; n0 = (r & 127)*32; k0 = (r >> 7)*32;
    } else {
        int r = bid - 8192;
        in = W2; out = W2T; K = 4096; N = 1024; n0 = (r & 31)*32; k0 = (r >> 5)*32;
    }
    int tx = threadIdx.x & 31, ty = threadIdx.x >> 5;
    #pragma unroll
    for (int i=0;i<4;i++){ int k = ty + i*8; t[k][tx] = in[(size_t)(k0+k)*N + n0 + tx]; }
    __syncthreads();
    #pragma unroll
    for (int i=0;i<4;i++){ int n = ty + i*8; out[(size_t)(n0+n)*K + k0 + tx] = f2bf(t[tx][n]); }
}

// =============== 256x256 8-phase GEMM (T3+T4+T2+T5), 512 threads = 8 waves (2M x 4N) ===============
// C = A[M,K] @ BT[N,K]^T. modes: 0 = GELU(bf16 out), 1 = QKV epilogue.
// LDS: [buf2][op2][ks2][256 rows][32 K] bf16 planes (16KB each) = 128KB. 64B rows, slot^((row>>1)&3).
__global__ __launch_bounds__(512) void mgemm256(const u16* __restrict__ A, const u16* __restrict__ BT,
    int nbx, int K, int mode, const float* __restrict__ bias, float scale,
    void* __restrict__ Cout, void* __restrict__ C2a, void* __restrict__ C2b)
{
    __shared__ __align__(16) u16 lds[2][2][2][256*32];
    int tid = threadIdx.x, l = tid&63, w = tid>>6;
    int wr = w>>2, wc = w&3;
    int nwg = gridDim.x, q8 = nwg>>3;
    int bid = blockIdx.x;
    int swz = (bid & 7)*q8 + (bid >> 3);
    int by = swz / nbx, bx = swz % nbx;
    int bm = by*256, bn = bx*256;
    const int NT = K >> 6;

    f32x4 acc[8][4];
    #pragma unroll
    for (int i=0;i<8;i++)
        #pragma unroll
        for (int j=0;j<4;j++)
            #pragma unroll
            for (int r=0;r<4;r++) acc[i][j][r]=0.f;

    // stage one 16KB plane: 16 issues (8 waves x 2), each 64 lanes x 16B
    auto stage_plane = [&](int buf, int op, int ks, int tt){
        const u16* base = op ? BT : A;
        int tile0 = op ? bn : bm;
        #pragma unroll
        for (int i=0;i<2;i++){
            int rbase = (w*2+i)*16;
            int row = rbase + (l>>2);
            int slotlog = (l&3) ^ ((row>>1)&3);
            const u16* g = base + (size_t)(tile0 + row)*K + tt*64 + ks*32 + slotlog*8;
            GLL16(g, (u16*)&lds[buf][op][ks][0] + rbase*32);
        }
    };
    auto ds_a = [&](int buf, int ks, int ai) -> short8v {
        int row = wr*128 + ai*16 + (l&15);
        int slot = (l>>4) ^ ((row>>1)&3);
        return *(const short8v*)((const char*)&lds[buf][0][ks][0] + row*64 + slot*16);
    };
    auto ds_b = [&](int buf, int ks, int bi) -> short8v {
        int row = wc*64 + bi*16 + (l&15);
        int slot = (l>>4) ^ ((row>>1)&3);
        return *(const short8v*)((const char*)&lds[buf][1][ks][0] + row*64 + slot*16);
    };

    // prologue: t0.ks0, t0.ks1, t1.ks0  (12 issues/wave)
    stage_plane(0,0,0,0); stage_plane(0,1,0,0);
    stage_plane(0,0,1,0); stage_plane(0,1,1,0);
    stage_plane(1,0,0,1); stage_plane(1,1,0,1);
    VMCNT8;       // t0.ks0 landed (8 newer in flight)
    SBAR; SCHEDB;

    for (int t=0; t<NT; t++){
        int buf = t&1, obuf = buf^1;
        bool s1 = (t+1 < NT), s2 = (t+2 < NT);
        short8v b0,b1,b2,b3, a0,a1,a2,a3;
        // ---- Ph0: frags @ks0 (a0-3, b0-3); stage A-plane of (t+1).ks1
        b0=ds_b(buf,0,0); b1=ds_b(buf,0,1); b2=ds_b(buf,0,2); b3=ds_b(buf,0,3);
        a0=ds_a(buf,0,0); a1=ds_a(buf,0,1); a2=ds_a(buf,0,2); a3=ds_a(buf,0,3);
        if (s1) stage_plane(obuf,0,1,t+1);
        __builtin_amdgcn_s_setprio(1);
        acc[0][0]=__builtin_amdgcn_mfma_f32_16x16x32_bf16(b0,a0,acc[0][0],0,0,0);
        acc[0][1]=__builtin_amdgcn_mfma_f32_16x16x32_bf16(b1,a0,acc[0][1],0,0,0);
        acc[0][2]=__builtin_amdgcn_mfma_f32_16x16x32_bf16(b2,a0,acc[0][2],0,0,0);
        acc[0][3]=__builtin_amdgcn_mfma_f32_16x16x32_bf16(b3,a0,acc[0][3],0,0,0);
        acc[1][0]=__builtin_amdgcn_mfma_f32_16x16x32_bf16(b0,a1,acc[1][0],0,0,0);
        acc[1][1]=__builtin_amdgcn_mfma_f32_16x16x32_bf16(b1,a1,acc[1][1],0,0,0);
        acc[1][2]=__builtin_amdgcn_mfma_f32_16x16x32_bf16(b2,a1,acc[1][2],0,0,0);
        acc[1][3]=__builtin_amdgcn_mfma_f32_16x16x32_bf16(b3,a1,acc[1][3],0,0,0);
        acc[2][0]=__builtin_amdgcn_mfma_f32_16x16x32_bf16(b0,a2,acc[2][0],0,0,0);
        acc[2][1]=__builtin_amdgcn_mfma_f32_16x16x32_bf16(b1,a2,acc[2][1],0,0,0);
        acc[2][2]=__builtin_amdgcn_mfma_f32_16x16x32_bf16(b2,a2,acc[2][2],0,0,0);
        acc[2][3]=__builtin_amdgcn_mfma_f32_16x16x32_bf16(b3,a2,acc[2][3],0,0,0);
        acc[3][0]=__builtin_amdgcn_mfma_f32_16x16x32_bf16(b0,a3,acc[3][0],0,0,0);
        acc[3][1]=__builtin_amdgcn_mfma_f32_16x16x32_bf16(b1,a3,acc[3][1],0,0,0);
        acc[3][2]=__builtin_amdgcn_mfma_f32_16x16x32_bf16(b2,a3,acc[3][2],0,0,0);
        acc[3][3]=__builtin_amdgcn_mfma_f32_16x16x32_bf16(b3,a3,acc[3][3],0,0,0);
        __builtin_amdgcn_s_setprio(0);
        SBAR; SCHEDB;
        // ---- Ph1: a4-7 @ks0; stage B-plane of (t+1).ks1
        a0=ds_a(buf,0,4); a1=ds_a(buf,0,5); a2=ds_a(buf,0,6); a3=ds_a(buf,0,7);
        if (s1) stage_plane(obuf,1,1,t+1);
        __builtin_amdgcn_s_setprio(1);
        acc[4][0]=__builtin_amdgcn_mfma_f32_16x16x32_bf16(b0,a0,acc[4][0],0,0,0);
        acc[4][1]=__builtin_amdgcn_mfma_f32_16x16x32_bf16(b1,a0,acc[4][1],0,0,0);
        acc[4][2]=__builtin_amdgcn_mfma_f32_16x16x32_bf16(b2,a0,acc[4][2],0,0,0);
        acc[4][3]=__builtin_amdgcn_mfma_f32_16x16x32_bf16(b3,a0,acc[4][3],0,0,0);
        acc[5][0]=__builtin_amdgcn_mfma_f32_16x16x32_bf16(b0,a1,acc[5][0],0,0,0);
        acc[5][1]=__builtin_amdgcn_mfma_f32_16x16x32_bf16(b1,a1,acc[5][1],0,0,0);
        acc[5][2]=__builtin_amdgcn_mfma_f32_16x16x32_bf16(b2,a1,acc[5][2],0,0,0);
        acc[5][3]=__builtin_amdgcn_mfma_f32_16x16x32_bf16(b3,a1,acc[5][3],0,0,0);
        acc[6][0]=__builtin_amdgcn_mfma_f32_16x16x32_bf16(b0,a2,acc[6][0],0,0,0);
        acc[6][1]=__builtin_amdgcn_mfma_f32_16x16x32_bf16(b1,a2,acc[6][1],0,0,0);
        acc[6][2]=__builtin_amdgcn_mfma_f32_16x16x32_bf16(b2,a2,acc[6][2],0,0,0);
        acc[6][3]=__builtin_amdgcn_mfma_f32_16x16x32_bf16(b3,a2,acc[6][3],0,0,0);
        acc[7][0]=__builtin_amdgcn_mfma_f32_16x16x32_bf16(b0,a3,acc[7][0],0,0,0);
        acc[7][1]=__builtin_amdgcn_mfma_f32_16x16x32_bf16(b1,a3,acc[7][1],0,0,0);
        acc[7][2]=__builtin_amdgcn_mfma_f32_16x16x32_bf16(b2,a3,acc[7][2],0,0,0);
        acc[7][3]=__builtin_amdgcn_mfma_f32_16x16x32_bf16(b3,a3,acc[7][3],0,0,0);
        __builtin_amdgcn_s_setprio(0);
        if (s1) { VMCNT8; } else { VMCNT0; }   // (t).ks1 landed
        SBAR; SCHEDB;
        // ---- Ph2: frags @ks1 (a0-3,b0-3); stage A-plane of (t+2).ks0
        b0=ds_b(buf,1,0); b1=ds_b(buf,1,1); b2=ds_b(buf,1,2); b3=ds_b(buf,1,3);
        a0=ds_a(buf,1,0); a1=ds_a(buf,1,1); a2=ds_a(buf,1,2); a3=ds_a(buf,1,3);
        if (s2) stage_plane(buf,0,0,t+2);
        __builtin_amdgcn_s_setprio(1);
        acc[0][0]=__builtin_amdgcn_mfma_f32_16x16x32_bf16(b0,a0,acc[0][0],0,0,0);
        acc[0][1]=__builtin_amdgcn_mfma_f32_16x16x32_bf16(b1,a0,acc[0][1],0,0,0);
        acc[0][2]=__builtin_amdgcn_mfma_f32_16x16x32_bf16(b2,a0,acc[0][2],0,0,0);
        acc[0][3]=__builtin_amdgcn_mfma_f32_16x16x32_bf16(b3,a0,acc[0][3],0,0,0);
        acc[1][0]=__builtin_amdgcn_mfma_f32_16x16x32_bf16(b0,a1,acc[1][0],0,0,0);
        acc[1][1]=__builtin_amdgcn_mfma_f32_16x16x32_bf16(b1,a1,acc[1][1],0,0,0);
        acc[1][2]=__builtin_amdgcn_mfma_f32_16x16x32_bf16(b2,a1,acc[1][2],0,0,0);
        acc[1][3]=__builtin_amdgcn_mfma_f32_16x16x32_bf16(b3,a1,acc[1][3],0,0,0);
        acc[2][0]=__builtin_amdgcn_mfma_f32_16x16x32_bf16(b0,a2,acc[2][0],0,0,0);
        acc[2][1]=__builtin_amdgcn_mfma_f32_16x16x32_bf16(b1,a2,acc[2][1],0,0,0);
        acc[2][2]=__builtin_amdgcn_mfma_f32_16x16x32_bf16(b2,a2,acc[2][2],0,0,0);
        acc[2][3]=__builtin_amdgcn_mfma_f32_16x16x32_bf16(b3,a2,acc[2][3],0,0,0);
        acc[3][0]=__builtin_amdgcn_mfma_f32_16x16x32_bf16(b0,a3,acc[3][0],0,0,0);
        acc[3][1]=__builtin_amdgcn_mfma_f32_16x16x32_bf16(b1,a3,acc[3][1],0,0,0);
        acc[3][2]=__builtin_amdgcn_mfma_f32_16x16x32_bf16(b2,a3,acc[3][2],0,0,0);
        acc[3][3]=__builtin_amdgcn_mfma_f32_16x16x32_bf16(b3,a3,acc[3][3],0,0,0);
        __builtin_amdgcn_s_setprio(0);
        SBAR; SCHEDB;
        // ---- Ph3: a4-7 @ks1; stage B-plane of (t+2).ks0
        a0=ds_a(buf,1,4); a1=ds_a(buf,1,5); a2=ds_a(buf,1,6); a3=ds_a(buf,1,7);
        if (s2) stage_plane(buf,1,0,t+2);
        __builtin_amdgcn_s_setprio(1);
        acc[4][0]=__builtin_amdgcn_mfma_f32_16x16x32_bf16(b0,a0,acc[4][0],0,0,0);
        acc[4][1]=__builtin_amdgcn_mfma_f32_16x16x32_bf16(b1,a0,acc[4][1],0,0,0);
        acc[4][2]=__builtin_amdgcn_mfma_f32_16x16x32_bf16(b2,a0,acc[4][2],0,0,0);
        acc[4][3]=__builtin_amdgcn_mfma_f32_16x16x32_bf16(b3,a0,acc[4][3],0,0,0);
        acc[5][0]=__builtin_amdgcn_mfma_f32_16x16x32_bf16(b0,a1,acc[5][0],0,0,0);
        acc[5][1]=__builtin_amdgcn_mfma_f32_16x16x32_bf16(b1,a1,acc[5][1],0,0,0);
        acc[5][2]=__builtin_amdgcn_mfma_f32_16x16x32_bf16(b2,a1,acc[5][2],0,0,0);
        acc[5][3]=__builtin_amdgcn_mfma_f32_16x16x32_bf16(b3,a1,acc[5][3],0,0,0);
        acc[6][0]=__builtin_amdgcn_mfma_f32_16x16x32_bf16(b0,a2,acc[6][0],0,0,0);
        acc[6][1]=__builtin_amdgcn_mfma_f32_16x16x32_bf16(b1,a2,acc[6][1],0,0,0);
        acc[6][2]=__builtin_amdgcn_mfma_f32_16x16x32_bf16(b2,a2,acc[6][2],0,0,0);
        acc[6][3]=__builtin_amdgcn_mfma_f32_16x16x32_bf16(b3,a2,acc[6][3],0,0,0);
        acc[7][0]=__builtin_amdgcn_mfma_f32_16x16x32_bf16(b0,a3,acc[7][0],0,0,0);
        acc[7][1]=__builtin_amdgcn_mfma_f32_16x16x32_bf16(b1,a3,acc[7][1],0,0,0);
        acc[7][2]=__builtin_amdgcn_mfma_f32_16x16x32_bf16(b2,a3,acc[7][2],0,0,0);
        acc[7][3]=__builtin_amdgcn_mfma_f32_16x16x32_bf16(b3,a3,acc[7][3],0,0,0);
        __builtin_amdgcn_s_setprio(0);
        if (s2) { VMCNT8; } else if (s1) { VMCNT4; } else { VMCNT0; }  // (t+1).ks0 landed
        SBAR; SCHEDB;
    }

    // epilogue
    #pragma unroll
    for (int ai=0; ai<8; ai++){
        int m = bm + wr*128 + ai*16 + (l&15);
        #pragma unroll
        for (int bi=0; bi<4; bi++){
            int nb = bn + wc*64 + bi*16 + ((l>>4)<<2);
            f32x4 v = acc[ai][bi];
            if (mode == 0){   // GELU bf16
                float4 bv = *(const float4*)(bias + nb);
                float t0=v[0]+bv.x, t1=v[1]+bv.y, t2=v[2]+bv.z, t3=v[3]+bv.w;
                u16x4 o;
                o[0]=f2bf(0.5f*t0*(1.0f+erf_fast(t0*0.70710678118654752f)));
                o[1]=f2bf(0.5f*t1*(1.0f+erf_fast(t1*0.70710678118654752f)));
                o[2]=f2bf(0.5f*t2*(1.0f+erf_fast(t2*0.70710678118654752f)));
                o[3]=f2bf(0.5f*t3*(1.0f+erf_fast(t3*0.70710678118654752f)));
                *(u16x4*)((u16*)Cout + (size_t)m*(nbx*256) + nb) = o;
            } else {          // QKV
                if (nb < 1024){
                    u16x4 o;
                    #pragma unroll
                    for (int r=0;r<4;r++) o[r] = f2bf(v[r]*scale);
                    *(u16x4*)((u16*)Cout + (size_t)m*1024 + nb) = o;
                } else if (nb < 2048){
                    int cc = nb-1024; int hh = cc>>6, dh = cc&63;
                    int b2 = m>>11, key = m&2047;
                    u16x4 o;
                    #pragma unroll
                    for (int r=0;r<4;r++) o[r] = f2bf(v[r]);
                    *(u16x4*)((u16*)C2a + ((size_t)(b2*HH+hh)*KSTRIDE + key)*64 + dh) = o;
                } else {
                    int cc = nb-2048; int hh = cc>>6, dh = cc&63;
                    int b2 = m>>11, key = m&2047;
                    #pragma unroll
                    for (int r=0;r<4;r++)
                        ((u16*)C2b)[((size_t)(b2*HH+hh)*64 + dh + r)*KSTRIDE + key] = f2bf(v[r]);
                }
            }
        }
    }
}

// ---------------- 128x128 MFMA GEMM (kept for Wo and FFN2 split-K) ----------------
#define MODE_F32R 3
#define MODE_PART 6

__global__ __launch_bounds__(256) void mgemm(const u16* __restrict__ A, const u16* __restrict__ BT,
    int nbx, int Kc, int kchunks, int mode,
    const float* __restrict__ bias, const float* __restrict__ resid, float scale,
    void* __restrict__ Cout, void* __restrict__ C2a, void* __restrict__ C2b)
{
    int tid=threadIdx.x, l=tid&63, w=tid>>6;
    int nwg = gridDim.x;
    int qq = nwg >> 3;
    int bid = blockIdx.x;
    int swz = (bid & 7)*qq + (bid >> 3);
    int tiles = nwg / kchunks;
    int chunk = swz / tiles;
    int t2 = swz % tiles;
    int sby = t2 / (nbx*8);
    int rem = t2 - sby*(nbx*8);
    int sbx = rem >> 6;
    int ci  = rem & 63;
    int bx = sbx*8 + (ci&7);
    int by = sby*8 + (ci>>3);

    int bm = by*128, bn = bx*128;
    int N = nbx*128;
    int lda = Kc*kchunks;
    int koff = chunk*Kc;
    int wr = w>>1, wc = w&1;
    f32x4 acc[4][4];
    #pragma unroll
    for(int i=0;i<4;i++)
        #pragma unroll
        for(int j=0;j<4;j++)
            #pragma unroll
            for(int r=0;r<4;r++) acc[i][j][r]=0.f;

    __shared__ __align__(16) u16 Al[2][4096];
    __shared__ __align__(16) u16 Bl[2][4096];
    int srow = (w<<4) + (l>>2);
    int sph  = l&3;
    const int NT = Kc >> 5;

    auto stage = [&](int buf, int kt){
        #pragma unroll
        for (int r=0;r<2;r++){
            int rowA = srow + r*64;
            int sl = sph ^ ((rowA>>1)&3);
            const u16* gA = A + (size_t)(bm+rowA)*lda + koff + kt*32 + sl*8;
            GLL16(gA, (char*)&Al[buf][0] + r*4096 + w*1024);
            const u16* gB = BT + (size_t)(bn+rowA)*lda + koff + kt*32 + sl*8;
            GLL16(gB, (char*)&Bl[buf][0] + r*4096 + w*1024);
        }
    };

    int cur=0;
    stage(0,0);
    __syncthreads();
    for (int kt=0; kt<NT; kt++){
        if (kt+1<NT) stage(cur^1, kt+1);
        short8v af[4], bf[4];
        #pragma unroll
        for (int mi=0;mi<4;mi++){
            int row = wr*64 + mi*16 + (l&15);
            int sl = (l>>4) ^ ((row>>1)&3);
            af[mi] = *(const short8v*)((const char*)&Al[cur][0] + row*64 + sl*16);
        }
        #pragma unroll
        for (int ni=0;ni<4;ni++){
            int row = wc*64 + ni*16 + (l&15);
            int sl = (l>>4) ^ ((row>>1)&3);
            bf[ni] = *(const short8v*)((const char*)&Bl[cur][0] + row*64 + sl*16);
        }
        #pragma unroll
        for (int mi=0;mi<4;mi++)
            #pragma unroll
            for (int ni=0;ni<4;ni++)
                acc[mi][ni] = __builtin_amdgcn_mfma_f32_16x16x32_bf16(bf[ni], af[mi], acc[mi][ni], 0,0,0);
        __syncthreads();
        cur ^= 1;
    }

    #pragma unroll
    for (int mi=0;mi<4;mi++){
        int m = bm + wr*64 + mi*16 + (l&15);
        #pragma unroll
        for (int ni=0;ni<4;ni++){
            int nb = bn + wc*64 + ni*16 + ((l>>4)<<2);
            f32x4 v = acc[mi][ni];
            if (mode==MODE_F32R){
                float4 rs = *(const float4*)(resid + (size_t)m*N + nb);
                float4 o = {v[0]+rs.x, v[1]+rs.y, v[2]+rs.z, v[3]+rs.w};
                *(float4*)((float*)Cout + (size_t)m*N + nb) = o;
            } else { // MODE_PART
                float4 o = {v[0],v[1],v[2],v[3]};
                if (chunk==0)       *(float4*)((float*)Cout + (size_t)m*N + nb) = o;
                else if (m < 2048)  *(float4*)((float*)C2a  + (size_t)m*N + nb) = o;
                else                *(float4*)((float*)C2b  + (size_t)(m-2048)*N + nb) = o;
            }
        }
    }
}

// ---------------- MFMA flash attention: pipelined, triple-buffer, exp2 softmax ----------------
__global__ __launch_bounds__(256) void attn_mfma(const u16* __restrict__ Qb, const u16* __restrict__ Kb,
    const u16* __restrict__ VTb, u16* __restrict__ ao)
{
    __shared__ __align__(16) u16 Kl[3][4096];
    __shared__ __align__(16) u16 Vl[3][4096];
    int tid=threadIdx.x, l=tid&63, w=tid>>6;
    int l31=l&31, hi=l>>5;
    int bid = blockIdx.x;
    int xcd = bid & 7, idx = bid >> 3;
    int bh = xcd*4 + (idx>>4);
    int qt = idx & 15;
    int b=bh>>4, h=bh&15;
    int qrow = qt*128 + w*32 + l31;

    const u16* qptr = Qb + (size_t)(b*SS + qrow)*DD + h*64;
    short8v qf[4];
    #pragma unroll
    for (int t=0;t<4;t++) qf[t] = *(const short8v*)(qptr + t*16 + hi*8);

    f32x16 so0, so1;
    #pragma unroll
    for (int i=0;i<16;i++){ so0[i]=0.f; so1[i]=0.f; }
    float l_run=0.f;

    int skey = (w<<3) + (l>>3);
    int ssl  = l&7;
    auto stage = [&](int buf, int kt){
        #pragma unroll
        for (int r=0;r<2;r++){
            int key = skey + r*32;
            int slot = ssl ^ (key&7);
            const u16* gK = Kb + ((size_t)bh*KSTRIDE + kt*64 + key)*64 + slot*8;
            GLL16(gK, (char*)&Kl[buf][0] + r*4096 + w*1024);
            const u16* gV = VTb + ((size_t)bh*64 + key)*KSTRIDE + kt*64 + slot*8;
            GLL16(gV, (char*)&Vl[buf][0] + r*4096 + w*1024);
        }
    };

    auto QK = [&](int bf, f32x16& s0, f32x16& s1){
        #pragma unroll
        for (int i=0;i<16;i++){ s0[i]=0.f; s1[i]=0.f; }
        __builtin_amdgcn_s_setprio(1);
        #pragma unroll
        for (int t=0;t<4;t++){
            int sl = (2*t+hi) ^ (l31&7);
            short8v kf0 = *(const short8v*)((const char*)&Kl[bf][0] + l31*128 + sl*16);
            s0 = __builtin_amdgcn_mfma_f32_32x32x16_bf16(kf0, qf[t], s0, 0,0,0);
            short8v kf1 = *(const short8v*)((const char*)&Kl[bf][0] + (32+l31)*128 + sl*16);
            s1 = __builtin_amdgcn_mfma_f32_32x32x16_bf16(kf1, qf[t], s1, 0,0,0);
        }
        __builtin_amdgcn_s_setprio(0);
    };

    auto SMPV = [&](int bf, f32x16& s0, f32x16& s1){
        float psum = 0.f;
        #pragma unroll
        for (int r=0;r<16;r++){
            float p=exp2_raw(s0[r]); s0[r]=p; psum+=p;
            float q=exp2_raw(s1[r]); s1[r]=q; psum+=q;
        }
        psum += __shfl_xor(psum, 32);
        l_run += psum;
        short8v pf[4];
        #pragma unroll
        for (int t=0;t<4;t++){
            u32 a0,a1,b0,b1;
            if (t==0){ a0=pk2(s0[0],s0[1]);   a1=pk2(s0[2],s0[3]);   b0=pk2(s0[4],s0[5]);   b1=pk2(s0[6],s0[7]); }
            else if (t==1){ a0=pk2(s0[8],s0[9]);   a1=pk2(s0[10],s0[11]); b0=pk2(s0[12],s0[13]); b1=pk2(s0[14],s0[15]); }
            else if (t==2){ a0=pk2(s1[0],s1[1]);   a1=pk2(s1[2],s1[3]);   b0=pk2(s1[4],s1[5]);   b1=pk2(s1[6],s1[7]); }
            else          { a0=pk2(s1[8],s1[9]);   a1=pk2(s1[10],s1[11]); b0=pk2(s1[12],s1[13]); b1=pk2(s1[14],s1[15]); }
            u32 sx0 = hi ? a0 : b0, sx1 = hi ? a1 : b1;
            u32 r0 = (u32)__shfl_xor((int)sx0, 32);
            u32 r1 = (u32)__shfl_xor((int)sx1, 32);
            union { u32 u[4]; short8v v; } cvt;
            cvt.u[0] = hi ? r0 : a0;
            cvt.u[1] = hi ? r1 : a1;
            cvt.u[2] = hi ? b0 : r0;
            cvt.u[3] = hi ? b1 : r1;
            pf[t] = cvt.v;
        }
        __builtin_amdgcn_s_setprio(1);
        #pragma unroll
        for (int t=0;t<4;t++){
            int sl = (2*t+hi) ^ (l31&7);
            short8v vf0 = *(const short8v*)((const char*)&Vl[bf][0] + l31*128 + sl*16);
            so0 = __builtin_amdgcn_mfma_f32_32x32x16_bf16(vf0, pf[t], so0, 0,0,0);
            short8v vf1 = *(const short8v*)((const char*)&Vl[bf][0] + (32+l31)*128 + sl*16);
            so1 = __builtin_amdgcn_mfma_f32_32x32x16_bf16(vf1, pf[t], so1, 0,0,0);
        }
        __builtin_amdgcn_s_setprio(0);
    };

    const int NTILE = 33;
    int bufA = 0, bufB = 1, bufC = 2;
    stage(0, 0);
    stage(1, 1);
    __syncthreads();

    f32x16 sA0, sA1, sB0, sB1;
    QK(bufA, sA0, sA1);

    auto ITER = [&](f32x16& c0, f32x16& c1, f32x16& n0, f32x16& n1, int t){
        if (t+2 < NTILE) stage(bufC, t+2);
        QK(bufB, n0, n1);
        SMPV(bufA, c0, c1);
        __syncthreads();
        int tmp = bufA; bufA = bufB; bufB = bufC; bufC = tmp;
    };
    #pragma unroll 1
    for (int tt=0; tt<16; tt++){
        ITER(sA0, sA1, sB0, sB1, 2*tt);
        ITER(sB0, sB1, sA0, sA1, 2*tt+1);
    }
    #pragma unroll
    for (int r=0;r<16;r++){
        int k0 = 2048 + (r&3) + 8*(r>>2) + 4*hi;
        if (k0 >= 2049) sA0[r] = -1e30f;
        sA1[r] = -1e30f;
    }
    SMPV(bufA, sA0, sA1);

    float inv = 1.f / l_run;
    u16* aop = ao + (size_t)(b*SS + qrow)*DD + h*64;
    #pragma unroll
    for (int rg=0; rg<4; rg++){
        int dh0 = rg*8 + 4*hi;
        u16x4 o0, o1;
        #pragma unroll
        for (int j=0;j<4;j++){ o0[j]=f2bf(so0[rg*4+j]*inv); o1[j]=f2bf(so1[rg*4+j]*inv); }
        *(u16x4*)(aop + dh0) = o0;
        *(u16x4*)(aop + 32 + dh0) = o1;
    }
}

// ---------------- split-K matvec ----------------
__global__ __launch_bounds__(256) void vecmat_part(const float* __restrict__ vec,
    const float* __restrict__ W, float* __restrict__ part, int K, int N)
{
    int b = blockIdx.z, kc = blockIdx.y;
    int j = blockIdx.x*256 + threadIdx.x;
    int k0 = kc * (K >> 3);
    float acc = 0.0f;
    #pragma unroll 4
    for (int k = k0; k < k0 + (K >> 3); k++)
        acc += vec[(size_t)b*K + k] * W[(size_t)k*N + j];
    part[((size_t)b*8 + kc)*N + j] = acc;
}

__global__ __launch_bounds__(256) void vecmat_red(const float* __restrict__ part,
    float* __restrict__ out, int N)
{
    int b = blockIdx.y;
    int j = blockIdx.x*256 + threadIdx.x;
    float acc = 0.0f;
    #pragma unroll
    for (int kc = 0; kc < 8; kc++) acc += part[((size_t)b*8 + kc)*N + j];
    out[(size_t)b*N + j] = acc;
}

__global__ __launch_bounds__(256) void vecmat2_part(const float* __restrict__ vec,
    const float* __restrict__ Wa, const float* __restrict__ Wb, float* __restrict__ part)
{
    int b = blockIdx.z, kc = blockIdx.y;
    int j = blockIdx.x*256 + threadIdx.x;
    int k0 = kc * 128;
    float accA = 0.0f, accB = 0.0f;
    #pragma unroll 4
    for (int k = k0; k < k0 + 128; k++){
        float v = vec[(size_t)b*DD + k];
        accA += v * Wa[(size_t)k*DD + j];
        accB += v * Wb[(size_t)k*DD + j];
    }
    part[((size_t)b*8 + kc)*2048 + j] = accA;
    part[((size_t)b*8 + kc)*2048 + 1024 + j] = accB;
}

__global__ __launch_bounds__(256) void vecmat2_red(const float* __restrict__ part,
    float* __restrict__ outA, float* __restrict__ outB)
{
    int b = blockIdx.y;
    int j = blockIdx.x*256 + threadIdx.x;
    float accA = 0.0f, accB = 0.0f;
    #pragma unroll
    for (int kc = 0; kc < 8; kc++){
        accA += part[((size_t)b*8 + kc)*2048 + j];
        accB += part[((size_t)b*8 + kc)*2048 + 1024 + j];
    }
    outA[(size_t)b*DD + j] = accA;
    outB[(size_t)b*DD + j] = accB;
}

__global__ __launch_bounds__(256) void fixup_kernel(const float* __restrict__ Kmb,
    const float* __restrict__ Vmb, u16* __restrict__ Kb, u16* __restrict__ VTb)
{
    int idx = blockIdx.x*256 + threadIdx.x;
    int b = idx>>10, j = idx&1023; int h=j>>6, dh=j&63; int bh=b*HH+h;
    Kb[((size_t)bh*KSTRIDE + 2048)*64 + dh] = f2bf(Kmb[idx]);
    VTb[((size_t)bh*64 + dh)*KSTRIDE + 2048] = f2bf(Vmb[idx]);
}

__global__ __launch_bounds__(256) void pool1_kernel(const float* __restrict__ att, float* __restrict__ ppart)
{
    int b = blockIdx.y, sc = blockIdx.x;
    int tid = threadIdx.x;
    float4 acc = {0,0,0,0};
    for (int s = 0; s < 32; s++) {
        int row = b*SS + sc*32 + s;
        float4 v = ((const float4*)(att + (size_t)row*DD))[tid];
        acc.x += v.x; acc.y += v.y; acc.z += v.z; acc.w += v.w;
    }
    ((float4*)(ppart + ((size_t)b*64 + sc)*DD))[tid] = acc;
}

__global__ __launch_bounds__(256) void pool2_kernel(const float* __restrict__ ppart, float* __restrict__ pooled)
{
    int b = blockIdx.y;
    int j = blockIdx.x*256 + threadIdx.x;
    float acc = 0.0f;
    for (int sc = 0; sc < 64; sc++) acc += ppart[((size_t)b*64 + sc)*DD + j];
    pooled[(size_t)b*DD + j] = acc * (1.0f/SS);
}

__global__ __launch_bounds__(256) void gates_part(const float* __restrict__ pooled,
    const float* __restrict__ h, const float* __restrict__ Wih, const float* __restrict__ Whh,
    float* __restrict__ part)
{
    int b = blockIdx.z, kc = blockIdx.y;
    int j = blockIdx.x*256 + threadIdx.x;
    int k0 = kc * 64;
    float acc = 0.0f;
    #pragma unroll 4
    for (int k = k0; k < k0 + 64; k++)
        acc += pooled[(size_t)b*DD + k] * Wih[(size_t)k*4*DD + j]
             + h[(size_t)b*DD + k]      * Whh[(size_t)k*4*DD + j];
    part[((size_t)b*16 + kc)*4*DD + j] = acc;
}

__device__ __forceinline__ float sigmoidf_(float x) { return 1.0f / (1.0f + __expf(-x)); }

__global__ __launch_bounds__(256) void lstm_kernel(const float* __restrict__ gpart,
    const float* __restrict__ b_ih, const float* __restrict__ b_hh,
    const float* __restrict__ c, float* __restrict__ newh_ws, float* __restrict__ out_tail)
{
    int idx = blockIdx.x*256 + threadIdx.x;
    int b = idx >> 10, d = idx & 1023;
    float sI = b_ih[d]          + b_hh[d];
    float sF = b_ih[DD + d]     + b_hh[DD + d];
    float sG = b_ih[2*DD + d]   + b_hh[2*DD + d];
    float sO = b_ih[3*DD + d]   + b_hh[3*DD + d];
    #pragma unroll
    for (int kc = 0; kc < 16; kc++){
        const float* gp = gpart + ((size_t)b*16 + kc)*4*DD;
        sI += gp[d]; sF += gp[DD + d]; sG += gp[2*DD + d]; sO += gp[3*DD + d];
    }
    float ig = sigmoidf_(sI);
    float fg = sigmoidf_(sF);
    float gg = tanhf(sG);
    float og = sigmoidf_(sO);
    float nc = fg * c[idx] + ig * gg;
    float nh = og * tanhf(nc);
    newh_ws[idx] = nh;
    out_tail[idx] = nh;
    out_tail[BB*DD + idx] = nc;
}

// ---------------- launch ----------------
extern "C" void kernel_launch(void* const* d_in, const int* in_sizes, int n_in,
                              void* d_out, int out_size, void* d_ws, size_t ws_size,
                              hipStream_t stream) {
    const float* x    = (const float*)d_in[0];
    const float* h    = (const float*)d_in[1];
    const float* c    = (const float*)d_in[2];
    const float* Wq   = (const float*)d_in[3];
    const float* Wk   = (const float*)d_in[4];
    const float* Wv   = (const float*)d_in[5];
    const float* Wo   = (const float*)d_in[6];
    const float* Wmk  = (const float*)d_in[7];
    const float* Wmv  = (const float*)d_in[8];
    const float* Wih  = (const float*)d_in[9];
    const float* Whh  = (const float*)d_in[10];
    const float* b_ih = (const float*)d_in[11];
    const float* b_hh = (const float*)d_in[12];
    const float* W1   = (const float*)d_in[13];
    const float* bf1  = (const float*)d_in[14];
    const float* W2   = (const float*)d_in[15];
    const float* bf2  = (const float*)d_in[16];
    const float* g1   = (const float*)d_in[17];
    const float* be1  = (const float*)d_in[18];
    const float* g2   = (const float*)d_in[19];
    const float* be2  = (const float*)d_in[20];
    const float* g3   = (const float*)d_in[21];
    const float* be3  = (const float*)d_in[22];
    const float* Wmp  = (const float*)d_in[23];

    float* out = (float*)d_out;
    char* wsb  = (char*)d_ws;

    u16*   xn   = (u16*)(wsb + 0);        // 8MB
    u16*   hn   = (u16*)(wsb + 8*MB);     // 8MB
    float* p0   = (float*)(wsb + 0);      // 16MB overlay (xn,hn dead)
    u16*   Qbuf = (u16*)(wsb + 16*MB);
    u16*   Kbuf = (u16*)(wsb + 24*MB);
    u16*   VTb  = (u16*)(wsb + 33*MB);
    u16*   act  = (u16*)(wsb + 16*MB);    // 32MB overlay
    u16*   ao   = (u16*)(wsb + 48*MB);
    float* p1a  = (float*)(wsb + 48*MB);
    float* attb = (float*)(wsb + 56*MB);
    u16*   WqkvT= (u16*)(wsb + 72*MB);
    u16*   WoT  = (u16*)(wsb + 78*MB);
    u16*   W1T  = (u16*)(wsb + 80*MB);
    float* p1b  = (float*)(wsb + 80*MB);
    u16*   W2T  = (u16*)(wsb + 88*MB);
    float* sm   = (float*)(wsb + 96*MB);
    float* Kmb     = sm;
    float* Vmb     = Kmb + 2048;
    float* pooled  = Vmb + 2048;
    float* newh    = pooled + 2048;
    float* mproj   = newh + 2048;
    float* vpart   = mproj + 2048;
    float* v2part  = vpart + 16384;
    float* gpart   = v2part + 32768;
    float* ppart   = gpart + 131072;

    tr6_kernel<<<12288, 256, 0, stream>>>(Wq, Wk, Wv, Wo, W1, W2, WqkvT, WoT, W1T, W2T);

    ln_kernel<<<RR, 256, 0, stream>>>(x, nullptr, g1, be1, nullptr, nullptr, xn);
    vecmat2_part<<<dim3(4,8,BB), 256, 0, stream>>>(h, Wmk, Wmv, v2part);
    vecmat2_red<<<dim3(4,BB), 256, 0, stream>>>(v2part, Kmb, Vmb);
    // fused QKV projection: 256^2 8-phase, M=4096 N=3072 K=1024 -> grid 192
    mgemm256<<<192, 512, 0, stream>>>(xn, WqkvT, 12, 1024, 1, nullptr,
                                      0.125f*1.44269504088896f, Qbuf, Kbuf, VTb);
    fixup_kernel<<<8, 256, 0, stream>>>(Kmb, Vmb, Kbuf, VTb);
    attn_mfma<<<512, 256, 0, stream>>>(Qbuf, Kbuf, VTb, ao);
    // attended = x + ao @ Wo (128^2 path)
    mgemm<<<8*32, 256, 0, stream>>>(ao, WoT, 8, 1024, 1, MODE_F32R, nullptr, x, 1.f, attb, nullptr, nullptr);
    pool1_kernel<<<dim3(64,BB), 256, 0, stream>>>(attb, ppart);
    pool2_kernel<<<dim3(4,BB), 256, 0, stream>>>(ppart, pooled);
    gates_part<<<dim3(16,16,BB), 256, 0, stream>>>(pooled, h, Wih, Whh, gpart);
    lstm_kernel<<<8, 256, 0, stream>>>(gpart, b_ih, b_hh, c, newh, out + (size_t)RR*DD);
    vecmat_part<<<dim3(4,8,BB), 256, 0, stream>>>(newh, Wmp, vpart, DD, DD);
    vecmat_red<<<dim3(4,BB), 256, 0, stream>>>(vpart, mproj, DD);
    ln_kernel<<<RR, 256, 0, stream>>>(attb, mproj, g2, be2, attb, nullptr, hn);
    // FFN1: 256^2 8-phase, M=4096 N=4096 K=1024 -> grid 256
    mgemm256<<<256, 512, 0, stream>>>(hn, W1T, 16, 1024, 0, bf1, 1.f, act, nullptr, nullptr);
    // FFN2 split-K=2 (128^2 path)
    mgemm<<<8*32*2, 256, 0, stream>>>(act, W2T, 8, 2048, 2, MODE_PART, nullptr, nullptr, 1.f, p0, p1a, p1b);
    ln3f_kernel<<<RR, 256, 0, stream>>>(p0, p1a, p1b, bf2, attb, g3, be3, out);
}

// Round 11
// 291.008 us; speedup vs baseline: 15.7414x; 1.0444x over previous
//
#include <hip/hip_runtime.h>
#include <hip/hip_bf16.h>
#include <math.h>

#define BB 2
#define SS 2048
#define DD 1024
#define HH 16
#define RR (BB*SS)
#define KSTRIDE 2064   // padded key stride per (b,h)
#define MB (1024ull*1024ull)

typedef unsigned short u16;
typedef unsigned int u32;
typedef __attribute__((ext_vector_type(8))) short short8v;
typedef __attribute__((ext_vector_type(4))) float f32x4;
typedef __attribute__((ext_vector_type(16))) float f32x16;
typedef __attribute__((ext_vector_type(4))) u16 u16x4;

__device__ __forceinline__ u16 f2bf(float f){
    union { __hip_bfloat16 h; u16 u; } c; c.h = __float2bfloat16(f); return c.u;
}
// packed f32x2 -> bf16x2 in one instruction (dst.lo=bf16(a), dst.hi=bf16(b))
__device__ __forceinline__ u32 cvtpk(float a, float b){
    u32 r;
    asm("v_cvt_pk_bf16_f32 %0, %1, %2" : "=v"(r) : "v"(a), "v"(b));
    return r;
}
__device__ __forceinline__ float exp2_raw(float x){
    float r;
    asm("v_exp_f32 %0, %1" : "=v"(r) : "v"(x));
    return r;
}
__device__ __forceinline__ float bf2f(u16 u){
    union { u32 i; float f; } c; c.i = (u32)u << 16; return c.f;
}
// A&S 7.1.26 erf approximation, |err| <= 1.5e-7
__device__ __forceinline__ float erf_fast(float x){
    float ax = fabsf(x);
    float t = __builtin_amdgcn_rcpf(1.0f + 0.3275911f*ax);
    float y = t*(0.254829592f + t*(-0.284496736f + t*(1.421413741f + t*(-1.453152027f + t*1.061405429f))));
    float r = 1.0f - y*__expf(-ax*ax);
    return copysignf(r, x);
}

#define GLL16(gp, lp) __builtin_amdgcn_global_load_lds( \
    (const __attribute__((address_space(1))) void*)(gp), \
    (__attribute__((address_space(3))) void*)(lp), 16, 0, 0)

#define VMCNT8 asm volatile("s_waitcnt vmcnt(8)" ::: "memory")
#define VMCNT4 asm volatile("s_waitcnt vmcnt(4)" ::: "memory")
#define VMCNT0 asm volatile("s_waitcnt vmcnt(0)" ::: "memory")
#define SBAR   __builtin_amdgcn_s_barrier()
#define SCHEDB __builtin_amdgcn_sched_barrier(0)

// ---------------- LayerNorm ----------------
__global__ __launch_bounds__(256) void ln_kernel(const float* __restrict__ in,
    const float* __restrict__ mproj, const float* __restrict__ g, const float* __restrict__ be,
    float* __restrict__ mixed_out, float* __restrict__ outf, u16* __restrict__ outb)
{
    int row = blockIdx.x; int b = row / SS; int tid = threadIdx.x;
    float4 v = ((const float4*)(in + (size_t)row*DD))[tid];
    if (mproj){
        float4 mp = ((const float4*)(mproj + (size_t)b*DD))[tid];
        v.x+=mp.x; v.y+=mp.y; v.z+=mp.z; v.w+=mp.w;
        ((float4*)(mixed_out + (size_t)row*DD))[tid] = v;
    }
    float s = v.x+v.y+v.z+v.w, s2 = v.x*v.x+v.y*v.y+v.z*v.z+v.w*v.w;
    #pragma unroll
    for (int off=32; off>0; off>>=1){ s += __shfl_down(s,off); s2 += __shfl_down(s2,off); }
    __shared__ float red[2][4];
    if ((tid&63)==0){ red[0][tid>>6]=s; red[1][tid>>6]=s2; }
    __syncthreads();
    float st = red[0][0]+red[0][1]+red[0][2]+red[0][3];
    float s2t= red[1][0]+red[1][1]+red[1][2]+red[1][3];
    float mean = st*(1.f/DD); float var = s2t*(1.f/DD)-mean*mean;
    float rs = rsqrtf(var + 1e-5f);
    float4 gg=((const float4*)g)[tid], bb2=((const float4*)be)[tid];
    float o0=(v.x-mean)*rs*gg.x+bb2.x, o1=(v.y-mean)*rs*gg.y+bb2.y;
    float o2=(v.z-mean)*rs*gg.z+bb2.z, o3=(v.w-mean)*rs*gg.w+bb2.w;
    if (outf){ float4 o={o0,o1,o2,o3}; ((float4*)(outf+(size_t)row*DD))[tid]=o; }
    if (outb){ u16x4 o={f2bf(o0),f2bf(o1),f2bf(o2),f2bf(o3)}; ((u16x4*)(outb+(size_t)row*DD))[tid]=o; }
}

// ---------------- final: y = sum(4 bf16 partials)+bias+resid, out = LN(y) ----------------
__global__ __launch_bounds__(256) void ln3f_kernel(const u16* __restrict__ pb0,
    const u16* __restrict__ pb1, const u16* __restrict__ pb2, const u16* __restrict__ pb3,
    const float* __restrict__ bias, const float* __restrict__ resid,
    const float* __restrict__ g, const float* __restrict__ be, float* __restrict__ out)
{
    int row = blockIdx.x; int tid = threadIdx.x;
    size_t off = (size_t)row*DD;
    u16x4 q0 = ((const u16x4*)(pb0+off))[tid];
    u16x4 q1 = ((const u16x4*)(pb1+off))[tid];
    u16x4 q2 = ((const u16x4*)(pb2+off))[tid];
    u16x4 q3 = ((const u16x4*)(pb3+off))[tid];
    float4 bi = ((const float4*)bias)[tid];
    float4 rs4= ((const float4*)(resid+off))[tid];
    float4 v;
    v.x = bf2f(q0[0])+bf2f(q1[0])+bf2f(q2[0])+bf2f(q3[0]) + bi.x + rs4.x;
    v.y = bf2f(q0[1])+bf2f(q1[1])+bf2f(q2[1])+bf2f(q3[1]) + bi.y + rs4.y;
    v.z = bf2f(q0[2])+bf2f(q1[2])+bf2f(q2[2])+bf2f(q3[2]) + bi.z + rs4.z;
    v.w = bf2f(q0[3])+bf2f(q1[3])+bf2f(q2[3])+bf2f(q3[3]) + bi.w + rs4.w;
    float s = v.x+v.y+v.z+v.w, s2 = v.x*v.x+v.y*v.y+v.z*v.z+v.w*v.w;
    #pragma unroll
    for (int off2=32; off2>0; off2>>=1){ s += __shfl_down(s,off2); s2 += __shfl_down(s2,off2); }
    __shared__ float red[2][4];
    if ((tid&63)==0){ red[0][tid>>6]=s; red[1][tid>>6]=s2; }
    __syncthreads();
    float st = red[0][0]+red[0][1]+red[0][2]+red[0][3];
    float s2t= red[1][0]+red[1][1]+red[1][2]+red[1][3];
    float mean = st*(1.f/DD); float var = s2t*(1.f/DD)-mean*mean;
    float rs = rsqrtf(var + 1e-5f);
    float4 gg=((const float4*)g)[tid], bb2=((const float4*)be)[tid];
    float4 o;
    o.x=(v.x-mean)*rs*gg.x+bb2.x; o.y=(v.y-mean)*rs*gg.y+bb2.y;
    o.z=(v.z-mean)*rs*gg.z+bb2.z; o.w=(v.w-mean)*rs*gg.w+bb2.w;
    ((float4*)(out + off))[tid] = o;
}

// ---------------- merged weight transposes ----------------
__global__ __launch_bounds__(256) void tr6_kernel(const float* __restrict__ Wq, const float* __restrict__ Wk,
    const float* __restrict__ Wv, const float* __restrict__ Wo,
    const float* __restrict__ W1, const float* __restrict__ W2,
    u16* __restrict__ WqkvT, u16* __restrict__ WoT, u16* __restrict__ W1T, u16* __restrict__ W2T)
{
    __shared__ float t[32][33];
    int bid = blockIdx.x;
    const float* in; u16* out; int K, N, n0, k0;
    if (bid < 3072){
        int m = bid >> 10, r = bid & 1023;
        in = (m==0) ? Wq : (m==1) ? Wk : Wv;
        out = WqkvT + (size_t)m*1024*1024;
        K = 1024; N = 1024; n0 = (r & 31)*32; k0 = (r >> 5)*32;
    } else if (bid < 4096){
        int r = bid - 3072;
        in = Wo; out = WoT; K = 1024; N = 1024; n0 = (r & 31)*32; k0 = (r >> 5)*32;
    } else if (bid < 8192){
        int r = bid - 4096;
        in = W1; out = W1T; K = 1024; N = 4096; n0 = (r & 127)*32; k0 = (r >> 7)*32;
    } else {
        int r = bid - 8192;
        in = W2; out = W2T; K = 4096; N = 1024; n0 = (r & 31)*32; k0 = (r >> 5)*32;
    }
    int tx = threadIdx.x & 31, ty = threadIdx.x >> 5;
    #pragma unroll
    for (int i=0;i<4;i++){ int k = ty + i*8; t[k][tx] = in[(size_t)(k0+k)*N + n0 + tx]; }
    __syncthreads();
    #pragma unroll
    for (int i=0;i<4;i++){ int n = ty + i*8; out[(size_t)(n0+n)*K + k0 + tx] = f2bf(t[tx][n]); }
}

// =============== 256x256 8-phase GEMM (T2+T3+T4+T5), 512 threads = 8 waves (2M x 4N) ===============
// C = A[M,Kc*kchunks] @ BT[N,Kc*kchunks]^T per K-chunk. modes: 0=GELU bf16, 1=QKV, 2=bf16 partial.
__global__ __launch_bounds__(512) void mgemm256(const u16* __restrict__ A, const u16* __restrict__ BT,
    int nbx, int Kc, int kchunks, int mode, const float* __restrict__ bias, float scale,
    void* __restrict__ Cout, void* __restrict__ C2a, void* __restrict__ C2b, void* __restrict__ C2c)
{
    __shared__ __align__(16) u16 lds[2][2][2][256*32];
    int tid = threadIdx.x, l = tid&63, w = tid>>6;
    int wr = w>>2, wc = w&3;
    int nwg = gridDim.x, q8 = nwg>>3;
    int bid = blockIdx.x;
    int swz = (bid & 7)*q8 + (bid >> 3);
    int tiles = nwg / kchunks;
    int chunk = swz / tiles;
    int t2 = swz % tiles;
    int by = t2 / nbx, bx = t2 % nbx;
    int bm = by*256, bn = bx*256;
    int lda = Kc*kchunks;
    int koff = chunk*Kc;
    const int NT = Kc >> 6;

    f32x4 acc[8][4];
    #pragma unroll
    for (int i=0;i<8;i++)
        #pragma unroll
        for (int j=0;j<4;j++)
            #pragma unroll
            for (int r=0;r<4;r++) acc[i][j][r]=0.f;

    auto stage_plane = [&](int buf, int op, int ks, int tt){
        const u16* base = op ? BT : A;
        int tile0 = op ? bn : bm;
        #pragma unroll
        for (int i=0;i<2;i++){
            int rbase = (w*2+i)*16;
            int row = rbase + (l>>2);
            int slotlog = (l&3) ^ ((row>>1)&3);
            const u16* g = base + (size_t)(tile0 + row)*lda + koff + tt*64 + ks*32 + slotlog*8;
            GLL16(g, (u16*)&lds[buf][op][ks][0] + rbase*32);
        }
    };
    auto ds_a = [&](int buf, int ks, int ai) -> short8v {
        int row = wr*128 + ai*16 + (l&15);
        int slot = (l>>4) ^ ((row>>1)&3);
        return *(const short8v*)((const char*)&lds[buf][0][ks][0] + row*64 + slot*16);
    };
    auto ds_b = [&](int buf, int ks, int bi) -> short8v {
        int row = wc*64 + bi*16 + (l&15);
        int slot = (l>>4) ^ ((row>>1)&3);
        return *(const short8v*)((const char*)&lds[buf][1][ks][0] + row*64 + slot*16);
    };

    // prologue: t0.ks0, t0.ks1, t1.ks0  (12 issues/wave)
    stage_plane(0,0,0,0); stage_plane(0,1,0,0);
    stage_plane(0,0,1,0); stage_plane(0,1,1,0);
    stage_plane(1,0,0,1); stage_plane(1,1,0,1);
    VMCNT8;
    SBAR; SCHEDB;

    for (int t=0; t<NT; t++){
        int buf = t&1, obuf = buf^1;
        bool s1 = (t+1 < NT), s2 = (t+2 < NT);
        short8v b0,b1,b2,b3, a0,a1,a2,a3;
        // ---- Ph0
        b0=ds_b(buf,0,0); b1=ds_b(buf,0,1); b2=ds_b(buf,0,2); b3=ds_b(buf,0,3);
        a0=ds_a(buf,0,0); a1=ds_a(buf,0,1); a2=ds_a(buf,0,2); a3=ds_a(buf,0,3);
        if (s1) stage_plane(obuf,0,1,t+1);
        __builtin_amdgcn_s_setprio(1);
        acc[0][0]=__builtin_amdgcn_mfma_f32_16x16x32_bf16(b0,a0,acc[0][0],0,0,0);
        acc[0][1]=__builtin_amdgcn_mfma_f32_16x16x32_bf16(b1,a0,acc[0][1],0,0,0);
        acc[0][2]=__builtin_amdgcn_mfma_f32_16x16x32_bf16(b2,a0,acc[0][2],0,0,0);
        acc[0][3]=__builtin_amdgcn_mfma_f32_16x16x32_bf16(b3,a0,acc[0][3],0,0,0);
        acc[1][0]=__builtin_amdgcn_mfma_f32_16x16x32_bf16(b0,a1,acc[1][0],0,0,0);
        acc[1][1]=__builtin_amdgcn_mfma_f32_16x16x32_bf16(b1,a1,acc[1][1],0,0,0);
        acc[1][2]=__builtin_amdgcn_mfma_f32_16x16x32_bf16(b2,a1,acc[1][2],0,0,0);
        acc[1][3]=__builtin_amdgcn_mfma_f32_16x16x32_bf16(b3,a1,acc[1][3],0,0,0);
        acc[2][0]=__builtin_amdgcn_mfma_f32_16x16x32_bf16(b0,a2,acc[2][0],0,0,0);
        acc[2][1]=__builtin_amdgcn_mfma_f32_16x16x32_bf16(b1,a2,acc[2][1],0,0,0);
        acc[2][2]=__builtin_amdgcn_mfma_f32_16x16x32_bf16(b2,a2,acc[2][2],0,0,0);
        acc[2][3]=__builtin_amdgcn_mfma_f32_16x16x32_bf16(b3,a2,acc[2][3],0,0,0);
        acc[3][0]=__builtin_amdgcn_mfma_f32_16x16x32_bf16(b0,a3,acc[3][0],0,0,0);
        acc[3][1]=__builtin_amdgcn_mfma_f32_16x16x32_bf16(b1,a3,acc[3][1],0,0,0);
        acc[3][2]=__builtin_amdgcn_mfma_f32_16x16x32_bf16(b2,a3,acc[3][2],0,0,0);
        acc[3][3]=__builtin_amdgcn_mfma_f32_16x16x32_bf16(b3,a3,acc[3][3],0,0,0);
        __builtin_amdgcn_s_setprio(0);
        SBAR; SCHEDB;
        // ---- Ph1
        a0=ds_a(buf,0,4); a1=ds_a(buf,0,5); a2=ds_a(buf,0,6); a3=ds_a(buf,0,7);
        if (s1) stage_plane(obuf,1,1,t+1);
        __builtin_amdgcn_s_setprio(1);
        acc[4][0]=__builtin_amdgcn_mfma_f32_16x16x32_bf16(b0,a0,acc[4][0],0,0,0);
        acc[4][1]=__builtin_amdgcn_mfma_f32_16x16x32_bf16(b1,a0,acc[4][1],0,0,0);
        acc[4][2]=__builtin_amdgcn_mfma_f32_16x16x32_bf16(b2,a0,acc[4][2],0,0,0);
        acc[4][3]=__builtin_amdgcn_mfma_f32_16x16x32_bf16(b3,a0,acc[4][3],0,0,0);
        acc[5][0]=__builtin_amdgcn_mfma_f32_16x16x32_bf16(b0,a1,acc[5][0],0,0,0);
        acc[5][1]=__builtin_amdgcn_mfma_f32_16x16x32_bf16(b1,a1,acc[5][1],0,0,0);
        acc[5][2]=__builtin_amdgcn_mfma_f32_16x16x32_bf16(b2,a1,acc[5][2],0,0,0);
        acc[5][3]=__builtin_amdgcn_mfma_f32_16x16x32_bf16(b3,a1,acc[5][3],0,0,0);
        acc[6][0]=__builtin_amdgcn_mfma_f32_16x16x32_bf16(b0,a2,acc[6][0],0,0,0);
        acc[6][1]=__builtin_amdgcn_mfma_f32_16x16x32_bf16(b1,a2,acc[6][1],0,0,0);
        acc[6][2]=__builtin_amdgcn_mfma_f32_16x16x32_bf16(b2,a2,acc[6][2],0,0,0);
        acc[6][3]=__builtin_amdgcn_mfma_f32_16x16x32_bf16(b3,a2,acc[6][3],0,0,0);
        acc[7][0]=__builtin_amdgcn_mfma_f32_16x16x32_bf16(b0,a3,acc[7][0],0,0,0);
        acc[7][1]=__builtin_amdgcn_mfma_f32_16x16x32_bf16(b1,a3,acc[7][1],0,0,0);
        acc[7][2]=__builtin_amdgcn_mfma_f32_16x16x32_bf16(b2,a3,acc[7][2],0,0,0);
        acc[7][3]=__builtin_amdgcn_mfma_f32_16x16x32_bf16(b3,a3,acc[7][3],0,0,0);
        __builtin_amdgcn_s_setprio(0);
        if (s1) { VMCNT8; } else { VMCNT0; }
        SBAR; SCHEDB;
        // ---- Ph2
        b0=ds_b(buf,1,0); b1=ds_b(buf,1,1); b2=ds_b(buf,1,2); b3=ds_b(buf,1,3);
        a0=ds_a(buf,1,0); a1=ds_a(buf,1,1); a2=ds_a(buf,1,2); a3=ds_a(buf,1,3);
        if (s2) stage_plane(buf,0,0,t+2);
        __builtin_amdgcn_s_setprio(1);
        acc[0][0]=__builtin_amdgcn_mfma_f32_16x16x32_bf16(b0,a0,acc[0][0],0,0,0);
        acc[0][1]=__builtin_amdgcn_mfma_f32_16x16x32_bf16(b1,a0,acc[0][1],0,0,0);
        acc[0][2]=__builtin_amdgcn_mfma_f32_16x16x32_bf16(b2,a0,acc[0][2],0,0,0);
        acc[0][3]=__builtin_amdgcn_mfma_f32_16x16x32_bf16(b3,a0,acc[0][3],0,0,0);
        acc[1][0]=__builtin_amdgcn_mfma_f32_16x16x32_bf16(b0,a1,acc[1][0],0,0,0);
        acc[1][1]=__builtin_amdgcn_mfma_f32_16x16x32_bf16(b1,a1,acc[1][1],0,0,0);
        acc[1][2]=__builtin_amdgcn_mfma_f32_16x16x32_bf16(b2,a1,acc[1][2],0,0,0);
        acc[1][3]=__builtin_amdgcn_mfma_f32_16x16x32_bf16(b3,a1,acc[1][3],0,0,0);
        acc[2][0]=__builtin_amdgcn_mfma_f32_16x16x32_bf16(b0,a2,acc[2][0],0,0,0);
        acc[2][1]=__builtin_amdgcn_mfma_f32_16x16x32_bf16(b1,a2,acc[2][1],0,0,0);
        acc[2][2]=__builtin_amdgcn_mfma_f32_16x16x32_bf16(b2,a2,acc[2][2],0,0,0);
        acc[2][3]=__builtin_amdgcn_mfma_f32_16x16x32_bf16(b3,a2,acc[2][3],0,0,0);
        acc[3][0]=__builtin_amdgcn_mfma_f32_16x16x32_bf16(b0,a3,acc[3][0],0,0,0);
        acc[3][1]=__builtin_amdgcn_mfma_f32_16x16x32_bf16(b1,a3,acc[3][1],0,0,0);
        acc[3][2]=__builtin_amdgcn_mfma_f32_16x16x32_bf16(b2,a3,acc[3][2],0,0,0);
        acc[3][3]=__builtin_amdgcn_mfma_f32_16x16x32_bf16(b3,a3,acc[3][3],0,0,0);
        __builtin_amdgcn_s_setprio(0);
        SBAR; SCHEDB;
        // ---- Ph3
        a0=ds_a(buf,1,4); a1=ds_a(buf,1,5); a2=ds_a(buf,1,6); a3=ds_a(buf,1,7);
        if (s2) stage_plane(buf,1,0,t+2);
        __builtin_amdgcn_s_setprio(1);
        acc[4][0]=__builtin_amdgcn_mfma_f32_16x16x32_bf16(b0,a0,acc[4][0],0,0,0);
        acc[4][1]=__builtin_amdgcn_mfma_f32_16x16x32_bf16(b1,a0,acc[4][1],0,0,0);
        acc[4][2]=__builtin_amdgcn_mfma_f32_16x16x32_bf16(b2,a0,acc[4][2],0,0,0);
        acc[4][3]=__builtin_amdgcn_mfma_f32_16x16x32_bf16(b3,a0,acc[4][3],0,0,0);
        acc[5][0]=__builtin_amdgcn_mfma_f32_16x16x32_bf16(b0,a1,acc[5][0],0,0,0);
        acc[5][1]=__builtin_amdgcn_mfma_f32_16x16x32_bf16(b1,a1,acc[5][1],0,0,0);
        acc[5][2]=__builtin_amdgcn_mfma_f32_16x16x32_bf16(b2,a1,acc[5][2],0,0,0);
        acc[5][3]=__builtin_amdgcn_mfma_f32_16x16x32_bf16(b3,a1,acc[5][3],0,0,0);
        acc[6][0]=__builtin_amdgcn_mfma_f32_16x16x32_bf16(b0,a2,acc[6][0],0,0,0);
        acc[6][1]=__builtin_amdgcn_mfma_f32_16x16x32_bf16(b1,a2,acc[6][1],0,0,0);
        acc[6][2]=__builtin_amdgcn_mfma_f32_16x16x32_bf16(b2,a2,acc[6][2],0,0,0);
        acc[6][3]=__builtin_amdgcn_mfma_f32_16x16x32_bf16(b3,a2,acc[6][3],0,0,0);
        acc[7][0]=__builtin_amdgcn_mfma_f32_16x16x32_bf16(b0,a3,acc[7][0],0,0,0);
        acc[7][1]=__builtin_amdgcn_mfma_f32_16x16x32_bf16(b1,a3,acc[7][1],0,0,0);
        acc[7][2]=__builtin_amdgcn_mfma_f32_16x16x32_bf16(b2,a3,acc[7][2],0,0,0);
        acc[7][3]=__builtin_amdgcn_mfma_f32_16x16x32_bf16(b3,a3,acc[7][3],0,0,0);
        __builtin_amdgcn_s_setprio(0);
        if (s2) { VMCNT8; } else if (s1) { VMCNT4; } else { VMCNT0; }
        SBAR; SCHEDB;
    }

    // epilogue
    int N = nbx*256;
    #pragma unroll
    for (int ai=0; ai<8; ai++){
        int m = bm + wr*128 + ai*16 + (l&15);
        #pragma unroll
        for (int bi=0; bi<4; bi++){
            int nb = bn + wc*64 + bi*16 + ((l>>4)<<2);
            f32x4 v = acc[ai][bi];
            if (mode == 0){   // GELU bf16
                float4 bv = *(const float4*)(bias + nb);
                float t0=v[0]+bv.x, t1=v[1]+bv.y, t2=v[2]+bv.z, t3=v[3]+bv.w;
                u16x4 o;
                o[0]=f2bf(0.5f*t0*(1.0f+erf_fast(t0*0.70710678118654752f)));
                o[1]=f2bf(0.5f*t1*(1.0f+erf_fast(t1*0.70710678118654752f)));
                o[2]=f2bf(0.5f*t2*(1.0f+erf_fast(t2*0.70710678118654752f)));
                o[3]=f2bf(0.5f*t3*(1.0f+erf_fast(t3*0.70710678118654752f)));
                *(u16x4*)((u16*)Cout + (size_t)m*N + nb) = o;
            } else if (mode == 1){  // QKV
                if (nb < 1024){
                    u16x4 o;
                    #pragma unroll
                    for (int r=0;r<4;r++) o[r] = f2bf(v[r]*scale);
                    *(u16x4*)((u16*)Cout + (size_t)m*1024 + nb) = o;
                } else if (nb < 2048){
                    int cc = nb-1024; int hh = cc>>6, dh = cc&63;
                    int b2 = m>>11, key = m&2047;
                    u16x4 o;
                    #pragma unroll
                    for (int r=0;r<4;r++) o[r] = f2bf(v[r]);
                    *(u16x4*)((u16*)C2a + ((size_t)(b2*HH+hh)*KSTRIDE + key)*64 + dh) = o;
                } else {
                    int cc = nb-2048; int hh = cc>>6, dh = cc&63;
                    int b2 = m>>11, key = m&2047;
                    #pragma unroll
                    for (int r=0;r<4;r++)
                        ((u16*)C2b)[((size_t)(b2*HH+hh)*64 + dh + r)*KSTRIDE + key] = f2bf(v[r]);
                }
            } else {          // mode 2: bf16 partial per chunk
                u16* pp = (chunk==0) ? (u16*)Cout : (chunk==1) ? (u16*)C2a :
                          (chunk==2) ? (u16*)C2b : (u16*)C2c;
                u16x4 o;
                #pragma unroll
                for (int r=0;r<4;r++) o[r] = f2bf(v[r]);
                *(u16x4*)(pp + (size_t)m*N + nb) = o;
            }
        }
    }
}

// ---------------- 128x128 MFMA GEMM (kept for Wo) ----------------
#define MODE_F32R 3

__global__ __launch_bounds__(256) void mgemm(const u16* __restrict__ A, const u16* __restrict__ BT,
    int nbx, int Kc, int kchunks, int mode,
    const float* __restrict__ bias, const float* __restrict__ resid, float scale,
    void* __restrict__ Cout, void* __restrict__ C2a, void* __restrict__ C2b)
{
    int tid=threadIdx.x, l=tid&63, w=tid>>6;
    int nwg = gridDim.x;
    int qq = nwg >> 3;
    int bid = blockIdx.x;
    int swz = (bid & 7)*qq + (bid >> 3);
    int tiles = nwg / kchunks;
    int chunk = swz / tiles;
    int t2 = swz % tiles;
    int sby = t2 / (nbx*8);
    int rem = t2 - sby*(nbx*8);
    int sbx = rem >> 6;
    int ci  = rem & 63;
    int bx = sbx*8 + (ci&7);
    int by = sby*8 + (ci>>3);

    int bm = by*128, bn = bx*128;
    int N = nbx*128;
    int lda = Kc*kchunks;
    int koff = chunk*Kc;
    int wr = w>>1, wc = w&1;
    f32x4 acc[4][4];
    #pragma unroll
    for(int i=0;i<4;i++)
        #pragma unroll
        for(int j=0;j<4;j++)
            #pragma unroll
            for(int r=0;r<4;r++) acc[i][j][r]=0.f;

    __shared__ __align__(16) u16 Al[2][4096];
    __shared__ __align__(16) u16 Bl[2][4096];
    int srow = (w<<4) + (l>>2);
    int sph  = l&3;
    const int NT = Kc >> 5;

    auto stage = [&](int buf, int kt){
        #pragma unroll
        for (int r=0;r<2;r++){
            int rowA = srow + r*64;
            int sl = sph ^ ((rowA>>1)&3);
            const u16* gA = A + (size_t)(bm+rowA)*lda + koff + kt*32 + sl*8;
            GLL16(gA, (char*)&Al[buf][0] + r*4096 + w*1024);
            const u16* gB = BT + (size_t)(bn+rowA)*lda + koff + kt*32 + sl*8;
            GLL16(gB, (char*)&Bl[buf][0] + r*4096 + w*1024);
        }
    };

    int cur=0;
    stage(0,0);
    __syncthreads();
    for (int kt=0; kt<NT; kt++){
        if (kt+1<NT) stage(cur^1, kt+1);
        short8v af[4], bf[4];
        #pragma unroll
        for (int mi=0;mi<4;mi++){
            int row = wr*64 + mi*16 + (l&15);
            int sl = (l>>4) ^ ((row>>1)&3);
            af[mi] = *(const short8v*)((const char*)&Al[cur][0] + row*64 + sl*16);
        }
        #pragma unroll
        for (int ni=0;ni<4;ni++){
            int row = wc*64 + ni*16 + (l&15);
            int sl = (l>>4) ^ ((row>>1)&3);
            bf[ni] = *(const short8v*)((const char*)&Bl[cur][0] + row*64 + sl*16);
        }
        #pragma unroll
        for (int mi=0;mi<4;mi++)
            #pragma unroll
            for (int ni=0;ni<4;ni++)
                acc[mi][ni] = __builtin_amdgcn_mfma_f32_16x16x32_bf16(bf[ni], af[mi], acc[mi][ni], 0,0,0);
        __syncthreads();
        cur ^= 1;
    }

    #pragma unroll
    for (int mi=0;mi<4;mi++){
        int m = bm + wr*64 + mi*16 + (l&15);
        #pragma unroll
        for (int ni=0;ni<4;ni++){
            int nb = bn + wc*64 + ni*16 + ((l>>4)<<2);
            f32x4 v = acc[mi][ni];
            float4 rs = *(const float4*)(resid + (size_t)m*N + nb);
            float4 o = {v[0]+rs.x, v[1]+rs.y, v[2]+rs.z, v[3]+rs.w};
            *(float4*)((float*)Cout + (size_t)m*N + nb) = o;
        }
    }
}

// ---------------- MFMA flash attention: pipelined, triple-buffer, exp2 softmax ----------------
__global__ __launch_bounds__(256) void attn_mfma(const u16* __restrict__ Qb, const u16* __restrict__ Kb,
    const u16* __restrict__ VTb, u16* __restrict__ ao)
{
    __shared__ __align__(16) u16 Kl[3][4096];
    __shared__ __align__(16) u16 Vl[3][4096];
    int tid=threadIdx.x, l=tid&63, w=tid>>6;
    int l31=l&31, hi=l>>5;
    int bid = blockIdx.x;
    int xcd = bid & 7, idx = bid >> 3;
    int bh = xcd*4 + (idx>>4);
    int qt = idx & 15;
    int b=bh>>4, h=bh&15;
    int qrow = qt*128 + w*32 + l31;

    const u16* qptr = Qb + (size_t)(b*SS + qrow)*DD + h*64;
    short8v qf[4];
    #pragma unroll
    for (int t=0;t<4;t++) qf[t] = *(const short8v*)(qptr + t*16 + hi*8);

    f32x16 so0, so1;
    #pragma unroll
    for (int i=0;i<16;i++){ so0[i]=0.f; so1[i]=0.f; }
    float l_run=0.f;

    int skey = (w<<3) + (l>>3);
    int ssl  = l&7;
    auto stage = [&](int buf, int kt){
        #pragma unroll
        for (int r=0;r<2;r++){
            int key = skey + r*32;
            int slot = ssl ^ (key&7);
            const u16* gK = Kb + ((size_t)bh*KSTRIDE + kt*64 + key)*64 + slot*8;
            GLL16(gK, (char*)&Kl[buf][0] + r*4096 + w*1024);
            const u16* gV = VTb + ((size_t)bh*64 + key)*KSTRIDE + kt*64 + slot*8;
            GLL16(gV, (char*)&Vl[buf][0] + r*4096 + w*1024);
        }
    };

    auto QK = [&](int bf, f32x16& s0, f32x16& s1){
        #pragma unroll
        for (int i=0;i<16;i++){ s0[i]=0.f; s1[i]=0.f; }
        __builtin_amdgcn_s_setprio(1);
        #pragma unroll
        for (int t=0;t<4;t++){
            int sl = (2*t+hi) ^ (l31&7);
            short8v kf0 = *(const short8v*)((const char*)&Kl[bf][0] + l31*128 + sl*16);
            s0 = __builtin_amdgcn_mfma_f32_32x32x16_bf16(kf0, qf[t], s0, 0,0,0);
            short8v kf1 = *(const short8v*)((const char*)&Kl[bf][0] + (32+l31)*128 + sl*16);
            s1 = __builtin_amdgcn_mfma_f32_32x32x16_bf16(kf1, qf[t], s1, 0,0,0);
        }
        __builtin_amdgcn_s_setprio(0);
    };

    auto SMPV = [&](int bf, f32x16& s0, f32x16& s1){
        float psum = 0.f;
        #pragma unroll
        for (int r=0;r<16;r++){
            float p=exp2_raw(s0[r]); s0[r]=p; psum+=p;
            float q=exp2_raw(s1[r]); s1[r]=q; psum+=q;
        }
        psum += __shfl_xor(psum, 32);
        l_run += psum;
        short8v pf[4];
        #pragma unroll
        for (int t=0;t<4;t++){
            u32 a0,a1,b0,b1;
            if (t==0){ a0=cvtpk(s0[0],s0[1]);   a1=cvtpk(s0[2],s0[3]);   b0=cvtpk(s0[4],s0[5]);   b1=cvtpk(s0[6],s0[7]); }
            else if (t==1){ a0=cvtpk(s0[8],s0[9]);   a1=cvtpk(s0[10],s0[11]); b0=cvtpk(s0[12],s0[13]); b1=cvtpk(s0[14],s0[15]); }
            else if (t==2){ a0=cvtpk(s1[0],s1[1]);   a1=cvtpk(s1[2],s1[3]);   b0=cvtpk(s1[4],s1[5]);   b1=cvtpk(s1[6],s1[7]); }
            else          { a0=cvtpk(s1[8],s1[9]);   a1=cvtpk(s1[10],s1[11]); b0=cvtpk(s1[12],s1[13]); b1=cvtpk(s1[14],s1[15]); }
            union { u32 u[4]; short8v v; } cvt;
#if __has_builtin(__builtin_amdgcn_permlane32_swap)
            // swap(a,b): new_a={lo:a, hi:b[partner]}, new_b={lo:a[partner], hi:b}
            auto r0 = __builtin_amdgcn_permlane32_swap(a0, b0, false, false);
            auto r1 = __builtin_amdgcn_permlane32_swap(a1, b1, false, false);
            cvt.u[0] = (u32)r0[0];
            cvt.u[1] = (u32)r1[0];
            cvt.u[2] = (u32)r0[1];
            cvt.u[3] = (u32)r1[1];
#else
            u32 sx0 = hi ? a0 : b0, sx1 = hi ? a1 : b1;
            u32 r0 = (u32)__shfl_xor((int)sx0, 32);
            u32 r1 = (u32)__shfl_xor((int)sx1, 32);
            cvt.u[0] = hi ? r0 : a0;
            cvt.u[1] = hi ? r1 : a1;
            cvt.u[2] = hi ? b0 : r0;
            cvt.u[3] = hi ? b1 : r1;
#endif
            pf[t] = cvt.v;
        }
        __builtin_amdgcn_s_setprio(1);
        #pragma unroll
        for (int t=0;t<4;t++){
            int sl = (2*t+hi) ^ (l31&7);
            short8v vf0 = *(const short8v*)((const char*)&Vl[bf][0] + l31*128 + sl*16);
            so0 = __builtin_amdgcn_mfma_f32_32x32x16_bf16(vf0, pf[t], so0, 0,0,0);
            short8v vf1 = *(const short8v*)((const char*)&Vl[bf][0] + (32+l31)*128 + sl*16);
            so1 = __builtin_amdgcn_mfma_f32_32x32x16_bf16(vf1, pf[t], so1, 0,0,0);
        }
        __builtin_amdgcn_s_setprio(0);
    };

    const int NTILE = 33;
    int bufA = 0, bufB = 1, bufC = 2;
    stage(0, 0);
    stage(1, 1);
    __syncthreads();

    f32x16 sA0, sA1, sB0, sB1;
    QK(bufA, sA0, sA1);

    auto ITER = [&](f32x16& c0, f32x16& c1, f32x16& n0, f32x16& n1, int t){
        if (t+2 < NTILE) stage(bufC, t+2);
        QK(bufB, n0, n1);
        SMPV(bufA, c0, c1);
        __syncthreads();
        int tmp = bufA; bufA = bufB; bufB = bufC; bufC = tmp;
    };
    #pragma unroll 1
    for (int tt=0; tt<16; tt++){
        ITER(sA0, sA1, sB0, sB1, 2*tt);
        ITER(sB0, sB1, sA0, sA1, 2*tt+1);
    }
    #pragma unroll
    for (int r=0;r<16;r++){
        int k0 = 2048 + (r&3) + 8*(r>>2) + 4*hi;
        if (k0 >= 2049) sA0[r] = -1e30f;
        sA1[r] = -1e30f;
    }
    SMPV(bufA, sA0, sA1);

    float inv = 1.f / l_run;
    u16* aop = ao + (size_t)(b*SS + qrow)*DD + h*64;
    #pragma unroll
    for (int rg=0; rg<4; rg++){
        int dh0 = rg*8 + 4*hi;
        u16x4 o0, o1;
        #pragma unroll
        for (int j=0;j<4;j++){ o0[j]=f2bf(so0[rg*4+j]*inv); o1[j]=f2bf(so1[rg*4+j]*inv); }
        *(u16x4*)(aop + dh0) = o0;
        *(u16x4*)(aop + 32 + dh0) = o1;
    }
}

// ---------------- split-K matvec ----------------
__global__ __launch_bounds__(256) void vecmat_part(const float* __restrict__ vec,
    const float* __restrict__ W, float* __restrict__ part, int K, int N)
{
    int b = blockIdx.z, kc = blockIdx.y;
    int j = blockIdx.x*256 + threadIdx.x;
    int k0 = kc * (K >> 3);
    float acc = 0.0f;
    #pragma unroll 4
    for (int k = k0; k < k0 + (K >> 3); k++)
        acc += vec[(size_t)b*K + k] * W[(size_t)k*N + j];
    part[((size_t)b*8 + kc)*N + j] = acc;
}

__global__ __launch_bounds__(256) void vecmat_red(const float* __restrict__ part,
    float* __restrict__ out, int N)
{
    int b = blockIdx.y;
    int j = blockIdx.x*256 + threadIdx.x;
    float acc = 0.0f;
    #pragma unroll
    for (int kc = 0; kc < 8; kc++) acc += part[((size_t)b*8 + kc)*N + j];
    out[(size_t)b*N + j] = acc;
}

__global__ __launch_bounds__(256) void vecmat2_part(const float* __restrict__ vec,
    const float* __restrict__ Wa, const float* __restrict__ Wb, float* __restrict__ part)
{
    int b = blockIdx.z, kc = blockIdx.y;
    int j = blockIdx.x*256 + threadIdx.x;
    int k0 = kc * 128;
    float accA = 0.0f, accB = 0.0f;
    #pragma unroll 4
    for (int k = k0; k < k0 + 128; k++){
        float v = vec[(size_t)b*DD + k];
        accA += v * Wa[(size_t)k*DD + j];
        accB += v * Wb[(size_t)k*DD + j];
    }
    part[((size_t)b*8 + kc)*2048 + j] = accA;
    part[((size_t)b*8 + kc)*2048 + 1024 + j] = accB;
}

__global__ __launch_bounds__(256) void vecmat2_red(const float* __restrict__ part,
    float* __restrict__ outA, float* __restrict__ outB)
{
    int b = blockIdx.y;
    int j = blockIdx.x*256 + threadIdx.x;
    float accA = 0.0f, accB = 0.0f;
    #pragma unroll
    for (int kc = 0; kc < 8; kc++){
        accA += part[((size_t)b*8 + kc)*2048 + j];
        accB += part[((size_t)b*8 + kc)*2048 + 1024 + j];
    }
    outA[(size_t)b*DD + j] = accA;
    outB[(size_t)b*DD + j] = accB;
}

__global__ __launch_bounds__(256) void fixup_kernel(const float* __restrict__ Kmb,
    const float* __restrict__ Vmb, u16* __restrict__ Kb, u16* __restrict__ VTb)
{
    int idx = blockIdx.x*256 + threadIdx.x;
    int b = idx>>10, j = idx&1023; int h=j>>6, dh=j&63; int bh=b*HH+h;
    Kb[((size_t)bh*KSTRIDE + 2048)*64 + dh] = f2bf(Kmb[idx]);
    VTb[((size_t)bh*64 + dh)*KSTRIDE + 2048] = f2bf(Vmb[idx]);
}

__global__ __launch_bounds__(256) void pool1_kernel(const float* __restrict__ att, float* __restrict__ ppart)
{
    int b = blockIdx.y, sc = blockIdx.x;
    int tid = threadIdx.x;
    float4 acc = {0,0,0,0};
    for (int s = 0; s < 32; s++) {
        int row = b*SS + sc*32 + s;
        float4 v = ((const float4*)(att + (size_t)row*DD))[tid];
        acc.x += v.x; acc.y += v.y; acc.z += v.z; acc.w += v.w;
    }
    ((float4*)(ppart + ((size_t)b*64 + sc)*DD))[tid] = acc;
}

__global__ __launch_bounds__(256) void pool2_kernel(const float* __restrict__ ppart, float* __restrict__ pooled)
{
    int b = blockIdx.y;
    int j = blockIdx.x*256 + threadIdx.x;
    float acc = 0.0f;
    for (int sc = 0; sc < 64; sc++) acc += ppart[((size_t)b*64 + sc)*DD + j];
    pooled[(size_t)b*DD + j] = acc * (1.0f/SS);
}

__global__ __launch_bounds__(256) void gates_part(const float* __restrict__ pooled,
    const float* __restrict__ h, const float* __restrict__ Wih, const float* __restrict__ Whh,
    float* __restrict__ part)
{
    int b = blockIdx.z, kc = blockIdx.y;
    int j = blockIdx.x*256 + threadIdx.x;
    int k0 = kc * 64;
    float acc = 0.0f;
    #pragma unroll 4
    for (int k = k0; k < k0 + 64; k++)
        acc += pooled[(size_t)b*DD + k] * Wih[(size_t)k*4*DD + j]
             + h[(size_t)b*DD + k]      * Whh[(size_t)k*4*DD + j];
    part[((size_t)b*16 + kc)*4*DD + j] = acc;
}

__device__ __forceinline__ float sigmoidf_(float x) { return 1.0f / (1.0f + __expf(-x)); }

__global__ __launch_bounds__(256) void lstm_kernel(const float* __restrict__ gpart,
    const float* __restrict__ b_ih, const float* __restrict__ b_hh,
    const float* __restrict__ c, float* __restrict__ newh_ws, float* __restrict__ out_tail)
{
    int idx = blockIdx.x*256 + threadIdx.x;
    int b = idx >> 10, d = idx & 1023;
    float sI = b_ih[d]          + b_hh[d];
    float sF = b_ih[DD + d]     + b_hh[DD + d];
    float sG = b_ih[2*DD + d]   + b_hh[2*DD + d];
    float sO = b_ih[3*DD + d]   + b_hh[3*DD + d];
    #pragma unroll
    for (int kc = 0; kc < 16; kc++){
        const float* gp = gpart + ((size_t)b*16 + kc)*4*DD;
        sI += gp[d]; sF += gp[DD + d]; sG += gp[2*DD + d]; sO += gp[3*DD + d];
    }
    float ig = sigmoidf_(sI);
    float fg = sigmoidf_(sF);
    float gg = tanhf(sG);
    float og = sigmoidf_(sO);
    float nc = fg * c[idx] + ig * gg;
    float nh = og * tanhf(nc);
    newh_ws[idx] = nh;
    out_tail[idx] = nh;
    out_tail[BB*DD + idx] = nc;
}

// ---------------- launch ----------------
extern "C" void kernel_launch(void* const* d_in, const int* in_sizes, int n_in,
                              void* d_out, int out_size, void* d_ws, size_t ws_size,
                              hipStream_t stream) {
    const float* x    = (const float*)d_in[0];
    const float* h    = (const float*)d_in[1];
    const float* c    = (const float*)d_in[2];
    const float* Wq   = (const float*)d_in[3];
    const float* Wk   = (const float*)d_in[4];
    const float* Wv   = (const float*)d_in[5];
    const float* Wo   = (const float*)d_in[6];
    const float* Wmk  = (const float*)d_in[7];
    const float* Wmv  = (const float*)d_in[8];
    const float* Wih  = (const float*)d_in[9];
    const float* Whh  = (const float*)d_in[10];
    const float* b_ih = (const float*)d_in[11];
    const float* b_hh = (const float*)d_in[12];
    const float* W1   = (const float*)d_in[13];
    const float* bf1  = (const float*)d_in[14];
    const float* W2   = (const float*)d_in[15];
    const float* bf2  = (const float*)d_in[16];
    const float* g1   = (const float*)d_in[17];
    const float* be1  = (const float*)d_in[18];
    const float* g2   = (const float*)d_in[19];
    const float* be2  = (const float*)d_in[20];
    const float* g3   = (const float*)d_in[21];
    const float* be3  = (const float*)d_in[22];
    const float* Wmp  = (const float*)d_in[23];

    float* out = (float*)d_out;
    char* wsb  = (char*)d_ws;

    u16*   xn   = (u16*)(wsb + 0);        // 8MB  [0,8)
    u16*   hn   = (u16*)(wsb + 8*MB);     // 8MB  [8,16)
    u16*   pb0  = (u16*)(wsb + 0);        // FFN2 partial (xn dead)
    u16*   pb1  = (u16*)(wsb + 8*MB);     // FFN2 partial (hn dead)
    u16*   Qbuf = (u16*)(wsb + 16*MB);
    u16*   Kbuf = (u16*)(wsb + 24*MB);
    u16*   VTb  = (u16*)(wsb + 33*MB);
    u16*   act  = (u16*)(wsb + 16*MB);    // 32MB overlay [16,48)
    u16*   ao   = (u16*)(wsb + 48*MB);    // 8MB
    u16*   pb2  = (u16*)(wsb + 48*MB);    // FFN2 partial (ao dead)
    float* attb = (float*)(wsb + 56*MB);  // 16MB [56,72)
    u16*   WqkvT= (u16*)(wsb + 72*MB);    // 6MB
    u16*   WoT  = (u16*)(wsb + 78*MB);    // 2MB
    u16*   W1T  = (u16*)(wsb + 80*MB);    // 8MB
    u16*   pb3  = (u16*)(wsb + 80*MB);    // FFN2 partial (W1T dead)
    u16*   W2T  = (u16*)(wsb + 88*MB);    // 8MB
    float* sm   = (float*)(wsb + 96*MB);
    float* Kmb     = sm;
    float* Vmb     = Kmb + 2048;
    float* pooled  = Vmb + 2048;
    float* newh    = pooled + 2048;
    float* mproj   = newh + 2048;
    float* vpart   = mproj + 2048;
    float* v2part  = vpart + 16384;
    float* gpart   = v2part + 32768;
    float* ppart   = gpart + 131072;

    tr6_kernel<<<12288, 256, 0, stream>>>(Wq, Wk, Wv, Wo, W1, W2, WqkvT, WoT, W1T, W2T);

    ln_kernel<<<RR, 256, 0, stream>>>(x, nullptr, g1, be1, nullptr, nullptr, xn);
    vecmat2_part<<<dim3(4,8,BB), 256, 0, stream>>>(h, Wmk, Wmv, v2part);
    vecmat2_red<<<dim3(4,BB), 256, 0, stream>>>(v2part, Kmb, Vmb);
    // fused QKV projection: 256^2 8-phase, M=4096 N=3072 K=1024 -> grid 192
    mgemm256<<<192, 512, 0, stream>>>(xn, WqkvT, 12, 1024, 1, 1, nullptr,
                                      0.125f*1.44269504088896f, Qbuf, Kbuf, VTb, nullptr);
    fixup_kernel<<<8, 256, 0, stream>>>(Kmb, Vmb, Kbuf, VTb);
    attn_mfma<<<512, 256, 0, stream>>>(Qbuf, Kbuf, VTb, ao);
    // attended = x + ao @ Wo (128^2 path)
    mgemm<<<8*32, 256, 0, stream>>>(ao, WoT, 8, 1024, 1, MODE_F32R, nullptr, x, 1.f, attb, nullptr, nullptr);
    pool1_kernel<<<dim3(64,BB), 256, 0, stream>>>(attb, ppart);
    pool2_kernel<<<dim3(4,BB), 256, 0, stream>>>(ppart, pooled);
    gates_part<<<dim3(16,16,BB), 256, 0, stream>>>(pooled, h, Wih, Whh, gpart);
    lstm_kernel<<<8, 256, 0, stream>>>(gpart, b_ih, b_hh, c, newh, out + (size_t)RR*DD);
    vecmat_part<<<dim3(4,8,BB), 256, 0, stream>>>(newh, Wmp, vpart, DD, DD);
    vecmat_red<<<dim3(4,BB), 256, 0, stream>>>(vpart, mproj, DD);
    ln_kernel<<<RR, 256, 0, stream>>>(attb, mproj, g2, be2, attb, nullptr, hn);
    // FFN1: 256^2 8-phase, M=4096 N=4096 K=1024 -> grid 256
    mgemm256<<<256, 512, 0, stream>>>(hn, W1T, 16, 1024, 1, 0, bf1, 1.f, act, nullptr, nullptr, nullptr);
    // FFN2: 256^2 8-phase split-K=4 (bf16 partials), M=4096 N=1024 K=4x1024 -> grid 256
    mgemm256<<<256, 512, 0, stream>>>(act, W2T, 4, 1024, 4, 2, nullptr, 1.f, pb0, pb1, pb2, pb3);
    // out = LN3(sum(partials)+bias+resid)
    ln3f_kernel<<<RR, 256, 0, stream>>>(pb0, pb1, pb2, pb3, bf2, attb, g3, be3, out);
}